// Round 5
// baseline (391.846 us; speedup 1.0000x reference)
//
#include <hip/hip_runtime.h>
#include <hip/hip_fp16.h>

#define NM 131072   // mol nodes
#define EM 524288   // mol edges
#define NG 4096     // graphs
#define DM 6        // mol in dim
#define NP 100000   // prot nodes
#define EP 1600000  // prot edges
#define DP 20       // prot in dim

static inline int cdiv(int a, int b){ return (a + b - 1) / b; }

__device__ __forceinline__ float leaky(float x){ return x > 0.f ? x : 0.2f * x; }

union H8 { float4 f4; __half2 h2[4]; };
union HF8 { float4 f4; _Float16 h[8]; };

typedef _Float16 f16x8 __attribute__((ext_vector_type(8)));
typedef float    f32x4 __attribute__((ext_vector_type(4)));

// ================= merged bucketed CSR build (round-16, proven) =================
__global__ void k_hist2(const int* __restrict__ dstM, const int* __restrict__ dstP,
                        int* __restrict__ coarseM, int* __restrict__ coarseP){
    __shared__ int lh[512];
    int t = threadIdx.x;
    const int* dst; int* coarse; int K, E, base, chunk;
    if (blockIdx.x < 256) { dst = dstM; coarse = coarseM; K = 512; E = EM; chunk = 2048; base = blockIdx.x * 2048; }
    else                  { dst = dstP; coarse = coarseP; K = 391; E = EP; chunk = 4096; base = (blockIdx.x - 256) * 4096; }
    for (int i = t; i < K; i += 256) lh[i] = 0;
    __syncthreads();
    int end = min(base + chunk, E);
    for (int e = base + t; e < end; e += 256)
        atomicAdd(&lh[dst[e] >> 8], 1);
    __syncthreads();
    for (int i = t; i < K; i += 256)
        if (lh[i]) atomicAdd(&coarse[i], lh[i]);
}

__global__ void k_scan2(const int* __restrict__ coarseM, int* __restrict__ cstartM, int* __restrict__ cursorM,
                        const int* __restrict__ coarseP, int* __restrict__ cstartP, int* __restrict__ cursorP){
    const int* coarse; int* cstart; int* cursor; int K;
    if (blockIdx.x == 0) { coarse = coarseM; cstart = cstartM; cursor = cursorM; K = 512; }
    else                 { coarse = coarseP; cstart = cstartP; cursor = cursorP; K = 391; }
    int t = threadIdx.x, lane = t & 63, wid = t >> 6;
    int v0 = (t < K) ? coarse[t] : 0;
    int v = v0;
    #pragma unroll
    for (int off = 1; off < 64; off <<= 1) {
        int x = __shfl_up(v, off, 64);
        if (lane >= off) v += x;
    }
    __shared__ int ws[8];
    if (lane == 63) ws[wid] = v;
    __syncthreads();
    int add = 0;
    for (int w = 0; w < wid; w++) add += ws[w];
    int excl = v + add - v0;
    if (t < K) { cstart[t] = excl; cursor[t] = excl; }
    if (t == K - 1) cstart[K] = excl + v0;
}

__global__ void k_part2(const int* __restrict__ eiM, int* __restrict__ cursorM, unsigned* __restrict__ bufM,
                        const int* __restrict__ eiP, int* __restrict__ cursorP, unsigned* __restrict__ bufP){
    __shared__ int lh[512];
    __shared__ int lbase[512];
    const int* ei; int* cursor; unsigned* buf; int E, K, base;
    if (blockIdx.x < 128) { ei = eiM; cursor = cursorM; buf = bufM; E = EM; K = 512; base = blockIdx.x * 4096; }
    else                  { ei = eiP; cursor = cursorP; buf = bufP; E = EP; K = 391; base = (blockIdx.x - 128) * 4096; }
    int t = threadIdx.x;
    for (int i = t; i < K; i += 256) lh[i] = 0;
    __syncthreads();
    int end = min(base + 4096, E);
    unsigned pay[16]; int bslot[16];
    int cnt = 0;
    for (int e = base + t; e < end; e += 256) {
        int u = ei[e], v = ei[E + e];
        int b = v >> 8;
        int ls = atomicAdd(&lh[b], 1);
        pay[cnt] = ((unsigned)(v & 255) << 24) | (unsigned)u;
        bslot[cnt] = (b << 13) | ls;
        cnt++;
    }
    __syncthreads();
    for (int i = t; i < K; i += 256)
        lbase[i] = lh[i] ? atomicAdd(&cursor[i], lh[i]) : 0;
    __syncthreads();
    for (int j = 0; j < cnt; j++) {
        int b = bslot[j] >> 13, ls = bslot[j] & 8191;
        buf[lbase[b] + ls] = pay[j];
    }
}

__global__ void k_fine2(const unsigned* __restrict__ bufM, const int* __restrict__ cstartM,
                        int* __restrict__ molRP, int* __restrict__ molCOL, float* __restrict__ dinv,
                        const unsigned* __restrict__ bufP, const int* __restrict__ cstartP,
                        int* __restrict__ protRP, int* __restrict__ protCOL){
    int t = threadIdx.x;
    int k; const unsigned* buf; const int* cstart; int* rp; int* col; int n, OB, dv;
    if (blockIdx.x < 512) { k = blockIdx.x;       buf = bufM; cstart = cstartM; rp = molRP;  col = molCOL;  n = NM; OB = 20; dv = 1; }
    else                  { k = blockIdx.x - 512; buf = bufP; cstart = cstartP; rp = protRP; col = protCOL; n = NP; OB = 21; dv = 0; }
    int start = cstart[k], end = cstart[k + 1];
    __shared__ int cnt[256];
    __shared__ int cur[256];
    cnt[t] = 0;
    __syncthreads();
    for (int p = start + t; p < end; p += 256)
        atomicAdd(&cnt[buf[p] >> 24], 1);
    __syncthreads();
    int v0 = cnt[t];
    int lane = t & 63, wid = t >> 6;
    int v = v0;
    #pragma unroll
    for (int off = 1; off < 64; off <<= 1) {
        int x = __shfl_up(v, off, 64);
        if (lane >= off) v += x;
    }
    __shared__ int ws[4];
    if (lane == 63) ws[wid] = v;
    __syncthreads();
    int add = 0;
    for (int w = 0; w < wid; w++) add += ws[w];
    int excl = v + add - v0;
    int ofs = start + excl;
    cur[t] = ofs;
    int idx = (k << 8) + t;
    if (idx < n) {
        rp[idx] = (int)((unsigned)ofs | ((unsigned)v0 << OB));
        if (dv) dinv[idx] = rsqrtf((float)(v0 + 1));
    }
    __syncthreads();
    for (int p = start + t; p < end; p += 256) {
        unsigned pk = buf[p];
        int slot = atomicAdd(&cur[pk >> 24], 1);
        col[slot] = (int)(pk & 0xFFFFFFu);
    }
}

// ================= merged prep: molprep (512) + segbounds (512) + prot prep (391) =================
__global__ void k_prep2(const float* __restrict__ mol_x, const float* __restrict__ dinv,
                        __half* __restrict__ x8, const int* __restrict__ batch,
                        int* __restrict__ gstart, int* __restrict__ gend,
                        const float* __restrict__ prot_x, const float* __restrict__ W1,
                        const float* __restrict__ as_, const float* __restrict__ ad_,
                        __half* __restrict__ x32, float* __restrict__ es,
                        float* __restrict__ ed_){
    __shared__ float vas[20], vds[20];
    int b = blockIdx.x, t = threadIdx.x;
    if (b < 512) {
        int i = b * 256 + t;
        float dd = dinv[i];
        H8 r;
        #pragma unroll
        for (int k = 0; k < 3; k++)
            r.h2[k] = __floats2half2_rn(dd * mol_x[i*6 + 2*k], dd * mol_x[i*6 + 2*k + 1]);
        r.h2[3] = __floats2half2_rn(0.f, 0.f);
        *(float4*)&x8[(size_t)i * 8] = r.f4;
    } else if (b < 1024) {
        int i = (b - 512) * 256 + t;
        int g = batch[i];
        if (i == 0 || batch[i - 1] != g) gstart[g] = i;
        if (i == NM - 1 || batch[i + 1] != g) gend[g] = i + 1;
    } else {
        if (t < 20) {
            float s = 0.f;
            for (int j = 0; j < 64; j++) s += W1[t * 64 + j] * as_[j];
            vas[t] = s;
        } else if (t >= 32 && t < 52) {
            int k = t - 32;
            float s = 0.f;
            for (int j = 0; j < 64; j++) s += W1[k * 64 + j] * ad_[j];
            vds[k] = s;
        }
        __syncthreads();
        int i = (b - 1024) * 256 + t;
        if (i >= NP) return;
        float xv[20];
        float s = 0.f, d = 0.f;
        #pragma unroll
        for (int k = 0; k < 20; k++) {
            xv[k] = prot_x[i*20 + k];
            s += xv[k] * vas[k]; d += xv[k] * vds[k];
        }
        es[i] = s; ed_[i] = d;
        H8 r0, r1, r2, rz;
        #pragma unroll
        for (int k = 0; k < 4; k++) r0.h2[k] = __floats2half2_rn(xv[2*k],   xv[2*k+1]);
        #pragma unroll
        for (int k = 0; k < 4; k++) r1.h2[k] = __floats2half2_rn(xv[8+2*k], xv[9+2*k]);
        r2.h2[0] = __floats2half2_rn(xv[16], xv[17]);
        r2.h2[1] = __floats2half2_rn(xv[18], xv[19]);
        r2.h2[2] = __floats2half2_rn(0.f, 0.f);
        r2.h2[3] = __floats2half2_rn(0.f, 0.f);
        rz.h2[0] = rz.h2[1] = rz.h2[2] = rz.h2[3] = __floats2half2_rn(0.f, 0.f);
        *(float4*)&x32[(size_t)i * 32]      = r0.f4;
        *(float4*)&x32[(size_t)i * 32 + 8]  = r1.f4;
        *(float4*)&x32[(size_t)i * 32 + 16] = r2.f4;
        *(float4*)&x32[(size_t)i * 32 + 24] = rz.f4;
    }
}

// ================= merged L1 gathers: mol (4096 blocks) + prot (6250 blocks, 4 nodes/wave) =================
// loads predicated on slot validity (kernel is scatter-load bound, dummy loads waste TA/L2 work)
__global__ void k_l1g2(const int* __restrict__ molRP, const int* __restrict__ molCOL,
                       const __half* __restrict__ x8, const float* __restrict__ dinv,
                       float* __restrict__ aggM,
                       const int* __restrict__ protRP, const int* __restrict__ protCOL,
                       const __half* __restrict__ x32, const float* __restrict__ es,
                       const float* __restrict__ ed_, float* __restrict__ aggP){
    __shared__ float ost[192];
    int tid = threadIdx.x;
    if (blockIdx.x < NM/32) {
        int bid = blockIdx.x;
        int wv = tid >> 6, l = tid & 63, g = l >> 3, q = l & 7;
        int node = (bid << 5) + (wv << 3) + g;
        unsigned pk = (unsigned)molRP[node];
        int s0 = (int)(pk & 0xFFFFFu);
        int deg = (int)(pk >> 20);
        float acc[6] = {0.f,0.f,0.f,0.f,0.f,0.f};
        if (q == 0) {
            HF8 r; r.f4 = *(const float4*)&x8[(size_t)node * 8];
            #pragma unroll
            for (int i = 0; i < 6; i++) acc[i] = (float)r.h[i];
        }
        for (int base = 0; base < deg; base += 8) {
            int s = base + q;
            if (s < deg) {
                int c = molCOL[s0 + s];
                HF8 r; r.f4 = *(const float4*)&x8[(size_t)c * 8];
                #pragma unroll
                for (int i = 0; i < 6; i++) acc[i] += (float)r.h[i];
            }
        }
        #pragma unroll
        for (int m = 1; m < 8; m <<= 1) {
            #pragma unroll
            for (int i = 0; i < 6; i++) acc[i] += __shfl_xor(acc[i], m, 8);
        }
        if (q == 0) {
            float dd = dinv[node];
            int slot = (wv << 3) + g;
            #pragma unroll
            for (int i = 0; i < 6; i++) ost[slot * 6 + i] = dd * acc[i];
        }
        __syncthreads();
        if (tid < 48)
            *(float4*)&aggM[(size_t)bid * 192 + (tid << 2)] = *(float4*)&ost[tid << 2];
    } else {
        // prot: 16 nodes/block, 4 nodes/wave; per node: 4 edge-slots x 4 feature-chunks
        int bid = blockIdx.x - NM/32;
        int wv = tid >> 6, l = tid & 63;
        int nd = l >> 4;          // node within wave
        int slot = (l >> 2) & 3;  // edge slot
        int chunk = l & 3;        // 8-half feature chunk
        int node = (bid << 4) + (wv << 2) + nd;
        unsigned pk = (unsigned)protRP[node];
        int s0 = (int)(pk & 0x1FFFFFu);
        int deg = (int)(pk >> 21);
        float edv = ed_[node];
        float selfw = __expf(leaky(es[node] + edv));
        float acc[8] = {0.f,0.f,0.f,0.f,0.f,0.f,0.f,0.f};
        float den = (slot == 0) ? selfw : 0.f;
        if (slot == 0) {
            HF8 r; r.f4 = *(const float4*)&x32[(size_t)node * 32 + (chunk << 3)];
            #pragma unroll
            for (int i = 0; i < 8; i++) acc[i] = selfw * (float)r.h[i];
        }
        for (int base = 0; base < deg; base += 4) {
            int s = base + slot;
            if (s < deg) {
                int u = protCOL[s0 + s];
                float w = __expf(leaky(es[u] + edv));
                HF8 r; r.f4 = *(const float4*)&x32[(size_t)u * 32 + (chunk << 3)];
                #pragma unroll
                for (int i = 0; i < 8; i++) acc[i] += w * (float)r.h[i];
                den += w;
            }
        }
        #pragma unroll
        for (int m = 4; m <= 8; m <<= 1) {
            #pragma unroll
            for (int i = 0; i < 8; i++) acc[i] += __shfl_xor(acc[i], m, 64);
            den += __shfl_xor(den, m, 64);
        }
        float inv = 1.f / den;
        if (slot == 0) {
            float4 v0 = make_float4(acc[0]*inv, acc[1]*inv, acc[2]*inv, acc[3]*inv);
            if (chunk < 2) {
                float4 v1 = make_float4(acc[4]*inv, acc[5]*inv, acc[6]*inv, acc[7]*inv);
                *(float4*)&aggP[(size_t)node * 20 + (chunk << 3)]     = v0;
                *(float4*)&aggP[(size_t)node * 20 + (chunk << 3) + 4] = v1;
            } else if (chunk == 2) {
                *(float4*)&aggP[(size_t)node * 20 + 16] = v0;
            }
        }
    }
}

// ================= merged MLP via MFMA (f16 16x16x32), 64 nodes/block, 4 waves =================
// LDS (halves): W1T [64][40] @0, W2T [64][72] @2560, Ain [4][16][40] @7168, X1 [4][16][72] @9728
template<int D, int ATT, int SCALE>
__device__ __forceinline__ void mlp_mfma(__half* smemh, int bid, int tid,
                                         const float* __restrict__ agg, const float* __restrict__ W1,
                                         const float* __restrict__ b1, const float* __restrict__ W2,
                                         const float* __restrict__ as_, const float* __restrict__ ad_,
                                         __half* __restrict__ hout, float* __restrict__ es,
                                         float* __restrict__ ed_, const float* __restrict__ dinv,
                                         int n){
    __half* W1Ts = smemh;            // 64*40 = 2560 halves
    __half* W2Ts = smemh + 2560;     // 64*72 = 4608 halves
    __half* AinS = smemh + 7168;     // 4 waves * 16 rows * 40 k
    __half* X1S  = smemh + 9728;     // 4 waves * 16 rows * 72 cols
    int lane = tid & 63, w = tid >> 6;
    int c = lane & 15, g = lane >> 4;
    int node0 = bid * 64 + w * 16;

    for (int idx = tid; idx < 2048; idx += 256) {
        int k = idx >> 6, col = idx & 63;
        W1Ts[col * 40 + k] = __float2half(k < D ? W1[k * 64 + col] : 0.f);
    }
    for (int idx = tid; idx < 4096; idx += 256) {
        int k = idx >> 6, col = idx & 63;
        W2Ts[col * 72 + k] = __float2half(W2[k * 64 + col]);
    }
    {
        float4 z4 = make_float4(0.f, 0.f, 0.f, 0.f);
        float4* az = (float4*)(AinS + w * 640);
        for (int i = lane; i < 80; i += 64) az[i] = z4;
        int lim = 16 * D;
        if (ATT) { int rem = n - node0; if (rem < 0) rem = 0; if (rem < 16) lim = rem * D; }
        const float* aw = agg + (size_t)node0 * D;
        for (int idx = lane; idx < lim; idx += 64) {
            int r = idx / D, k = idx - r * D;
            AinS[w * 640 + r * 40 + k] = __float2half(aw[idx]);
        }
    }
    __syncthreads();

    f32x4 zz = {0.f, 0.f, 0.f, 0.f};
    f16x8 a1 = *(const f16x8*)&AinS[w * 640 + c * 40 + 8 * g];
    #pragma unroll
    for (int t = 0; t < 4; t++) {
        f16x8 b = *(const f16x8*)&W1Ts[(16 * t + c) * 40 + 8 * g];
        f32x4 h = __builtin_amdgcn_mfma_f32_16x16x32_f16(a1, b, zz, 0, 0, 0);
        float bv = b1[16 * t + c];
        #pragma unroll
        for (int r = 0; r < 4; r++) {
            float v = fmaxf(h[r] + bv, 0.f);
            X1S[w * 1152 + (4 * g + r) * 72 + 16 * t + c] = __float2half(v);
        }
    }
    __syncthreads();

    f32x4 acc[4];
    #pragma unroll
    for (int t = 0; t < 4; t++) acc[t] = zz;
    #pragma unroll
    for (int kt = 0; kt < 2; kt++) {
        f16x8 a = *(const f16x8*)&X1S[w * 1152 + c * 72 + 32 * kt + 8 * g];
        #pragma unroll
        for (int t = 0; t < 4; t++) {
            f16x8 b = *(const f16x8*)&W2Ts[(16 * t + c) * 72 + 32 * kt + 8 * g];
            acc[t] = __builtin_amdgcn_mfma_f32_16x16x32_f16(a, b, acc[t], 0, 0, 0);
        }
    }

    if (ATT) {
        float asv[4], adv[4];
        #pragma unroll
        for (int t = 0; t < 4; t++) { asv[t] = as_[16 * t + c]; adv[t] = ad_[16 * t + c]; }
        #pragma unroll
        for (int r = 0; r < 4; r++) {
            float xa = 0.f, ya = 0.f;
            #pragma unroll
            for (int t = 0; t < 4; t++) { xa += acc[t][r] * asv[t]; ya += acc[t][r] * adv[t]; }
            #pragma unroll
            for (int m = 1; m < 16; m <<= 1) { xa += __shfl_xor(xa, m, 16); ya += __shfl_xor(ya, m, 16); }
            int nd = node0 + 4 * g + r;
            if (c == 0 && nd < n) { es[nd] = xa; ed_[nd] = ya; }
        }
    }
    if (SCALE) {
        #pragma unroll
        for (int r = 0; r < 4; r++) {
            float dd = dinv[node0 + 4 * g + r];
            #pragma unroll
            for (int t = 0; t < 4; t++) acc[t][r] *= dd;
        }
    }

    #pragma unroll
    for (int t = 0; t < 4; t++) {
        #pragma unroll
        for (int r = 0; r < 4; r++)
            X1S[w * 1152 + (4 * g + r) * 72 + 16 * t + c] = __float2half(acc[t][r]);
    }
    __syncthreads();
    int rr = lane >> 2, seg = lane & 3;
    union { f16x8 h; float4 f; } o;
    o.h = *(const f16x8*)&X1S[w * 1152 + rr * 72 + seg * 16];
    int nd = node0 + rr;
    if (!ATT || nd < n)
        *(float4*)&hout[(size_t)nd * 64 + seg * 16] = o.f;
}

__global__ void k_mlp2(const float* __restrict__ aggM, const float* __restrict__ gcn_w1,
                       const float* __restrict__ gcn_b1, const float* __restrict__ gcn_w2,
                       __half* __restrict__ h2hM, const float* __restrict__ dinvM,
                       const float* __restrict__ aggP, const float* __restrict__ gat_w1,
                       const float* __restrict__ gat_b1, const float* __restrict__ gat_w2,
                       const float* __restrict__ as2, const float* __restrict__ ad2,
                       __half* __restrict__ h2hP, float* __restrict__ es, float* __restrict__ ed_){
    __shared__ __attribute__((aligned(16))) __half smemh[14336];   // 28672 B -> 5 blocks/CU
    if (blockIdx.x < NM/64)
        mlp_mfma<6, 0, 1>(smemh, blockIdx.x, threadIdx.x, aggM, gcn_w1, gcn_b1, gcn_w2,
                          nullptr, nullptr, h2hM, nullptr, nullptr, dinvM, NM);
    else
        mlp_mfma<20, 1, 0>(smemh, blockIdx.x - NM/64, threadIdx.x, aggP, gat_w1, gat_b1, gat_w2,
                           as2, ad2, h2hP, es, ed_, nullptr, NP);
}

// ================= L2 phase, restructured =================
// prot pooled output = sum_u coef_u * hh_u  (source-sum collapse; no scattered row gathers)
//   k_l2g2 prot part: den_v per node (4B es gathers only); seeds coefP[v] = selfw_v/den_v
//   k_coef: edge sweep, coefP[u] += exp(leaky(es_u+ed_v))/den_v
//   k_psum: coalesced stream of hhP weighted by coefP -> psumP partials
// mol part keeps the row gather (pooling is per-graph, edges cross graphs); loads predicated.
__global__ void k_l2g2(const int* __restrict__ protRP, const int* __restrict__ protCOL,
                       const float* __restrict__ es, const float* __restrict__ ed_,
                       float* __restrict__ denP, float* __restrict__ coefP,
                       const int* __restrict__ molRP, const int* __restrict__ molCOL,
                       const __half* __restrict__ hhM, const float* __restrict__ dinv,
                       const int* __restrict__ batch, float* __restrict__ gsum){
    __shared__ float sb[4][64];
    __shared__ int gidS[4];
    int tid = threadIdx.x;
    if (blockIdx.x < NP/16) {
        // prot den: 16 nodes/block, 16 lanes/node, es-only gather
        int node = (blockIdx.x << 4) + (tid >> 4);
        int l16 = tid & 15;
        unsigned pk = (unsigned)protRP[node];
        int s0 = (int)(pk & 0x1FFFFFu);
        int deg = (int)(pk >> 21);
        float edv = ed_[node];
        float den = 0.f;
        for (int s = l16; s < deg; s += 16) {
            int u = protCOL[s0 + s];
            den += __expf(leaky(es[u] + edv));
        }
        #pragma unroll
        for (int m = 1; m < 16; m <<= 1) den += __shfl_xor(den, m, 16);
        if (l16 == 0) {
            float selfw = __expf(leaky(es[node] + edv));
            float dd = den + selfw;
            denP[node] = dd;
            coefP[node] = selfw / dd;
        }
    } else {
        int bid = blockIdx.x - NP/16;
        int wv = tid >> 6, l = tid & 63, g = l >> 3, q = l & 7;
        int node = (bid << 2) + wv;
        unsigned pk = (unsigned)molRP[node];
        int s0 = (int)(pk & 0xFFFFFu);
        int deg = (int)(pk >> 20);
        float acc[8] = {0.f,0.f,0.f,0.f,0.f,0.f,0.f,0.f};
        if (g == 0) {
            HF8 r; r.f4 = *(const float4*)&hhM[(size_t)node * 64 + (q << 3)];
            #pragma unroll
            for (int i = 0; i < 8; i++) acc[i] = (float)r.h[i];
        }
        for (int base = 0; base < deg; base += 8) {
            int s = base + g;
            if (s < deg) {
                int u = molCOL[s0 + s];
                HF8 r; r.f4 = *(const float4*)&hhM[(size_t)u * 64 + (q << 3)];
                #pragma unroll
                for (int i = 0; i < 8; i++) acc[i] += (float)r.h[i];
            }
        }
        #pragma unroll
        for (int m = 8; m <= 32; m <<= 1) {
            #pragma unroll
            for (int i = 0; i < 8; i++) acc[i] += __shfl_xor(acc[i], m, 64);
        }
        if (g == 0) {
            float sc = dinv[node];
            #pragma unroll
            for (int i = 0; i < 8; i++) sb[wv][(q << 3) + i] = acc[i] * sc;
        }
        if (l == 0) gidS[wv] = batch[node];
        __syncthreads();
        if (tid < 64) {
            int g0 = gidS[0];
            if (gidS[1] == g0 && gidS[2] == g0 && gidS[3] == g0) {
                float s = sb[0][tid] + sb[1][tid] + sb[2][tid] + sb[3][tid];
                atomicAdd(&gsum[(g0 << 6) + tid], s);
            } else {
                #pragma unroll
                for (int w2 = 0; w2 < 4; w2++)
                    atomicAdd(&gsum[(gidS[w2] << 6) + tid], sb[w2][tid]);
            }
        }
    }
}

// ---------------- coef pass: edge-parallel, coefP[u] += w_uv / den_v ----------------
__global__ void k_coef(const int* __restrict__ ei, const float* __restrict__ es,
                       const float* __restrict__ ed_, const float* __restrict__ denP,
                       float* __restrict__ coefP){
    int i = blockIdx.x * 256 + threadIdx.x;
    int e = i * 4;
    if (e >= EP) return;
    int4 u4 = *(const int4*)&ei[e];
    int4 v4 = *(const int4*)&ei[EP + e];
    float w0 = __expf(leaky(es[u4.x] + ed_[v4.x])) / denP[v4.x];
    float w1 = __expf(leaky(es[u4.y] + ed_[v4.y])) / denP[v4.y];
    float w2 = __expf(leaky(es[u4.z] + ed_[v4.z])) / denP[v4.z];
    float w3 = __expf(leaky(es[u4.w] + ed_[v4.w])) / denP[v4.w];
    atomicAdd(&coefP[u4.x], w0);
    atomicAdd(&coefP[u4.y], w1);
    atomicAdd(&coefP[u4.z], w2);
    atomicAdd(&coefP[u4.w], w3);
}

// ---------------- psum pass: coalesced stream, psum = sum_u coefP[u]*hh_u ----------------
__global__ void k_psum(const float* __restrict__ coefP, const __half* __restrict__ hhP,
                       float* __restrict__ psumP){
    __shared__ float red[4][64];
    int tid = threadIdx.x;
    int wv = tid >> 6, l = tid & 63, g = l >> 3, q = l & 7;
    float acc[8] = {0.f,0.f,0.f,0.f,0.f,0.f,0.f,0.f};
    for (int base = blockIdx.x * 32; base < NP; base += 512 * 32) {
        int u = base + (wv << 3) + g;
        if (u < NP) {
            float cf = coefP[u];
            HF8 r; r.f4 = *(const float4*)&hhP[(size_t)u * 64 + (q << 3)];
            #pragma unroll
            for (int i = 0; i < 8; i++) acc[i] += cf * (float)r.h[i];
        }
    }
    #pragma unroll
    for (int m = 8; m <= 32; m <<= 1) {
        #pragma unroll
        for (int i = 0; i < 8; i++) acc[i] += __shfl_xor(acc[i], m, 64);
    }
    if (g == 0) {
        #pragma unroll
        for (int i = 0; i < 8; i++) red[wv][(q << 3) + i] = acc[i];
    }
    __syncthreads();
    if (tid < 64) {
        float s = red[0][tid] + red[1][tid] + red[2][tid] + red[3][tid];
        atomicAdd(&psumP[((blockIdx.x & 63) << 6) + tid], s);
    }
}

// ---------------- fused classifier (reduces psumP, applies layer-2 biases) ----------------
__global__ void k_cls(const float* __restrict__ gsum, const int* __restrict__ gstart,
                      const int* __restrict__ gend, const float* __restrict__ psumP,
                      const float* __restrict__ bg, const float* __restrict__ bp,
                      const float* __restrict__ W1, const float* __restrict__ b1,
                      const float* __restrict__ w2, const float* __restrict__ b2,
                      float* __restrict__ out){
    __shared__ float W1s[128 * 64];
    __shared__ float pv[64], bgs[64];
    int tid = threadIdx.x;
    for (int k = tid; k < 128 * 64; k += 256) W1s[k] = W1[k];
    if (tid < 64) {
        float s = 0.f;
        for (int sl = 0; sl < 64; sl++) s += psumP[(sl << 6) + tid];
        pv[tid] = s * (1.0f / (float)NP) + bp[tid];
        bgs[tid] = bg[tid];
    }
    __syncthreads();
    int g = blockIdx.x * 4 + (tid >> 6);
    int j = tid & 63;
    float cntf = (float)(gend[g] - gstart[g]);
    float inv = 1.0f / fmaxf(cntf, 1.0f);
    float acc = b1[j];
    #pragma unroll 8
    for (int k = 0; k < 64; k++) acc += (gsum[g * 64 + k] * inv + bgs[k]) * W1s[k * 64 + j];
    #pragma unroll 8
    for (int k = 0; k < 64; k++) acc += pv[k] * W1s[(64 + k) * 64 + j];
    float v = fmaxf(acc, 0.f) * w2[j];
    #pragma unroll
    for (int off = 32; off > 0; off >>= 1) v += __shfl_down(v, off, 64);
    if (j == 0) out[g] = 1.0f / (1.0f + expf(-(v + b2[0])));
}

extern "C" void kernel_launch(void* const* d_in, const int* in_sizes, int n_in,
                              void* d_out, int out_size, void* d_ws, size_t ws_size,
                              hipStream_t stream) {
    const float* mol_x   = (const float*)d_in[0];
    const int*   mol_ei  = (const int*)d_in[1];
    const int*   mol_bat = (const int*)d_in[2];
    const float* prot_x  = (const float*)d_in[3];
    const int*   prot_ei = (const int*)d_in[4];
    const float* gcn_w1  = (const float*)d_in[5];
    const float* gcn_b1  = (const float*)d_in[6];
    const float* gcn_w2  = (const float*)d_in[7];
    const float* gcn_b2  = (const float*)d_in[8];
    const float* gat_w1  = (const float*)d_in[9];
    const float* gat_as1 = (const float*)d_in[10];
    const float* gat_ad1 = (const float*)d_in[11];
    const float* gat_b1  = (const float*)d_in[12];
    const float* gat_w2  = (const float*)d_in[13];
    const float* gat_as2 = (const float*)d_in[14];
    const float* gat_ad2 = (const float*)d_in[15];
    const float* gat_b2  = (const float*)d_in[16];
    const float* cls_w1  = (const float*)d_in[17];
    const float* cls_b1  = (const float*)d_in[18];
    const float* cls_w2  = (const float*)d_in[19];
    const float* cls_b2  = (const float*)d_in[20];
    float* out = (float*)d_out;

    float* ws_f = (float*)d_ws;

    // ---- persistent tail ----
    float* T       = ws_f + 16777216;
    float* gsum    = T;                       // 262,144 floats (zeroed; atomic-accumulated)
    int*   gstart  = (int*)(T + 262144);      // 4,096 ints (zeroed)
    int*   gend    = (int*)(T + 266240);      // 4,096 ints (zeroed)
    int*   coarseM = (int*)(T + 270400);      // 512 ints (zeroed)
    int*   coarseP = (int*)(T + 270912);      // 512 ints (zeroed)
    int*   cstartM = (int*)(T + 271424);      // 513
    int*   cursorM = (int*)(T + 271937);      // 512
    int*   cstartP = (int*)(T + 272449);      // 513
    int*   cursorP = (int*)(T + 272962);      // 512
    float* psumP   = T + 273474;              // 64 x 64 floats (zeroed; atomic partials)

    // ---- early CSR staging (dead after k_fine2) ----
    unsigned* bufM = (unsigned*)ws_f;                    // [0, 524,288)
    unsigned* bufP = (unsigned*)(ws_f + 524352);         // [524,352, 2,124,416)

    // ---- overlapping phase regions (all offsets in floats) ----
    // [0, 3,200,000):          h2hP (fp16, NP*64) -- written by mlp2, read by k_psum
    // [4,194,304, 5,794,304):  x32h (fp16, NP*32) -- dead after l1g2
    // [5,794,304, 7,794,304):  aggP -- dead after mlp2; denP/coefP live there for the L2 phase
    // [7,794,304, 7,894,304):  es ; [7,894,304, 7,994,304): ed
    // [8,388,608, 12,582,912): h2hM (fp16, NM*64) -- read by l2g2 (mol)
    __half*   h2hP      = (__half*)ws_f;
    __half*   x32h      = (__half*)(ws_f + 4194304);
    float*    aggP      = ws_f + 5794304;
    float*    denP      = ws_f + 5794304;                // reuses aggP (dead after mlp2)
    float*    coefP     = ws_f + 5894304;                // reuses aggP region
    float*    es        = ws_f + 7794304;
    float*    ed_       = ws_f + 7894304;
    __half*   h2hM      = (__half*)(ws_f + 8388608);
    int*      molCOL    = (int*)(ws_f + 12582912);       // EM+64 -> 13,107,264
    int*      molRP     = (int*)(ws_f + 13107264);       // NM -> 13,238,336 (+pad)
    float*    dinvM     = ws_f + 13238352;               // NM -> 13,369,424 (+pad)
    __half*   x8h       = (__half*)(ws_f + 13369440);    // NM*8 halves -> 13,893,728 (+pad)
    float*    aggM      = ws_f + 13893792;               // NM*6 -> 14,680,224 (+pad)
    int*      protCOL   = (int*)(ws_f + 14680256);       // EP+64 -> 16,280,320
    int*      protRP    = (int*)(ws_f + 16280320);       // NP -> 16,380,320

    // single upfront zero of gsum..psumP (contiguous)
    (void)hipMemsetAsync(gsum, 0, (size_t)(273474 + 4096) * sizeof(float), stream);

    // ================= merged CSR build (mol + prot) =================
    k_hist2<<<256 + 391, 256, 0, stream>>>(mol_ei + EM, prot_ei + EP, coarseM, coarseP);
    k_scan2<<<2, 512, 0, stream>>>(coarseM, cstartM, cursorM, coarseP, cstartP, cursorP);
    k_part2<<<128 + 391, 256, 0, stream>>>(mol_ei, cursorM, bufM, prot_ei, cursorP, bufP);
    k_fine2<<<512 + 391, 256, 0, stream>>>(bufM, cstartM, molRP, molCOL, dinvM,
                                           bufP, cstartP, protRP, protCOL);

    // ================= merged preps =================
    k_prep2<<<512 + 512 + 391, 256, 0, stream>>>(mol_x, dinvM, x8h, mol_bat, gstart, gend,
                                                 prot_x, gat_w1, gat_as1, gat_ad1, x32h, es, ed_);

    // ================= merged L1 gathers (prot: 16 nodes/block) =================
    k_l1g2<<<NM/32 + NP/16, 256, 0, stream>>>(molRP, molCOL, x8h, dinvM, aggM,
                                              protRP, protCOL, x32h, es, ed_, aggP);

    // ================= merged MLPs (MFMA, 64 nodes/block) =================
    k_mlp2<<<NM/64 + cdiv(NP, 64), 256, 0, stream>>>(aggM, gcn_w1, gcn_b1, gcn_w2, h2hM, dinvM,
                                                     aggP, gat_w1, gat_b1, gat_w2, gat_as2, gat_ad2,
                                                     h2hP, es, ed_);

    // ================= L2 phase: mol gather + prot den (one launch), then coef, then psum ======
    k_l2g2<<<NP/16 + NM/4, 256, 0, stream>>>(protRP, protCOL, es, ed_, denP, coefP,
                                             molRP, molCOL, h2hM, dinvM, mol_bat, gsum);
    k_coef<<<cdiv(EP/4, 256), 256, 0, stream>>>(prot_ei, es, ed_, denP, coefP);
    k_psum<<<512, 256, 0, stream>>>(coefP, h2hP, psumP);

    // ================= classifier (reduces psumP, applies layer-2 biases) =================
    k_cls<<<NG/4, 256, 0, stream>>>(gsum, gstart, gend, psumP, gcn_b2, gat_b2,
                                    cls_w1, cls_b1, cls_w2, cls_b2, out);
}

// Round 6
// 328.029 us; speedup vs baseline: 1.1945x; 1.1945x over previous
//
#include <hip/hip_runtime.h>
#include <hip/hip_fp16.h>

#define NM 131072   // mol nodes
#define EM 524288   // mol edges
#define NG 4096     // graphs
#define DM 6        // mol in dim
#define NP 100000   // prot nodes
#define EP 1600000  // prot edges
#define DP 20       // prot in dim

static inline int cdiv(int a, int b){ return (a + b - 1) / b; }

__device__ __forceinline__ float leaky(float x){ return x > 0.f ? x : 0.2f * x; }

union H8 { float4 f4; __half2 h2[4]; };
union HF8 { float4 f4; _Float16 h[8]; };

typedef _Float16 f16x8 __attribute__((ext_vector_type(8)));
typedef float    f32x4 __attribute__((ext_vector_type(4)));

// ================= merged bucketed CSR build: mol-dst + prot-dst + prot-src =================
__global__ void k_hist2(const int* __restrict__ dstM, const int* __restrict__ dstP,
                        const int* __restrict__ srcP,
                        int* __restrict__ coarseM, int* __restrict__ coarseP,
                        int* __restrict__ coarseS){
    __shared__ int lh[512];
    int t = threadIdx.x;
    const int* dst; int* coarse; int K, E, base, chunk;
    if (blockIdx.x < 256)      { dst = dstM; coarse = coarseM; K = 512; E = EM; chunk = 2048; base = blockIdx.x * 2048; }
    else if (blockIdx.x < 647) { dst = dstP; coarse = coarseP; K = 391; E = EP; chunk = 4096; base = (blockIdx.x - 256) * 4096; }
    else                       { dst = srcP; coarse = coarseS; K = 391; E = EP; chunk = 4096; base = (blockIdx.x - 647) * 4096; }
    for (int i = t; i < K; i += 256) lh[i] = 0;
    __syncthreads();
    int end = min(base + chunk, E);
    for (int e = base + t; e < end; e += 256)
        atomicAdd(&lh[dst[e] >> 8], 1);
    __syncthreads();
    for (int i = t; i < K; i += 256)
        if (lh[i]) atomicAdd(&coarse[i], lh[i]);
}

__global__ void k_scan2(const int* __restrict__ coarseM, int* __restrict__ cstartM, int* __restrict__ cursorM,
                        const int* __restrict__ coarseP, int* __restrict__ cstartP, int* __restrict__ cursorP,
                        const int* __restrict__ coarseS, int* __restrict__ cstartS, int* __restrict__ cursorS){
    const int* coarse; int* cstart; int* cursor; int K;
    if (blockIdx.x == 0)      { coarse = coarseM; cstart = cstartM; cursor = cursorM; K = 512; }
    else if (blockIdx.x == 1) { coarse = coarseP; cstart = cstartP; cursor = cursorP; K = 391; }
    else                      { coarse = coarseS; cstart = cstartS; cursor = cursorS; K = 391; }
    int t = threadIdx.x, lane = t & 63, wid = t >> 6;
    int v0 = (t < K) ? coarse[t] : 0;
    int v = v0;
    #pragma unroll
    for (int off = 1; off < 64; off <<= 1) {
        int x = __shfl_up(v, off, 64);
        if (lane >= off) v += x;
    }
    __shared__ int ws[8];
    if (lane == 63) ws[wid] = v;
    __syncthreads();
    int add = 0;
    for (int w = 0; w < wid; w++) add += ws[w];
    int excl = v + add - v0;
    if (t < K) { cstart[t] = excl; cursor[t] = excl; }
    if (t == K - 1) cstart[K] = excl + v0;
}

__global__ void k_part2(const int* __restrict__ eiM, int* __restrict__ cursorM, unsigned* __restrict__ bufM,
                        const int* __restrict__ eiP, int* __restrict__ cursorP, unsigned* __restrict__ bufP,
                        int* __restrict__ cursorS, unsigned* __restrict__ bufS){
    __shared__ int lh[512];
    __shared__ int lbase[512];
    const int* ei; int* cursor; unsigned* buf; int E, K, base, sw;
    if (blockIdx.x < 128)      { ei = eiM; cursor = cursorM; buf = bufM; E = EM; K = 512; base = blockIdx.x * 4096; sw = 0; }
    else if (blockIdx.x < 519) { ei = eiP; cursor = cursorP; buf = bufP; E = EP; K = 391; base = (blockIdx.x - 128) * 4096; sw = 0; }
    else                       { ei = eiP; cursor = cursorS; buf = bufS; E = EP; K = 391; base = (blockIdx.x - 519) * 4096; sw = 1; }
    int t = threadIdx.x;
    for (int i = t; i < K; i += 256) lh[i] = 0;
    __syncthreads();
    int end = min(base + 4096, E);
    unsigned pay[16]; int bslot[16];
    int cnt = 0;
    for (int e = base + t; e < end; e += 256) {
        int u = ei[e], v = ei[E + e];
        int key = sw ? u : v, oth = sw ? v : u;
        int b = key >> 8;
        int ls = atomicAdd(&lh[b], 1);
        pay[cnt] = ((unsigned)(key & 255) << 24) | (unsigned)oth;
        bslot[cnt] = (b << 13) | ls;
        cnt++;
    }
    __syncthreads();
    for (int i = t; i < K; i += 256)
        lbase[i] = lh[i] ? atomicAdd(&cursor[i], lh[i]) : 0;
    __syncthreads();
    for (int j = 0; j < cnt; j++) {
        int b = bslot[j] >> 13, ls = bslot[j] & 8191;
        buf[lbase[b] + ls] = pay[j];
    }
}

__global__ void k_fine2(const unsigned* __restrict__ bufM, const int* __restrict__ cstartM,
                        int* __restrict__ molRP, int* __restrict__ molCOL, float* __restrict__ dinv,
                        const unsigned* __restrict__ bufP, const int* __restrict__ cstartP,
                        int* __restrict__ protRP, int* __restrict__ protCOL,
                        const unsigned* __restrict__ bufS, const int* __restrict__ cstartS,
                        int* __restrict__ srcRP, int* __restrict__ srcCOL){
    int t = threadIdx.x;
    int k; const unsigned* buf; const int* cstart; int* rp; int* col; int n, OB, dv;
    if (blockIdx.x < 512)      { k = blockIdx.x;       buf = bufM; cstart = cstartM; rp = molRP;  col = molCOL;  n = NM; OB = 20; dv = 1; }
    else if (blockIdx.x < 903) { k = blockIdx.x - 512; buf = bufP; cstart = cstartP; rp = protRP; col = protCOL; n = NP; OB = 21; dv = 0; }
    else                       { k = blockIdx.x - 903; buf = bufS; cstart = cstartS; rp = srcRP;  col = srcCOL;  n = NP; OB = 21; dv = 0; }
    int start = cstart[k], end = cstart[k + 1];
    __shared__ int cnt[256];
    __shared__ int cur[256];
    cnt[t] = 0;
    __syncthreads();
    for (int p = start + t; p < end; p += 256)
        atomicAdd(&cnt[buf[p] >> 24], 1);
    __syncthreads();
    int v0 = cnt[t];
    int lane = t & 63, wid = t >> 6;
    int v = v0;
    #pragma unroll
    for (int off = 1; off < 64; off <<= 1) {
        int x = __shfl_up(v, off, 64);
        if (lane >= off) v += x;
    }
    __shared__ int ws[4];
    if (lane == 63) ws[wid] = v;
    __syncthreads();
    int add = 0;
    for (int w = 0; w < wid; w++) add += ws[w];
    int excl = v + add - v0;
    int ofs = start + excl;
    cur[t] = ofs;
    int idx = (k << 8) + t;
    if (idx < n) {
        rp[idx] = (int)((unsigned)ofs | ((unsigned)v0 << OB));
        if (dv) dinv[idx] = rsqrtf((float)(v0 + 1));
    }
    __syncthreads();
    for (int p = start + t; p < end; p += 256) {
        unsigned pk = buf[p];
        int slot = atomicAdd(&cur[pk >> 24], 1);
        col[slot] = (int)(pk & 0xFFFFFFu);
    }
}

// ================= merged prep: molprep (512) + segbounds (512) + prot prep (391) =================
__global__ void k_prep2(const float* __restrict__ mol_x, const float* __restrict__ dinv,
                        __half* __restrict__ x8, const int* __restrict__ batch,
                        int* __restrict__ gstart, int* __restrict__ gend,
                        const float* __restrict__ prot_x, const float* __restrict__ W1,
                        const float* __restrict__ as_, const float* __restrict__ ad_,
                        __half* __restrict__ x32, float* __restrict__ es,
                        float* __restrict__ ed_){
    __shared__ float vas[20], vds[20];
    int b = blockIdx.x, t = threadIdx.x;
    if (b < 512) {
        int i = b * 256 + t;
        float dd = dinv[i];
        H8 r;
        #pragma unroll
        for (int k = 0; k < 3; k++)
            r.h2[k] = __floats2half2_rn(dd * mol_x[i*6 + 2*k], dd * mol_x[i*6 + 2*k + 1]);
        r.h2[3] = __floats2half2_rn(0.f, 0.f);
        *(float4*)&x8[(size_t)i * 8] = r.f4;
    } else if (b < 1024) {
        int i = (b - 512) * 256 + t;
        int g = batch[i];
        if (i == 0 || batch[i - 1] != g) gstart[g] = i;
        if (i == NM - 1 || batch[i + 1] != g) gend[g] = i + 1;
    } else {
        if (t < 20) {
            float s = 0.f;
            for (int j = 0; j < 64; j++) s += W1[t * 64 + j] * as_[j];
            vas[t] = s;
        } else if (t >= 32 && t < 52) {
            int k = t - 32;
            float s = 0.f;
            for (int j = 0; j < 64; j++) s += W1[k * 64 + j] * ad_[j];
            vds[k] = s;
        }
        __syncthreads();
        int i = (b - 1024) * 256 + t;
        if (i >= NP) return;
        float xv[20];
        float s = 0.f, d = 0.f;
        #pragma unroll
        for (int k = 0; k < 20; k++) {
            xv[k] = prot_x[i*20 + k];
            s += xv[k] * vas[k]; d += xv[k] * vds[k];
        }
        es[i] = s; ed_[i] = d;
        H8 r0, r1, r2, rz;
        #pragma unroll
        for (int k = 0; k < 4; k++) r0.h2[k] = __floats2half2_rn(xv[2*k],   xv[2*k+1]);
        #pragma unroll
        for (int k = 0; k < 4; k++) r1.h2[k] = __floats2half2_rn(xv[8+2*k], xv[9+2*k]);
        r2.h2[0] = __floats2half2_rn(xv[16], xv[17]);
        r2.h2[1] = __floats2half2_rn(xv[18], xv[19]);
        r2.h2[2] = __floats2half2_rn(0.f, 0.f);
        r2.h2[3] = __floats2half2_rn(0.f, 0.f);
        rz.h2[0] = rz.h2[1] = rz.h2[2] = rz.h2[3] = __floats2half2_rn(0.f, 0.f);
        *(float4*)&x32[(size_t)i * 32]      = r0.f4;
        *(float4*)&x32[(size_t)i * 32 + 8]  = r1.f4;
        *(float4*)&x32[(size_t)i * 32 + 16] = r2.f4;
        *(float4*)&x32[(size_t)i * 32 + 24] = rz.f4;
    }
}

// ================= merged L1 gathers: mol (4096 blocks) + prot (6250 blocks, 4 nodes/wave) =================
__global__ void k_l1g2(const int* __restrict__ molRP, const int* __restrict__ molCOL,
                       const __half* __restrict__ x8, const float* __restrict__ dinv,
                       float* __restrict__ aggM,
                       const int* __restrict__ protRP, const int* __restrict__ protCOL,
                       const __half* __restrict__ x32, const float* __restrict__ es,
                       const float* __restrict__ ed_, float* __restrict__ aggP){
    __shared__ float ost[192];
    int tid = threadIdx.x;
    if (blockIdx.x < NM/32) {
        int bid = blockIdx.x;
        int wv = tid >> 6, l = tid & 63, g = l >> 3, q = l & 7;
        int node = (bid << 5) + (wv << 3) + g;
        unsigned pk = (unsigned)molRP[node];
        int s0 = (int)(pk & 0xFFFFFu);
        int deg = (int)(pk >> 20);
        float acc[6] = {0.f,0.f,0.f,0.f,0.f,0.f};
        if (q == 0) {
            HF8 r; r.f4 = *(const float4*)&x8[(size_t)node * 8];
            #pragma unroll
            for (int i = 0; i < 6; i++) acc[i] = (float)r.h[i];
        }
        for (int base = 0; base < deg; base += 8) {
            int s = base + q;
            if (s < deg) {
                int c = molCOL[s0 + s];
                HF8 r; r.f4 = *(const float4*)&x8[(size_t)c * 8];
                #pragma unroll
                for (int i = 0; i < 6; i++) acc[i] += (float)r.h[i];
            }
        }
        #pragma unroll
        for (int m = 1; m < 8; m <<= 1) {
            #pragma unroll
            for (int i = 0; i < 6; i++) acc[i] += __shfl_xor(acc[i], m, 8);
        }
        if (q == 0) {
            float dd = dinv[node];
            int slot = (wv << 3) + g;
            #pragma unroll
            for (int i = 0; i < 6; i++) ost[slot * 6 + i] = dd * acc[i];
        }
        __syncthreads();
        if (tid < 48)
            *(float4*)&aggM[(size_t)bid * 192 + (tid << 2)] = *(float4*)&ost[tid << 2];
    } else {
        // prot: 16 nodes/block, 4 nodes/wave; per node: 4 edge-slots x 4 feature-chunks
        int bid = blockIdx.x - NM/32;
        int wv = tid >> 6, l = tid & 63;
        int nd = l >> 4;          // node within wave
        int slot = (l >> 2) & 3;  // edge slot
        int chunk = l & 3;        // 8-half feature chunk
        int node = (bid << 4) + (wv << 2) + nd;
        unsigned pk = (unsigned)protRP[node];
        int s0 = (int)(pk & 0x1FFFFFu);
        int deg = (int)(pk >> 21);
        float edv = ed_[node];
        float selfw = __expf(leaky(es[node] + edv));
        float acc[8] = {0.f,0.f,0.f,0.f,0.f,0.f,0.f,0.f};
        float den = (slot == 0) ? selfw : 0.f;
        if (slot == 0) {
            HF8 r; r.f4 = *(const float4*)&x32[(size_t)node * 32 + (chunk << 3)];
            #pragma unroll
            for (int i = 0; i < 8; i++) acc[i] = selfw * (float)r.h[i];
        }
        for (int base = 0; base < deg; base += 4) {
            int s = base + slot;
            if (s < deg) {
                int u = protCOL[s0 + s];
                float w = __expf(leaky(es[u] + edv));
                HF8 r; r.f4 = *(const float4*)&x32[(size_t)u * 32 + (chunk << 3)];
                #pragma unroll
                for (int i = 0; i < 8; i++) acc[i] += w * (float)r.h[i];
                den += w;
            }
        }
        #pragma unroll
        for (int m = 4; m <= 8; m <<= 1) {
            #pragma unroll
            for (int i = 0; i < 8; i++) acc[i] += __shfl_xor(acc[i], m, 64);
            den += __shfl_xor(den, m, 64);
        }
        float inv = 1.f / den;
        if (slot == 0) {
            float4 v0 = make_float4(acc[0]*inv, acc[1]*inv, acc[2]*inv, acc[3]*inv);
            if (chunk < 2) {
                float4 v1 = make_float4(acc[4]*inv, acc[5]*inv, acc[6]*inv, acc[7]*inv);
                *(float4*)&aggP[(size_t)node * 20 + (chunk << 3)]     = v0;
                *(float4*)&aggP[(size_t)node * 20 + (chunk << 3) + 4] = v1;
            } else if (chunk == 2) {
                *(float4*)&aggP[(size_t)node * 20 + 16] = v0;
            }
        }
    }
}

// ================= merged MLP via MFMA (f16 16x16x32), 64 nodes/block, 4 waves =================
template<int D, int ATT, int SCALE>
__device__ __forceinline__ void mlp_mfma(__half* smemh, int bid, int tid,
                                         const float* __restrict__ agg, const float* __restrict__ W1,
                                         const float* __restrict__ b1, const float* __restrict__ W2,
                                         const float* __restrict__ as_, const float* __restrict__ ad_,
                                         __half* __restrict__ hout, float* __restrict__ es,
                                         float* __restrict__ ed_, const float* __restrict__ dinv,
                                         int n){
    __half* W1Ts = smemh;            // 64*40
    __half* W2Ts = smemh + 2560;     // 64*72
    __half* AinS = smemh + 7168;     // 4*16*40
    __half* X1S  = smemh + 9728;     // 4*16*72
    int lane = tid & 63, w = tid >> 6;
    int c = lane & 15, g = lane >> 4;
    int node0 = bid * 64 + w * 16;

    for (int idx = tid; idx < 2048; idx += 256) {
        int k = idx >> 6, col = idx & 63;
        W1Ts[col * 40 + k] = __float2half(k < D ? W1[k * 64 + col] : 0.f);
    }
    for (int idx = tid; idx < 4096; idx += 256) {
        int k = idx >> 6, col = idx & 63;
        W2Ts[col * 72 + k] = __float2half(W2[k * 64 + col]);
    }
    {
        float4 z4 = make_float4(0.f, 0.f, 0.f, 0.f);
        float4* az = (float4*)(AinS + w * 640);
        for (int i = lane; i < 80; i += 64) az[i] = z4;
        int lim = 16 * D;
        if (ATT) { int rem = n - node0; if (rem < 0) rem = 0; if (rem < 16) lim = rem * D; }
        const float* aw = agg + (size_t)node0 * D;
        for (int idx = lane; idx < lim; idx += 64) {
            int r = idx / D, k = idx - r * D;
            AinS[w * 640 + r * 40 + k] = __float2half(aw[idx]);
        }
    }
    __syncthreads();

    f32x4 zz = {0.f, 0.f, 0.f, 0.f};
    f16x8 a1 = *(const f16x8*)&AinS[w * 640 + c * 40 + 8 * g];
    #pragma unroll
    for (int t = 0; t < 4; t++) {
        f16x8 b = *(const f16x8*)&W1Ts[(16 * t + c) * 40 + 8 * g];
        f32x4 h = __builtin_amdgcn_mfma_f32_16x16x32_f16(a1, b, zz, 0, 0, 0);
        float bv = b1[16 * t + c];
        #pragma unroll
        for (int r = 0; r < 4; r++) {
            float v = fmaxf(h[r] + bv, 0.f);
            X1S[w * 1152 + (4 * g + r) * 72 + 16 * t + c] = __float2half(v);
        }
    }
    __syncthreads();

    f32x4 acc[4];
    #pragma unroll
    for (int t = 0; t < 4; t++) acc[t] = zz;
    #pragma unroll
    for (int kt = 0; kt < 2; kt++) {
        f16x8 a = *(const f16x8*)&X1S[w * 1152 + c * 72 + 32 * kt + 8 * g];
        #pragma unroll
        for (int t = 0; t < 4; t++) {
            f16x8 b = *(const f16x8*)&W2Ts[(16 * t + c) * 72 + 32 * kt + 8 * g];
            acc[t] = __builtin_amdgcn_mfma_f32_16x16x32_f16(a, b, acc[t], 0, 0, 0);
        }
    }

    if (ATT) {
        float asv[4], adv[4];
        #pragma unroll
        for (int t = 0; t < 4; t++) { asv[t] = as_[16 * t + c]; adv[t] = ad_[16 * t + c]; }
        #pragma unroll
        for (int r = 0; r < 4; r++) {
            float xa = 0.f, ya = 0.f;
            #pragma unroll
            for (int t = 0; t < 4; t++) { xa += acc[t][r] * asv[t]; ya += acc[t][r] * adv[t]; }
            #pragma unroll
            for (int m = 1; m < 16; m <<= 1) { xa += __shfl_xor(xa, m, 16); ya += __shfl_xor(ya, m, 16); }
            int nd = node0 + 4 * g + r;
            if (c == 0 && nd < n) { es[nd] = xa; ed_[nd] = ya; }
        }
    }
    if (SCALE) {
        #pragma unroll
        for (int r = 0; r < 4; r++) {
            float dd = dinv[node0 + 4 * g + r];
            #pragma unroll
            for (int t = 0; t < 4; t++) acc[t][r] *= dd;
        }
    }

    #pragma unroll
    for (int t = 0; t < 4; t++) {
        #pragma unroll
        for (int r = 0; r < 4; r++)
            X1S[w * 1152 + (4 * g + r) * 72 + 16 * t + c] = __float2half(acc[t][r]);
    }
    __syncthreads();
    int rr = lane >> 2, seg = lane & 3;
    union { f16x8 h; float4 f; } o;
    o.h = *(const f16x8*)&X1S[w * 1152 + rr * 72 + seg * 16];
    int nd = node0 + rr;
    if (!ATT || nd < n)
        *(float4*)&hout[(size_t)nd * 64 + seg * 16] = o.f;
}

__global__ void k_mlp2(const float* __restrict__ aggM, const float* __restrict__ gcn_w1,
                       const float* __restrict__ gcn_b1, const float* __restrict__ gcn_w2,
                       __half* __restrict__ h2hM, const float* __restrict__ dinvM,
                       const float* __restrict__ aggP, const float* __restrict__ gat_w1,
                       const float* __restrict__ gat_b1, const float* __restrict__ gat_w2,
                       const float* __restrict__ as2, const float* __restrict__ ad2,
                       __half* __restrict__ h2hP, float* __restrict__ es, float* __restrict__ ed_){
    __shared__ __attribute__((aligned(16))) __half smemh[14336];   // 28672 B -> 5 blocks/CU
    if (blockIdx.x < NM/64)
        mlp_mfma<6, 0, 1>(smemh, blockIdx.x, threadIdx.x, aggM, gcn_w1, gcn_b1, gcn_w2,
                          nullptr, nullptr, h2hM, nullptr, nullptr, dinvM, NM);
    else
        mlp_mfma<20, 1, 0>(smemh, blockIdx.x - NM/64, threadIdx.x, aggP, gat_w1, gat_b1, gat_w2,
                           as2, ad2, h2hP, es, ed_, nullptr, NP);
}

// ================= L2 phase =================
// prot pooled output = sum_u coef_u * hh_u (source-sum collapse).
//   k_l2g2 prot part: den_v per node via dst-CSR (4B es gathers); writes denEd[v]=(1/den_v, ed_v)
//   k_coef2: per-SOURCE gather over src-CSR: coef_u = selfw_u/den_u + sum_v exp(leaky(es_u+ed_v))/den_v
//   k_psum: coalesced stream of hhP weighted by coefP -> psumP partials
// mol part keeps the row gather (per-graph pooling, edges cross graphs).
__global__ void k_l2g2(const int* __restrict__ protRP, const int* __restrict__ protCOL,
                       const float* __restrict__ es, const float* __restrict__ ed_,
                       float2* __restrict__ denEd,
                       const int* __restrict__ molRP, const int* __restrict__ molCOL,
                       const __half* __restrict__ hhM, const float* __restrict__ dinv,
                       const int* __restrict__ batch, float* __restrict__ gsum){
    __shared__ float sb[4][64];
    __shared__ int gidS[4];
    int tid = threadIdx.x;
    if (blockIdx.x < NP/16) {
        // prot den: 16 nodes/block, 16 lanes/node, es-only gather
        int node = (blockIdx.x << 4) + (tid >> 4);
        int l16 = tid & 15;
        unsigned pk = (unsigned)protRP[node];
        int s0 = (int)(pk & 0x1FFFFFu);
        int deg = (int)(pk >> 21);
        float edv = ed_[node];
        float den = 0.f;
        for (int s = l16; s < deg; s += 16) {
            int u = protCOL[s0 + s];
            den += __expf(leaky(es[u] + edv));
        }
        #pragma unroll
        for (int m = 1; m < 16; m <<= 1) den += __shfl_xor(den, m, 16);
        if (l16 == 0) {
            float selfw = __expf(leaky(es[node] + edv));
            denEd[node] = make_float2(1.f / (den + selfw), edv);
        }
    } else {
        int bid = blockIdx.x - NP/16;
        int wv = tid >> 6, l = tid & 63, g = l >> 3, q = l & 7;
        int node = (bid << 2) + wv;
        unsigned pk = (unsigned)molRP[node];
        int s0 = (int)(pk & 0xFFFFFu);
        int deg = (int)(pk >> 20);
        float acc[8] = {0.f,0.f,0.f,0.f,0.f,0.f,0.f,0.f};
        if (g == 0) {
            HF8 r; r.f4 = *(const float4*)&hhM[(size_t)node * 64 + (q << 3)];
            #pragma unroll
            for (int i = 0; i < 8; i++) acc[i] = (float)r.h[i];
        }
        for (int base = 0; base < deg; base += 8) {
            int s = base + g;
            if (s < deg) {
                int u = molCOL[s0 + s];
                HF8 r; r.f4 = *(const float4*)&hhM[(size_t)u * 64 + (q << 3)];
                #pragma unroll
                for (int i = 0; i < 8; i++) acc[i] += (float)r.h[i];
            }
        }
        #pragma unroll
        for (int m = 8; m <= 32; m <<= 1) {
            #pragma unroll
            for (int i = 0; i < 8; i++) acc[i] += __shfl_xor(acc[i], m, 64);
        }
        if (g == 0) {
            float sc = dinv[node];
            #pragma unroll
            for (int i = 0; i < 8; i++) sb[wv][(q << 3) + i] = acc[i] * sc;
        }
        if (l == 0) gidS[wv] = batch[node];
        __syncthreads();
        if (tid < 64) {
            int g0 = gidS[0];
            if (gidS[1] == g0 && gidS[2] == g0 && gidS[3] == g0) {
                float s = sb[0][tid] + sb[1][tid] + sb[2][tid] + sb[3][tid];
                atomicAdd(&gsum[(g0 << 6) + tid], s);
            } else {
                #pragma unroll
                for (int w2 = 0; w2 < 4; w2++)
                    atomicAdd(&gsum[(gidS[w2] << 6) + tid], sb[w2][tid]);
            }
        }
    }
}

// ---------------- coef pass: per-source gather over src-CSR, zero atomics ----------------
__global__ void k_coef2(const int* __restrict__ srcRP, const int* __restrict__ srcCOL,
                        const float* __restrict__ es, const float2* __restrict__ denEd,
                        float* __restrict__ coefP){
    int tid = threadIdx.x;
    int node = blockIdx.x * 32 + (tid >> 3);   // 32 nodes/block, 8 lanes/node
    int l8 = tid & 7;
    unsigned pk = (unsigned)srcRP[node];
    int s0 = (int)(pk & 0x1FFFFFu);
    int deg = (int)(pk >> 21);
    float esu = es[node];
    float sum = 0.f;
    for (int s = l8; s < deg; s += 8) {
        int v = srcCOL[s0 + s];
        float2 de = denEd[v];
        sum += __expf(leaky(esu + de.y)) * de.x;
    }
    #pragma unroll
    for (int m = 1; m < 8; m <<= 1) sum += __shfl_xor(sum, m, 8);
    if (l8 == 0) {
        float2 du = denEd[node];
        coefP[node] = __expf(leaky(esu + du.y)) * du.x + sum;
    }
}

// ---------------- psum pass: coalesced stream, psum = sum_u coefP[u]*hh_u ----------------
__global__ void k_psum(const float* __restrict__ coefP, const __half* __restrict__ hhP,
                       float* __restrict__ psumP){
    __shared__ float red[4][64];
    int tid = threadIdx.x;
    int wv = tid >> 6, l = tid & 63, g = l >> 3, q = l & 7;
    float acc[8] = {0.f,0.f,0.f,0.f,0.f,0.f,0.f,0.f};
    for (int base = blockIdx.x * 32; base < NP; base += 512 * 32) {
        int u = base + (wv << 3) + g;
        if (u < NP) {
            float cf = coefP[u];
            HF8 r; r.f4 = *(const float4*)&hhP[(size_t)u * 64 + (q << 3)];
            #pragma unroll
            for (int i = 0; i < 8; i++) acc[i] += cf * (float)r.h[i];
        }
    }
    #pragma unroll
    for (int m = 8; m <= 32; m <<= 1) {
        #pragma unroll
        for (int i = 0; i < 8; i++) acc[i] += __shfl_xor(acc[i], m, 64);
    }
    if (g == 0) {
        #pragma unroll
        for (int i = 0; i < 8; i++) red[wv][(q << 3) + i] = acc[i];
    }
    __syncthreads();
    if (tid < 64) {
        float s = red[0][tid] + red[1][tid] + red[2][tid] + red[3][tid];
        atomicAdd(&psumP[((blockIdx.x & 63) << 6) + tid], s);
    }
}

// ---------------- fused classifier (reduces psumP, applies layer-2 biases) ----------------
__global__ void k_cls(const float* __restrict__ gsum, const int* __restrict__ gstart,
                      const int* __restrict__ gend, const float* __restrict__ psumP,
                      const float* __restrict__ bg, const float* __restrict__ bp,
                      const float* __restrict__ W1, const float* __restrict__ b1,
                      const float* __restrict__ w2, const float* __restrict__ b2,
                      float* __restrict__ out){
    __shared__ float W1s[128 * 64];
    __shared__ float pv[64], bgs[64];
    int tid = threadIdx.x;
    for (int k = tid; k < 128 * 64; k += 256) W1s[k] = W1[k];
    if (tid < 64) {
        float s = 0.f;
        for (int sl = 0; sl < 64; sl++) s += psumP[(sl << 6) + tid];
        pv[tid] = s * (1.0f / (float)NP) + bp[tid];
        bgs[tid] = bg[tid];
    }
    __syncthreads();
    int g = blockIdx.x * 4 + (tid >> 6);
    int j = tid & 63;
    float cntf = (float)(gend[g] - gstart[g]);
    float inv = 1.0f / fmaxf(cntf, 1.0f);
    float acc = b1[j];
    #pragma unroll 8
    for (int k = 0; k < 64; k++) acc += (gsum[g * 64 + k] * inv + bgs[k]) * W1s[k * 64 + j];
    #pragma unroll 8
    for (int k = 0; k < 64; k++) acc += pv[k] * W1s[(64 + k) * 64 + j];
    float v = fmaxf(acc, 0.f) * w2[j];
    #pragma unroll
    for (int off = 32; off > 0; off >>= 1) v += __shfl_down(v, off, 64);
    if (j == 0) out[g] = 1.0f / (1.0f + expf(-(v + b2[0])));
}

extern "C" void kernel_launch(void* const* d_in, const int* in_sizes, int n_in,
                              void* d_out, int out_size, void* d_ws, size_t ws_size,
                              hipStream_t stream) {
    const float* mol_x   = (const float*)d_in[0];
    const int*   mol_ei  = (const int*)d_in[1];
    const int*   mol_bat = (const int*)d_in[2];
    const float* prot_x  = (const float*)d_in[3];
    const int*   prot_ei = (const int*)d_in[4];
    const float* gcn_w1  = (const float*)d_in[5];
    const float* gcn_b1  = (const float*)d_in[6];
    const float* gcn_w2  = (const float*)d_in[7];
    const float* gcn_b2  = (const float*)d_in[8];
    const float* gat_w1  = (const float*)d_in[9];
    const float* gat_as1 = (const float*)d_in[10];
    const float* gat_ad1 = (const float*)d_in[11];
    const float* gat_b1  = (const float*)d_in[12];
    const float* gat_w2  = (const float*)d_in[13];
    const float* gat_as2 = (const float*)d_in[14];
    const float* gat_ad2 = (const float*)d_in[15];
    const float* gat_b2  = (const float*)d_in[16];
    const float* cls_w1  = (const float*)d_in[17];
    const float* cls_b1  = (const float*)d_in[18];
    const float* cls_w2  = (const float*)d_in[19];
    const float* cls_b2  = (const float*)d_in[20];
    float* out = (float*)d_out;

    float* ws_f = (float*)d_ws;

    // ---- persistent tail ----
    float* T       = ws_f + 16777216;
    float* gsum    = T;                       // 262,144 floats (zeroed)
    int*   gstart  = (int*)(T + 262144);      // 4,096 (zeroed)
    int*   gend    = (int*)(T + 266240);      // 4,096 (zeroed)
    int*   coarseM = (int*)(T + 270400);      // 512 (zeroed)
    int*   coarseP = (int*)(T + 270912);      // 512 (zeroed)
    int*   cstartM = (int*)(T + 271424);      // 513
    int*   cursorM = (int*)(T + 271937);      // 512
    int*   cstartP = (int*)(T + 272449);      // 513
    int*   cursorP = (int*)(T + 272962);      // 512
    float* psumP   = T + 273474;              // 64x64 (zeroed)
    int*   coarseS = (int*)(T + 277632);      // 512 (zeroed by extended memset)
    int*   cstartS = (int*)(T + 278144);      // 513
    int*   cursorS = (int*)(T + 278657);      // 512  -> tail ends T+279,169

    // ---- early CSR staging (dead after k_fine2) ----
    unsigned* bufM = (unsigned*)ws_f;                    // [0, 524,288)
    unsigned* bufP = (unsigned*)(ws_f + 524352);         // [524,352, 2,124,416)
    unsigned* bufS = (unsigned*)(ws_f + 2124480);        // [2,124,480, 3,724,480) dead after fine2

    // ---- overlapping phase regions (offsets in floats) ----
    // [0, 3,200,000):          h2hP (fp16, NP*64) -- mlp2 -> psum (bufM/bufP dead by then)
    // [2,124,480, 3,724,480):  x32h (fp16, NP*32) -- prep2 -> l1g2 (bufS dead by then; under h2hP tail? no:
    //                          x32h written AFTER fine2, h2hP written AFTER l1g2... x32h and h2hP overlap
    //                          [2,124,480..3,200,000): x32h dead after l1g2, h2hP written at mlp2 (later). OK.
    // [4,194,304, 5,794,304):  srcCOL (EP ints) -- fine2 -> coef2 (vacated x32h slot)
    // [5,794,304, 7,794,304):  aggP -- l1g2 -> mlp2; coefP reuses [5,894,304..) after mlp2
    // [7,794,304, 7,894,304):  es ; [7,894,304, 7,994,304): ed
    // [7,994,304, 8,194,304):  denEd (float2 NP) -- l2g2 -> coef2
    // [8,194,304, 8,294,304):  srcRP (NP ints) -- fine2 -> coef2
    // [8,388,608, 12,582,912): h2hM (fp16, NM*64) -- mlp2 -> l2g2 (mol)
    __half*   h2hP      = (__half*)ws_f;
    __half*   x32h      = (__half*)(ws_f + 2124480);
    int*      srcCOL    = (int*)(ws_f + 4194304);
    float*    aggP      = ws_f + 5794304;
    float*    coefP     = ws_f + 5894304;
    float*    es        = ws_f + 7794304;
    float*    ed_       = ws_f + 7894304;
    float2*   denEd     = (float2*)(ws_f + 7994304);
    int*      srcRP     = (int*)(ws_f + 8194304);
    __half*   h2hM      = (__half*)(ws_f + 8388608);
    int*      molCOL    = (int*)(ws_f + 12582912);       // EM+64 -> 13,107,264
    int*      molRP     = (int*)(ws_f + 13107264);       // NM -> 13,238,336 (+pad)
    float*    dinvM     = ws_f + 13238352;               // NM -> 13,369,424 (+pad)
    __half*   x8h       = (__half*)(ws_f + 13369440);    // NM*8 halves -> 13,893,728 (+pad)
    float*    aggM      = ws_f + 13893792;               // NM*6 -> 14,680,224 (+pad)
    int*      protCOL   = (int*)(ws_f + 14680256);       // EP+64 -> 16,280,320
    int*      protRP    = (int*)(ws_f + 16280320);       // NP -> 16,380,320

    // single upfront zero of gsum..cursorS (contiguous tail region)
    (void)hipMemsetAsync(gsum, 0, (size_t)279169 * sizeof(float), stream);

    // ================= merged CSR build (mol-dst + prot-dst + prot-src) =================
    k_hist2<<<256 + 391 + 391, 256, 0, stream>>>(mol_ei + EM, prot_ei + EP, prot_ei,
                                                 coarseM, coarseP, coarseS);
    k_scan2<<<3, 512, 0, stream>>>(coarseM, cstartM, cursorM, coarseP, cstartP, cursorP,
                                   coarseS, cstartS, cursorS);
    k_part2<<<128 + 391 + 391, 256, 0, stream>>>(mol_ei, cursorM, bufM, prot_ei, cursorP, bufP,
                                                 cursorS, bufS);
    k_fine2<<<512 + 391 + 391, 256, 0, stream>>>(bufM, cstartM, molRP, molCOL, dinvM,
                                                 bufP, cstartP, protRP, protCOL,
                                                 bufS, cstartS, srcRP, srcCOL);

    // ================= merged preps =================
    k_prep2<<<512 + 512 + 391, 256, 0, stream>>>(mol_x, dinvM, x8h, mol_bat, gstart, gend,
                                                 prot_x, gat_w1, gat_as1, gat_ad1, x32h, es, ed_);

    // ================= merged L1 gathers =================
    k_l1g2<<<NM/32 + NP/16, 256, 0, stream>>>(molRP, molCOL, x8h, dinvM, aggM,
                                              protRP, protCOL, x32h, es, ed_, aggP);

    // ================= merged MLPs (MFMA, 64 nodes/block) =================
    k_mlp2<<<NM/64 + cdiv(NP, 64), 256, 0, stream>>>(aggM, gcn_w1, gcn_b1, gcn_w2, h2hM, dinvM,
                                                     aggP, gat_w1, gat_b1, gat_w2, gat_as2, gat_ad2,
                                                     h2hP, es, ed_);

    // ================= L2 phase: mol gather + prot den -> coef gather -> psum =================
    k_l2g2<<<NP/16 + NM/4, 256, 0, stream>>>(protRP, protCOL, es, ed_, denEd,
                                             molRP, molCOL, h2hM, dinvM, mol_bat, gsum);
    k_coef2<<<NP/32, 256, 0, stream>>>(srcRP, srcCOL, es, denEd, coefP);
    k_psum<<<512, 256, 0, stream>>>(coefP, h2hP, psumP);

    // ================= classifier (reduces psumP, applies layer-2 biases) =================
    k_cls<<<NG/4, 256, 0, stream>>>(gsum, gstart, gend, psumP, gcn_b2, gat_b2,
                                    cls_w1, cls_b1, cls_w2, cls_b2, out);
}

// Round 7
// 305.606 us; speedup vs baseline: 1.2822x; 1.0734x over previous
//
#include <hip/hip_runtime.h>
#include <hip/hip_fp16.h>

#define NM 131072   // mol nodes
#define EM 524288   // mol edges
#define NG 4096     // graphs
#define DM 6        // mol in dim
#define NP 100000   // prot nodes
#define EP 1600000  // prot edges
#define DP 20       // prot in dim

static inline int cdiv(int a, int b){ return (a + b - 1) / b; }

__device__ __forceinline__ float leaky(float x){ return x > 0.f ? x : 0.2f * x; }

union H8 { float4 f4; __half2 h2[4]; };
union HF8 { float4 f4; _Float16 h[8]; };

typedef _Float16 f16x8 __attribute__((ext_vector_type(8)));
typedef float    f32x4 __attribute__((ext_vector_type(4)));

// ================= merged bucketed CSR build: mol-dst + prot-dst + prot-src =================
__global__ void k_hist2(const int* __restrict__ dstM, const int* __restrict__ dstP,
                        const int* __restrict__ srcP,
                        int* __restrict__ coarseM, int* __restrict__ coarseP,
                        int* __restrict__ coarseS){
    __shared__ int lh[512];
    int t = threadIdx.x;
    const int* dst; int* coarse; int K, E, base, chunk;
    if (blockIdx.x < 256)      { dst = dstM; coarse = coarseM; K = 512; E = EM; chunk = 2048; base = blockIdx.x * 2048; }
    else if (blockIdx.x < 647) { dst = dstP; coarse = coarseP; K = 391; E = EP; chunk = 4096; base = (blockIdx.x - 256) * 4096; }
    else                       { dst = srcP; coarse = coarseS; K = 391; E = EP; chunk = 4096; base = (blockIdx.x - 647) * 4096; }
    for (int i = t; i < K; i += 256) lh[i] = 0;
    __syncthreads();
    int end = min(base + chunk, E);
    for (int e = base + t; e < end; e += 256)
        atomicAdd(&lh[dst[e] >> 8], 1);
    __syncthreads();
    for (int i = t; i < K; i += 256)
        if (lh[i]) atomicAdd(&coarse[i], lh[i]);
}

__global__ void k_scan2(const int* __restrict__ coarseM, int* __restrict__ cstartM, int* __restrict__ cursorM,
                        const int* __restrict__ coarseP, int* __restrict__ cstartP, int* __restrict__ cursorP,
                        const int* __restrict__ coarseS, int* __restrict__ cstartS, int* __restrict__ cursorS){
    const int* coarse; int* cstart; int* cursor; int K;
    if (blockIdx.x == 0)      { coarse = coarseM; cstart = cstartM; cursor = cursorM; K = 512; }
    else if (blockIdx.x == 1) { coarse = coarseP; cstart = cstartP; cursor = cursorP; K = 391; }
    else                      { coarse = coarseS; cstart = cstartS; cursor = cursorS; K = 391; }
    int t = threadIdx.x, lane = t & 63, wid = t >> 6;
    int v0 = (t < K) ? coarse[t] : 0;
    int v = v0;
    #pragma unroll
    for (int off = 1; off < 64; off <<= 1) {
        int x = __shfl_up(v, off, 64);
        if (lane >= off) v += x;
    }
    __shared__ int ws[8];
    if (lane == 63) ws[wid] = v;
    __syncthreads();
    int add = 0;
    for (int w = 0; w < wid; w++) add += ws[w];
    int excl = v + add - v0;
    if (t < K) { cstart[t] = excl; cursor[t] = excl; }
    if (t == K - 1) cstart[K] = excl + v0;
}

__global__ void k_part2(const int* __restrict__ eiM, int* __restrict__ cursorM, unsigned* __restrict__ bufM,
                        const int* __restrict__ eiP, int* __restrict__ cursorP, unsigned* __restrict__ bufP,
                        int* __restrict__ cursorS, unsigned* __restrict__ bufS){
    __shared__ int lh[512];
    __shared__ int lbase[512];
    const int* ei; int* cursor; unsigned* buf; int E, K, base, sw;
    if (blockIdx.x < 128)      { ei = eiM; cursor = cursorM; buf = bufM; E = EM; K = 512; base = blockIdx.x * 4096; sw = 0; }
    else if (blockIdx.x < 519) { ei = eiP; cursor = cursorP; buf = bufP; E = EP; K = 391; base = (blockIdx.x - 128) * 4096; sw = 0; }
    else                       { ei = eiP; cursor = cursorS; buf = bufS; E = EP; K = 391; base = (blockIdx.x - 519) * 4096; sw = 1; }
    int t = threadIdx.x;
    for (int i = t; i < K; i += 256) lh[i] = 0;
    __syncthreads();
    int end = min(base + 4096, E);
    unsigned pay[16]; int bslot[16];
    int cnt = 0;
    for (int e = base + t; e < end; e += 256) {
        int u = ei[e], v = ei[E + e];
        int key = sw ? u : v, oth = sw ? v : u;
        int b = key >> 8;
        int ls = atomicAdd(&lh[b], 1);
        pay[cnt] = ((unsigned)(key & 255) << 24) | (unsigned)oth;
        bslot[cnt] = (b << 13) | ls;
        cnt++;
    }
    __syncthreads();
    for (int i = t; i < K; i += 256)
        lbase[i] = lh[i] ? atomicAdd(&cursor[i], lh[i]) : 0;
    __syncthreads();
    for (int j = 0; j < cnt; j++) {
        int b = bslot[j] >> 13, ls = bslot[j] & 8191;
        buf[lbase[b] + ls] = pay[j];
    }
}

__global__ void k_fine2(const unsigned* __restrict__ bufM, const int* __restrict__ cstartM,
                        int* __restrict__ molRP, int* __restrict__ molCOL, float* __restrict__ dinv,
                        const unsigned* __restrict__ bufP, const int* __restrict__ cstartP,
                        int* __restrict__ protRP, int* __restrict__ protCOL,
                        const unsigned* __restrict__ bufS, const int* __restrict__ cstartS,
                        int* __restrict__ srcRP, int* __restrict__ srcCOL){
    int t = threadIdx.x;
    int k; const unsigned* buf; const int* cstart; int* rp; int* col; int n, OB, dv;
    if (blockIdx.x < 512)      { k = blockIdx.x;       buf = bufM; cstart = cstartM; rp = molRP;  col = molCOL;  n = NM; OB = 20; dv = 1; }
    else if (blockIdx.x < 903) { k = blockIdx.x - 512; buf = bufP; cstart = cstartP; rp = protRP; col = protCOL; n = NP; OB = 21; dv = 0; }
    else                       { k = blockIdx.x - 903; buf = bufS; cstart = cstartS; rp = srcRP;  col = srcCOL;  n = NP; OB = 21; dv = 0; }
    int start = cstart[k], end = cstart[k + 1];
    __shared__ int cnt[256];
    __shared__ int cur[256];
    cnt[t] = 0;
    __syncthreads();
    for (int p = start + t; p < end; p += 256)
        atomicAdd(&cnt[buf[p] >> 24], 1);
    __syncthreads();
    int v0 = cnt[t];
    int lane = t & 63, wid = t >> 6;
    int v = v0;
    #pragma unroll
    for (int off = 1; off < 64; off <<= 1) {
        int x = __shfl_up(v, off, 64);
        if (lane >= off) v += x;
    }
    __shared__ int ws[4];
    if (lane == 63) ws[wid] = v;
    __syncthreads();
    int add = 0;
    for (int w = 0; w < wid; w++) add += ws[w];
    int excl = v + add - v0;
    int ofs = start + excl;
    cur[t] = ofs;
    int idx = (k << 8) + t;
    if (idx < n) {
        rp[idx] = (int)((unsigned)ofs | ((unsigned)v0 << OB));
        if (dv) dinv[idx] = rsqrtf((float)(v0 + 1));
    }
    __syncthreads();
    for (int p = start + t; p < end; p += 256) {
        unsigned pk = buf[p];
        int slot = atomicAdd(&cur[pk >> 24], 1);
        col[slot] = (int)(pk & 0xFFFFFFu);
    }
}

// ================= merged prep: molprep (512) + segbounds (512) + prot prep (391) =================
__global__ void k_prep2(const float* __restrict__ mol_x, const float* __restrict__ dinv,
                        __half* __restrict__ x8, const int* __restrict__ batch,
                        int* __restrict__ gstart, int* __restrict__ gend,
                        const float* __restrict__ prot_x, const float* __restrict__ W1,
                        const float* __restrict__ as_, const float* __restrict__ ad_,
                        __half* __restrict__ x32, float* __restrict__ es,
                        float* __restrict__ ed_){
    __shared__ float vas[20], vds[20];
    int b = blockIdx.x, t = threadIdx.x;
    if (b < 512) {
        int i = b * 256 + t;
        float dd = dinv[i];
        H8 r;
        #pragma unroll
        for (int k = 0; k < 3; k++)
            r.h2[k] = __floats2half2_rn(dd * mol_x[i*6 + 2*k], dd * mol_x[i*6 + 2*k + 1]);
        r.h2[3] = __floats2half2_rn(0.f, 0.f);
        *(float4*)&x8[(size_t)i * 8] = r.f4;
    } else if (b < 1024) {
        int i = (b - 512) * 256 + t;
        int g = batch[i];
        if (i == 0 || batch[i - 1] != g) gstart[g] = i;
        if (i == NM - 1 || batch[i + 1] != g) gend[g] = i + 1;
    } else {
        if (t < 20) {
            float s = 0.f;
            for (int j = 0; j < 64; j++) s += W1[t * 64 + j] * as_[j];
            vas[t] = s;
        } else if (t >= 32 && t < 52) {
            int k = t - 32;
            float s = 0.f;
            for (int j = 0; j < 64; j++) s += W1[k * 64 + j] * ad_[j];
            vds[k] = s;
        }
        __syncthreads();
        int i = (b - 1024) * 256 + t;
        if (i >= NP) return;
        float xv[20];
        float s = 0.f, d = 0.f;
        #pragma unroll
        for (int k = 0; k < 20; k++) {
            xv[k] = prot_x[i*20 + k];
            s += xv[k] * vas[k]; d += xv[k] * vds[k];
        }
        es[i] = s; ed_[i] = d;
        H8 r0, r1, r2, rz;
        #pragma unroll
        for (int k = 0; k < 4; k++) r0.h2[k] = __floats2half2_rn(xv[2*k],   xv[2*k+1]);
        #pragma unroll
        for (int k = 0; k < 4; k++) r1.h2[k] = __floats2half2_rn(xv[8+2*k], xv[9+2*k]);
        r2.h2[0] = __floats2half2_rn(xv[16], xv[17]);
        r2.h2[1] = __floats2half2_rn(xv[18], xv[19]);
        r2.h2[2] = __floats2half2_rn(0.f, 0.f);
        r2.h2[3] = __floats2half2_rn(0.f, 0.f);
        rz.h2[0] = rz.h2[1] = rz.h2[2] = rz.h2[3] = __floats2half2_rn(0.f, 0.f);
        *(float4*)&x32[(size_t)i * 32]      = r0.f4;
        *(float4*)&x32[(size_t)i * 32 + 8]  = r1.f4;
        *(float4*)&x32[(size_t)i * 32 + 16] = r2.f4;
        *(float4*)&x32[(size_t)i * 32 + 24] = rz.f4;
    }
}

// ================= merged L1 gathers: mol (4096 blocks) + prot (6250 blocks, 4 nodes/wave) =================
__global__ void k_l1g2(const int* __restrict__ molRP, const int* __restrict__ molCOL,
                       const __half* __restrict__ x8, const float* __restrict__ dinv,
                       float* __restrict__ aggM,
                       const int* __restrict__ protRP, const int* __restrict__ protCOL,
                       const __half* __restrict__ x32, const float* __restrict__ es,
                       const float* __restrict__ ed_, float* __restrict__ aggP){
    __shared__ float ost[192];
    int tid = threadIdx.x;
    if (blockIdx.x < NM/32) {
        int bid = blockIdx.x;
        int wv = tid >> 6, l = tid & 63, g = l >> 3, q = l & 7;
        int node = (bid << 5) + (wv << 3) + g;
        unsigned pk = (unsigned)molRP[node];
        int s0 = (int)(pk & 0xFFFFFu);
        int deg = (int)(pk >> 20);
        float acc[6] = {0.f,0.f,0.f,0.f,0.f,0.f};
        if (q == 0) {
            HF8 r; r.f4 = *(const float4*)&x8[(size_t)node * 8];
            #pragma unroll
            for (int i = 0; i < 6; i++) acc[i] = (float)r.h[i];
        }
        for (int base = 0; base < deg; base += 8) {
            int s = base + q;
            if (s < deg) {
                int c = molCOL[s0 + s];
                HF8 r; r.f4 = *(const float4*)&x8[(size_t)c * 8];
                #pragma unroll
                for (int i = 0; i < 6; i++) acc[i] += (float)r.h[i];
            }
        }
        #pragma unroll
        for (int m = 1; m < 8; m <<= 1) {
            #pragma unroll
            for (int i = 0; i < 6; i++) acc[i] += __shfl_xor(acc[i], m, 8);
        }
        if (q == 0) {
            float dd = dinv[node];
            int slot = (wv << 3) + g;
            #pragma unroll
            for (int i = 0; i < 6; i++) ost[slot * 6 + i] = dd * acc[i];
        }
        __syncthreads();
        if (tid < 48)
            *(float4*)&aggM[(size_t)bid * 192 + (tid << 2)] = *(float4*)&ost[tid << 2];
    } else {
        // prot: 16 nodes/block, 4 nodes/wave; per node: 4 edge-slots x 4 feature-chunks
        int bid = blockIdx.x - NM/32;
        int wv = tid >> 6, l = tid & 63;
        int nd = l >> 4;          // node within wave
        int slot = (l >> 2) & 3;  // edge slot
        int chunk = l & 3;        // 8-half feature chunk
        int node = (bid << 4) + (wv << 2) + nd;
        unsigned pk = (unsigned)protRP[node];
        int s0 = (int)(pk & 0x1FFFFFu);
        int deg = (int)(pk >> 21);
        float edv = ed_[node];
        float selfw = __expf(leaky(es[node] + edv));
        float acc[8] = {0.f,0.f,0.f,0.f,0.f,0.f,0.f,0.f};
        float den = (slot == 0) ? selfw : 0.f;
        if (slot == 0) {
            HF8 r; r.f4 = *(const float4*)&x32[(size_t)node * 32 + (chunk << 3)];
            #pragma unroll
            for (int i = 0; i < 8; i++) acc[i] = selfw * (float)r.h[i];
        }
        for (int base = 0; base < deg; base += 4) {
            int s = base + slot;
            if (s < deg) {
                int u = protCOL[s0 + s];
                float w = __expf(leaky(es[u] + edv));
                HF8 r; r.f4 = *(const float4*)&x32[(size_t)u * 32 + (chunk << 3)];
                #pragma unroll
                for (int i = 0; i < 8; i++) acc[i] += w * (float)r.h[i];
                den += w;
            }
        }
        #pragma unroll
        for (int m = 4; m <= 8; m <<= 1) {
            #pragma unroll
            for (int i = 0; i < 8; i++) acc[i] += __shfl_xor(acc[i], m, 64);
            den += __shfl_xor(den, m, 64);
        }
        float inv = 1.f / den;
        if (slot == 0) {
            float4 v0 = make_float4(acc[0]*inv, acc[1]*inv, acc[2]*inv, acc[3]*inv);
            if (chunk < 2) {
                float4 v1 = make_float4(acc[4]*inv, acc[5]*inv, acc[6]*inv, acc[7]*inv);
                *(float4*)&aggP[(size_t)node * 20 + (chunk << 3)]     = v0;
                *(float4*)&aggP[(size_t)node * 20 + (chunk << 3) + 4] = v1;
            } else if (chunk == 2) {
                *(float4*)&aggP[(size_t)node * 20 + 16] = v0;
            }
        }
    }
}

// ================= merged MLP via MFMA (f16 16x16x32), 64 nodes/block, 4 waves =================
template<int D, int ATT, int SCALE>
__device__ __forceinline__ void mlp_mfma(__half* smemh, int bid, int tid,
                                         const float* __restrict__ agg, const float* __restrict__ W1,
                                         const float* __restrict__ b1, const float* __restrict__ W2,
                                         const float* __restrict__ as_, const float* __restrict__ ad_,
                                         __half* __restrict__ hout, float* __restrict__ es,
                                         float* __restrict__ ed_, const float* __restrict__ dinv,
                                         int n){
    __half* W1Ts = smemh;            // 64*40
    __half* W2Ts = smemh + 2560;     // 64*72
    __half* AinS = smemh + 7168;     // 4*16*40
    __half* X1S  = smemh + 9728;     // 4*16*72
    int lane = tid & 63, w = tid >> 6;
    int c = lane & 15, g = lane >> 4;
    int node0 = bid * 64 + w * 16;

    for (int idx = tid; idx < 2048; idx += 256) {
        int k = idx >> 6, col = idx & 63;
        W1Ts[col * 40 + k] = __float2half(k < D ? W1[k * 64 + col] : 0.f);
    }
    for (int idx = tid; idx < 4096; idx += 256) {
        int k = idx >> 6, col = idx & 63;
        W2Ts[col * 72 + k] = __float2half(W2[k * 64 + col]);
    }
    {
        float4 z4 = make_float4(0.f, 0.f, 0.f, 0.f);
        float4* az = (float4*)(AinS + w * 640);
        for (int i = lane; i < 80; i += 64) az[i] = z4;
        int lim = 16 * D;
        if (ATT) { int rem = n - node0; if (rem < 0) rem = 0; if (rem < 16) lim = rem * D; }
        const float* aw = agg + (size_t)node0 * D;
        for (int idx = lane; idx < lim; idx += 64) {
            int r = idx / D, k = idx - r * D;
            AinS[w * 640 + r * 40 + k] = __float2half(aw[idx]);
        }
    }
    __syncthreads();

    f32x4 zz = {0.f, 0.f, 0.f, 0.f};
    f16x8 a1 = *(const f16x8*)&AinS[w * 640 + c * 40 + 8 * g];
    #pragma unroll
    for (int t = 0; t < 4; t++) {
        f16x8 b = *(const f16x8*)&W1Ts[(16 * t + c) * 40 + 8 * g];
        f32x4 h = __builtin_amdgcn_mfma_f32_16x16x32_f16(a1, b, zz, 0, 0, 0);
        float bv = b1[16 * t + c];
        #pragma unroll
        for (int r = 0; r < 4; r++) {
            float v = fmaxf(h[r] + bv, 0.f);
            X1S[w * 1152 + (4 * g + r) * 72 + 16 * t + c] = __float2half(v);
        }
    }
    __syncthreads();

    f32x4 acc[4];
    #pragma unroll
    for (int t = 0; t < 4; t++) acc[t] = zz;
    #pragma unroll
    for (int kt = 0; kt < 2; kt++) {
        f16x8 a = *(const f16x8*)&X1S[w * 1152 + c * 72 + 32 * kt + 8 * g];
        #pragma unroll
        for (int t = 0; t < 4; t++) {
            f16x8 b = *(const f16x8*)&W2Ts[(16 * t + c) * 72 + 32 * kt + 8 * g];
            acc[t] = __builtin_amdgcn_mfma_f32_16x16x32_f16(a, b, acc[t], 0, 0, 0);
        }
    }

    if (ATT) {
        float asv[4], adv[4];
        #pragma unroll
        for (int t = 0; t < 4; t++) { asv[t] = as_[16 * t + c]; adv[t] = ad_[16 * t + c]; }
        #pragma unroll
        for (int r = 0; r < 4; r++) {
            float xa = 0.f, ya = 0.f;
            #pragma unroll
            for (int t = 0; t < 4; t++) { xa += acc[t][r] * asv[t]; ya += acc[t][r] * adv[t]; }
            #pragma unroll
            for (int m = 1; m < 16; m <<= 1) { xa += __shfl_xor(xa, m, 16); ya += __shfl_xor(ya, m, 16); }
            int nd = node0 + 4 * g + r;
            if (c == 0 && nd < n) { es[nd] = xa; ed_[nd] = ya; }
        }
    }
    if (SCALE) {
        #pragma unroll
        for (int r = 0; r < 4; r++) {
            float dd = dinv[node0 + 4 * g + r];
            #pragma unroll
            for (int t = 0; t < 4; t++) acc[t][r] *= dd;
        }
    }

    #pragma unroll
    for (int t = 0; t < 4; t++) {
        #pragma unroll
        for (int r = 0; r < 4; r++)
            X1S[w * 1152 + (4 * g + r) * 72 + 16 * t + c] = __float2half(acc[t][r]);
    }
    __syncthreads();
    int rr = lane >> 2, seg = lane & 3;
    union { f16x8 h; float4 f; } o;
    o.h = *(const f16x8*)&X1S[w * 1152 + rr * 72 + seg * 16];
    int nd = node0 + rr;
    if (!ATT || nd < n)
        *(float4*)&hout[(size_t)nd * 64 + seg * 16] = o.f;
}

__global__ void k_mlp2(const float* __restrict__ aggM, const float* __restrict__ gcn_w1,
                       const float* __restrict__ gcn_b1, const float* __restrict__ gcn_w2,
                       __half* __restrict__ h2hM, const float* __restrict__ dinvM,
                       const float* __restrict__ aggP, const float* __restrict__ gat_w1,
                       const float* __restrict__ gat_b1, const float* __restrict__ gat_w2,
                       const float* __restrict__ as2, const float* __restrict__ ad2,
                       __half* __restrict__ h2hP, float* __restrict__ es, float* __restrict__ ed_){
    __shared__ __attribute__((aligned(16))) __half smemh[14336];   // 28672 B -> 5 blocks/CU
    if (blockIdx.x < NM/64)
        mlp_mfma<6, 0, 1>(smemh, blockIdx.x, threadIdx.x, aggM, gcn_w1, gcn_b1, gcn_w2,
                          nullptr, nullptr, h2hM, nullptr, nullptr, dinvM, NM);
    else
        mlp_mfma<20, 1, 0>(smemh, blockIdx.x - NM/64, threadIdx.x, aggP, gat_w1, gat_b1, gat_w2,
                           as2, ad2, h2hP, es, ed_, nullptr, NP);
}

// ================= L2 phase =================
// prot den (dst-CSR, es-only gather) + mol L2 gather (4 nodes/wave, 2 slots x 8 chunks)
__global__ void k_l2g2(const int* __restrict__ protRP, const int* __restrict__ protCOL,
                       const float* __restrict__ es, const float* __restrict__ ed_,
                       float2* __restrict__ denEd,
                       const int* __restrict__ molRP, const int* __restrict__ molCOL,
                       const __half* __restrict__ hhM, const float* __restrict__ dinv,
                       const int* __restrict__ batch, float* __restrict__ gsum){
    __shared__ float sb[16][64];
    __shared__ int gidS[16];
    int tid = threadIdx.x;
    if (blockIdx.x < NP/16) {
        // prot den: 16 nodes/block, 16 lanes/node, es-only gather
        int node = (blockIdx.x << 4) + (tid >> 4);
        int l16 = tid & 15;
        unsigned pk = (unsigned)protRP[node];
        int s0 = (int)(pk & 0x1FFFFFu);
        int deg = (int)(pk >> 21);
        float edv = ed_[node];
        float den = 0.f;
        for (int s = l16; s < deg; s += 16) {
            int u = protCOL[s0 + s];
            den += __expf(leaky(es[u] + edv));
        }
        #pragma unroll
        for (int m = 1; m < 16; m <<= 1) den += __shfl_xor(den, m, 16);
        if (l16 == 0) {
            float selfw = __expf(leaky(es[node] + edv));
            denEd[node] = make_float2(1.f / (den + selfw), edv);
        }
    } else {
        // mol L2: 16 nodes/block, 4 nodes/wave; per node: 2 edge-slots x 8 feature-chunks
        int bid = blockIdx.x - NP/16;
        int wv = tid >> 6, l = tid & 63;
        int nd = l >> 4;          // node within wave (0..3)
        int slot = (l >> 3) & 1;  // edge slot (0..1)
        int q = l & 7;            // 8-half feature chunk
        int node = (bid << 4) + (wv << 2) + nd;
        int row = (wv << 2) + nd;
        unsigned pk = (unsigned)molRP[node];
        int s0 = (int)(pk & 0xFFFFFu);
        int deg = (int)(pk >> 20);
        float acc[8] = {0.f,0.f,0.f,0.f,0.f,0.f,0.f,0.f};
        if (slot == 0) {
            HF8 r; r.f4 = *(const float4*)&hhM[(size_t)node * 64 + (q << 3)];
            #pragma unroll
            for (int i = 0; i < 8; i++) acc[i] = (float)r.h[i];
        }
        for (int base = 0; base < deg; base += 2) {
            int s = base + slot;
            if (s < deg) {
                int u = molCOL[s0 + s];
                HF8 r; r.f4 = *(const float4*)&hhM[(size_t)u * 64 + (q << 3)];
                #pragma unroll
                for (int i = 0; i < 8; i++) acc[i] += (float)r.h[i];
            }
        }
        #pragma unroll
        for (int i = 0; i < 8; i++) acc[i] += __shfl_xor(acc[i], 8, 64);
        if (slot == 0) {
            float sc = dinv[node];
            #pragma unroll
            for (int i = 0; i < 8; i++) sb[row][(q << 3) + i] = acc[i] * sc;
        }
        if (l == (nd << 4)) gidS[row] = batch[node];
        __syncthreads();
        if (tid < 64) {
            int i = 0;
            while (i < 16) {
                int g0 = gidS[i];
                float s = sb[i][tid];
                int j = i + 1;
                while (j < 16 && gidS[j] == g0) { s += sb[j][tid]; j++; }
                atomicAdd(&gsum[(g0 << 6) + tid], s);
                i = j;
            }
        }
    }
}

// ---------------- fused coef+psum: per-source coef gather, then coalesced weighted row sum ----------------
__global__ void k_cps(const int* __restrict__ srcRP, const int* __restrict__ srcCOL,
                      const float* __restrict__ es, const float2* __restrict__ denEd,
                      const __half* __restrict__ hhP, float* __restrict__ psumP){
    __shared__ float red[4][64];
    int tid = threadIdx.x;
    int wv = tid >> 6, l = tid & 63;
    int node = blockIdx.x * 32 + (tid >> 3);   // 32 nodes/block, 8 lanes/node
    int l8 = tid & 7;
    unsigned pk = (unsigned)srcRP[node];
    int s0 = (int)(pk & 0x1FFFFFu);
    int deg = (int)(pk >> 21);
    float esu = es[node];
    float sum = 0.f;
    for (int s = l8; s < deg; s += 8) {
        int v = srcCOL[s0 + s];
        float2 de = denEd[v];
        sum += __expf(leaky(esu + de.y)) * de.x;
    }
    #pragma unroll
    for (int m = 1; m < 8; m <<= 1) sum += __shfl_xor(sum, m, 8);
    float2 du = denEd[node];
    float coef = __expf(leaky(esu + du.y)) * du.x + sum;   // all 8 lanes hold coef
    // coalesced weighted row accumulate
    HF8 r; r.f4 = *(const float4*)&hhP[(size_t)node * 64 + (l8 << 3)];
    float acc[8];
    #pragma unroll
    for (int i = 0; i < 8; i++) acc[i] = coef * (float)r.h[i];
    #pragma unroll
    for (int m = 8; m <= 32; m <<= 1) {
        #pragma unroll
        for (int i = 0; i < 8; i++) acc[i] += __shfl_xor(acc[i], m, 64);
    }
    if ((l >> 3) == 0) {
        #pragma unroll
        for (int i = 0; i < 8; i++) red[wv][(l8 << 3) + i] = acc[i];
    }
    __syncthreads();
    if (tid < 64) {
        float s = red[0][tid] + red[1][tid] + red[2][tid] + red[3][tid];
        atomicAdd(&psumP[((blockIdx.x & 63) << 6) + tid], s);
    }
}

// ---------------- fused classifier (reduces psumP, applies layer-2 biases) ----------------
__global__ void k_cls(const float* __restrict__ gsum, const int* __restrict__ gstart,
                      const int* __restrict__ gend, const float* __restrict__ psumP,
                      const float* __restrict__ bg, const float* __restrict__ bp,
                      const float* __restrict__ W1, const float* __restrict__ b1,
                      const float* __restrict__ w2, const float* __restrict__ b2,
                      float* __restrict__ out){
    __shared__ float W1s[128 * 64];
    __shared__ float pv[64], bgs[64];
    int tid = threadIdx.x;
    for (int k = tid; k < 128 * 64; k += 256) W1s[k] = W1[k];
    if (tid < 64) {
        float s = 0.f;
        for (int sl = 0; sl < 64; sl++) s += psumP[(sl << 6) + tid];
        pv[tid] = s * (1.0f / (float)NP) + bp[tid];
        bgs[tid] = bg[tid];
    }
    __syncthreads();
    int g = blockIdx.x * 4 + (tid >> 6);
    int j = tid & 63;
    float cntf = (float)(gend[g] - gstart[g]);
    float inv = 1.0f / fmaxf(cntf, 1.0f);
    float acc = b1[j];
    #pragma unroll 8
    for (int k = 0; k < 64; k++) acc += (gsum[g * 64 + k] * inv + bgs[k]) * W1s[k * 64 + j];
    #pragma unroll 8
    for (int k = 0; k < 64; k++) acc += pv[k] * W1s[(64 + k) * 64 + j];
    float v = fmaxf(acc, 0.f) * w2[j];
    #pragma unroll
    for (int off = 32; off > 0; off >>= 1) v += __shfl_down(v, off, 64);
    if (j == 0) out[g] = 1.0f / (1.0f + expf(-(v + b2[0])));
}

extern "C" void kernel_launch(void* const* d_in, const int* in_sizes, int n_in,
                              void* d_out, int out_size, void* d_ws, size_t ws_size,
                              hipStream_t stream) {
    const float* mol_x   = (const float*)d_in[0];
    const int*   mol_ei  = (const int*)d_in[1];
    const int*   mol_bat = (const int*)d_in[2];
    const float* prot_x  = (const float*)d_in[3];
    const int*   prot_ei = (const int*)d_in[4];
    const float* gcn_w1  = (const float*)d_in[5];
    const float* gcn_b1  = (const float*)d_in[6];
    const float* gcn_w2  = (const float*)d_in[7];
    const float* gcn_b2  = (const float*)d_in[8];
    const float* gat_w1  = (const float*)d_in[9];
    const float* gat_as1 = (const float*)d_in[10];
    const float* gat_ad1 = (const float*)d_in[11];
    const float* gat_b1  = (const float*)d_in[12];
    const float* gat_w2  = (const float*)d_in[13];
    const float* gat_as2 = (const float*)d_in[14];
    const float* gat_ad2 = (const float*)d_in[15];
    const float* gat_b2  = (const float*)d_in[16];
    const float* cls_w1  = (const float*)d_in[17];
    const float* cls_b1  = (const float*)d_in[18];
    const float* cls_w2  = (const float*)d_in[19];
    const float* cls_b2  = (const float*)d_in[20];
    float* out = (float*)d_out;

    float* ws_f = (float*)d_ws;

    // ---- persistent tail ----
    float* T       = ws_f + 16777216;
    float* gsum    = T;                       // 262,144 floats (zeroed)
    int*   gstart  = (int*)(T + 262144);      // 4,096 (zeroed)
    int*   gend    = (int*)(T + 266240);      // 4,096 (zeroed)
    int*   coarseM = (int*)(T + 270400);      // 512 (zeroed)
    int*   coarseP = (int*)(T + 270912);      // 512 (zeroed)
    int*   cstartM = (int*)(T + 271424);      // 513
    int*   cursorM = (int*)(T + 271937);      // 512
    int*   cstartP = (int*)(T + 272449);      // 513
    int*   cursorP = (int*)(T + 272962);      // 512
    float* psumP   = T + 273474;              // 64x64 (zeroed)
    int*   coarseS = (int*)(T + 277632);      // 512 (zeroed)
    int*   cstartS = (int*)(T + 278144);      // 513
    int*   cursorS = (int*)(T + 278657);      // 512  -> tail ends T+279,169

    // ---- early CSR staging (dead after k_fine2) ----
    unsigned* bufM = (unsigned*)ws_f;                    // [0, 524,288)
    unsigned* bufP = (unsigned*)(ws_f + 524352);         // [524,352, 2,124,416)
    unsigned* bufS = (unsigned*)(ws_f + 2124480);        // [2,124,480, 3,724,480)

    // ---- overlapping phase regions (offsets in floats) ----
    __half*   h2hP      = (__half*)ws_f;
    __half*   x32h      = (__half*)(ws_f + 2124480);
    int*      srcCOL    = (int*)(ws_f + 4194304);
    float*    aggP      = ws_f + 5794304;
    float*    es        = ws_f + 7794304;
    float*    ed_       = ws_f + 7894304;
    float2*   denEd     = (float2*)(ws_f + 7994304);
    int*      srcRP     = (int*)(ws_f + 8194304);
    __half*   h2hM      = (__half*)(ws_f + 8388608);
    int*      molCOL    = (int*)(ws_f + 12582912);       // EM+64 -> 13,107,264
    int*      molRP     = (int*)(ws_f + 13107264);       // NM -> 13,238,336 (+pad)
    float*    dinvM     = ws_f + 13238352;               // NM -> 13,369,424 (+pad)
    __half*   x8h       = (__half*)(ws_f + 13369440);    // NM*8 halves -> 13,893,728 (+pad)
    float*    aggM      = ws_f + 13893792;               // NM*6 -> 14,680,224 (+pad)
    int*      protCOL   = (int*)(ws_f + 14680256);       // EP+64 -> 16,280,320
    int*      protRP    = (int*)(ws_f + 16280320);       // NP -> 16,380,320

    // single upfront zero of gsum..cursorS (contiguous tail region)
    (void)hipMemsetAsync(gsum, 0, (size_t)279169 * sizeof(float), stream);

    // ================= merged CSR build (mol-dst + prot-dst + prot-src) =================
    k_hist2<<<256 + 391 + 391, 256, 0, stream>>>(mol_ei + EM, prot_ei + EP, prot_ei,
                                                 coarseM, coarseP, coarseS);
    k_scan2<<<3, 512, 0, stream>>>(coarseM, cstartM, cursorM, coarseP, cstartP, cursorP,
                                   coarseS, cstartS, cursorS);
    k_part2<<<128 + 391 + 391, 256, 0, stream>>>(mol_ei, cursorM, bufM, prot_ei, cursorP, bufP,
                                                 cursorS, bufS);
    k_fine2<<<512 + 391 + 391, 256, 0, stream>>>(bufM, cstartM, molRP, molCOL, dinvM,
                                                 bufP, cstartP, protRP, protCOL,
                                                 bufS, cstartS, srcRP, srcCOL);

    // ================= merged preps =================
    k_prep2<<<512 + 512 + 391, 256, 0, stream>>>(mol_x, dinvM, x8h, mol_bat, gstart, gend,
                                                 prot_x, gat_w1, gat_as1, gat_ad1, x32h, es, ed_);

    // ================= merged L1 gathers =================
    k_l1g2<<<NM/32 + NP/16, 256, 0, stream>>>(molRP, molCOL, x8h, dinvM, aggM,
                                              protRP, protCOL, x32h, es, ed_, aggP);

    // ================= merged MLPs (MFMA, 64 nodes/block) =================
    k_mlp2<<<NM/64 + cdiv(NP, 64), 256, 0, stream>>>(aggM, gcn_w1, gcn_b1, gcn_w2, h2hM, dinvM,
                                                     aggP, gat_w1, gat_b1, gat_w2, gat_as2, gat_ad2,
                                                     h2hP, es, ed_);

    // ================= L2 phase: prot den + mol gather (one launch) -> fused coef*row sum ======
    k_l2g2<<<NP/16 + NM/16, 256, 0, stream>>>(protRP, protCOL, es, ed_, denEd,
                                              molRP, molCOL, h2hM, dinvM, mol_bat, gsum);
    k_cps<<<NP/32, 256, 0, stream>>>(srcRP, srcCOL, es, denEd, h2hP, psumP);

    // ================= classifier (reduces psumP, applies layer-2 biases) =================
    k_cls<<<NG/4, 256, 0, stream>>>(gsum, gstart, gend, psumP, gcn_b2, gat_b2,
                                    cls_w1, cls_b1, cls_w2, cls_b2, out);
}

// Round 8
// 304.913 us; speedup vs baseline: 1.2851x; 1.0023x over previous
//
#include <hip/hip_runtime.h>
#include <hip/hip_fp16.h>

#define NM 131072   // mol nodes
#define EM 524288   // mol edges
#define NG 4096     // graphs
#define DM 6        // mol in dim
#define NP 100000   // prot nodes
#define EP 1600000  // prot edges
#define DP 20       // prot in dim

static inline int cdiv(int a, int b){ return (a + b - 1) / b; }

__device__ __forceinline__ float leaky(float x){ return x > 0.f ? x : 0.2f * x; }

union H8 { float4 f4; __half2 h2[4]; };
union HF8 { float4 f4; _Float16 h[8]; };

typedef _Float16 f16x8 __attribute__((ext_vector_type(8)));
typedef float    f32x4 __attribute__((ext_vector_type(4)));

// ================= merged bucketed CSR build: mol-dst + prot-dst + prot-src =================
__global__ void k_hist2(const int* __restrict__ dstM, const int* __restrict__ dstP,
                        const int* __restrict__ srcP,
                        int* __restrict__ coarseM, int* __restrict__ coarseP,
                        int* __restrict__ coarseS){
    __shared__ int lh[512];
    int t = threadIdx.x;
    const int* dst; int* coarse; int K, E, base, chunk;
    if (blockIdx.x < 256)      { dst = dstM; coarse = coarseM; K = 512; E = EM; chunk = 2048; base = blockIdx.x * 2048; }
    else if (blockIdx.x < 647) { dst = dstP; coarse = coarseP; K = 391; E = EP; chunk = 4096; base = (blockIdx.x - 256) * 4096; }
    else                       { dst = srcP; coarse = coarseS; K = 391; E = EP; chunk = 4096; base = (blockIdx.x - 647) * 4096; }
    for (int i = t; i < K; i += 256) lh[i] = 0;
    __syncthreads();
    int end = min(base + chunk, E);
    for (int e = base + t; e < end; e += 256)
        atomicAdd(&lh[dst[e] >> 8], 1);
    __syncthreads();
    for (int i = t; i < K; i += 256)
        if (lh[i]) atomicAdd(&coarse[i], lh[i]);
}

__global__ void k_scan2(const int* __restrict__ coarseM, int* __restrict__ cstartM, int* __restrict__ cursorM,
                        const int* __restrict__ coarseP, int* __restrict__ cstartP, int* __restrict__ cursorP,
                        const int* __restrict__ coarseS, int* __restrict__ cstartS, int* __restrict__ cursorS){
    const int* coarse; int* cstart; int* cursor; int K;
    if (blockIdx.x == 0)      { coarse = coarseM; cstart = cstartM; cursor = cursorM; K = 512; }
    else if (blockIdx.x == 1) { coarse = coarseP; cstart = cstartP; cursor = cursorP; K = 391; }
    else                      { coarse = coarseS; cstart = cstartS; cursor = cursorS; K = 391; }
    int t = threadIdx.x, lane = t & 63, wid = t >> 6;
    int v0 = (t < K) ? coarse[t] : 0;
    int v = v0;
    #pragma unroll
    for (int off = 1; off < 64; off <<= 1) {
        int x = __shfl_up(v, off, 64);
        if (lane >= off) v += x;
    }
    __shared__ int ws[8];
    if (lane == 63) ws[wid] = v;
    __syncthreads();
    int add = 0;
    for (int w = 0; w < wid; w++) add += ws[w];
    int excl = v + add - v0;
    if (t < K) { cstart[t] = excl; cursor[t] = excl; }
    if (t == K - 1) cstart[K] = excl + v0;
}

__global__ void k_part2(const int* __restrict__ eiM, int* __restrict__ cursorM, unsigned* __restrict__ bufM,
                        const int* __restrict__ eiP, int* __restrict__ cursorP, unsigned* __restrict__ bufP,
                        int* __restrict__ cursorS, unsigned* __restrict__ bufS){
    __shared__ int lh[512];
    __shared__ int lbase[512];
    const int* ei; int* cursor; unsigned* buf; int E, K, base, sw;
    if (blockIdx.x < 128)      { ei = eiM; cursor = cursorM; buf = bufM; E = EM; K = 512; base = blockIdx.x * 4096; sw = 0; }
    else if (blockIdx.x < 519) { ei = eiP; cursor = cursorP; buf = bufP; E = EP; K = 391; base = (blockIdx.x - 128) * 4096; sw = 0; }
    else                       { ei = eiP; cursor = cursorS; buf = bufS; E = EP; K = 391; base = (blockIdx.x - 519) * 4096; sw = 1; }
    int t = threadIdx.x;
    for (int i = t; i < K; i += 256) lh[i] = 0;
    __syncthreads();
    int end = min(base + 4096, E);
    unsigned pay[16]; int bslot[16];
    int cnt = 0;
    for (int e = base + t; e < end; e += 256) {
        int u = ei[e], v = ei[E + e];
        int key = sw ? u : v, oth = sw ? v : u;
        int b = key >> 8;
        int ls = atomicAdd(&lh[b], 1);
        pay[cnt] = ((unsigned)(key & 255) << 24) | (unsigned)oth;
        bslot[cnt] = (b << 13) | ls;
        cnt++;
    }
    __syncthreads();
    for (int i = t; i < K; i += 256)
        lbase[i] = lh[i] ? atomicAdd(&cursor[i], lh[i]) : 0;
    __syncthreads();
    for (int j = 0; j < cnt; j++) {
        int b = bslot[j] >> 13, ls = bslot[j] & 8191;
        buf[lbase[b] + ls] = pay[j];
    }
}

__global__ void k_fine2(const unsigned* __restrict__ bufM, const int* __restrict__ cstartM,
                        int* __restrict__ molRP, int* __restrict__ molCOL, float* __restrict__ dinv,
                        const unsigned* __restrict__ bufP, const int* __restrict__ cstartP,
                        int* __restrict__ protRP, int* __restrict__ protCOL,
                        const unsigned* __restrict__ bufS, const int* __restrict__ cstartS,
                        int* __restrict__ srcRP, int* __restrict__ srcCOL){
    int t = threadIdx.x;
    int k; const unsigned* buf; const int* cstart; int* rp; int* col; int n, OB, dv;
    if (blockIdx.x < 512)      { k = blockIdx.x;       buf = bufM; cstart = cstartM; rp = molRP;  col = molCOL;  n = NM; OB = 20; dv = 1; }
    else if (blockIdx.x < 903) { k = blockIdx.x - 512; buf = bufP; cstart = cstartP; rp = protRP; col = protCOL; n = NP; OB = 21; dv = 0; }
    else                       { k = blockIdx.x - 903; buf = bufS; cstart = cstartS; rp = srcRP;  col = srcCOL;  n = NP; OB = 21; dv = 0; }
    int start = cstart[k], end = cstart[k + 1];
    __shared__ int cnt[256];
    __shared__ int cur[256];
    cnt[t] = 0;
    __syncthreads();
    for (int p = start + t; p < end; p += 256)
        atomicAdd(&cnt[buf[p] >> 24], 1);
    __syncthreads();
    int v0 = cnt[t];
    int lane = t & 63, wid = t >> 6;
    int v = v0;
    #pragma unroll
    for (int off = 1; off < 64; off <<= 1) {
        int x = __shfl_up(v, off, 64);
        if (lane >= off) v += x;
    }
    __shared__ int ws[4];
    if (lane == 63) ws[wid] = v;
    __syncthreads();
    int add = 0;
    for (int w = 0; w < wid; w++) add += ws[w];
    int excl = v + add - v0;
    int ofs = start + excl;
    cur[t] = ofs;
    int idx = (k << 8) + t;
    if (idx < n) {
        rp[idx] = (int)((unsigned)ofs | ((unsigned)v0 << OB));
        if (dv) dinv[idx] = rsqrtf((float)(v0 + 1));
    }
    __syncthreads();
    for (int p = start + t; p < end; p += 256) {
        unsigned pk = buf[p];
        int slot = atomicAdd(&cur[pk >> 24], 1);
        col[slot] = (int)(pk & 0xFFFFFFu);
    }
}

// ================= merged prep: molprep (512) + segbounds (512) + prot prep (391) =================
__global__ void k_prep2(const float* __restrict__ mol_x, const float* __restrict__ dinv,
                        __half* __restrict__ x8, const int* __restrict__ batch,
                        int* __restrict__ gstart, int* __restrict__ gend,
                        const float* __restrict__ prot_x, const float* __restrict__ W1,
                        const float* __restrict__ as_, const float* __restrict__ ad_,
                        __half* __restrict__ x32, float* __restrict__ es,
                        float* __restrict__ ed_){
    __shared__ float vas[20], vds[20];
    int b = blockIdx.x, t = threadIdx.x;
    if (b < 512) {
        int i = b * 256 + t;
        float dd = dinv[i];
        H8 r;
        #pragma unroll
        for (int k = 0; k < 3; k++)
            r.h2[k] = __floats2half2_rn(dd * mol_x[i*6 + 2*k], dd * mol_x[i*6 + 2*k + 1]);
        r.h2[3] = __floats2half2_rn(0.f, 0.f);
        *(float4*)&x8[(size_t)i * 8] = r.f4;
    } else if (b < 1024) {
        int i = (b - 512) * 256 + t;
        int g = batch[i];
        if (i == 0 || batch[i - 1] != g) gstart[g] = i;
        if (i == NM - 1 || batch[i + 1] != g) gend[g] = i + 1;
    } else {
        if (t < 20) {
            float s = 0.f;
            for (int j = 0; j < 64; j++) s += W1[t * 64 + j] * as_[j];
            vas[t] = s;
        } else if (t >= 32 && t < 52) {
            int k = t - 32;
            float s = 0.f;
            for (int j = 0; j < 64; j++) s += W1[k * 64 + j] * ad_[j];
            vds[k] = s;
        }
        __syncthreads();
        int i = (b - 1024) * 256 + t;
        if (i >= NP) return;
        float xv[20];
        float s = 0.f, d = 0.f;
        #pragma unroll
        for (int k = 0; k < 20; k++) {
            xv[k] = prot_x[i*20 + k];
            s += xv[k] * vas[k]; d += xv[k] * vds[k];
        }
        es[i] = s; ed_[i] = d;
        H8 r0, r1, r2, rz;
        #pragma unroll
        for (int k = 0; k < 4; k++) r0.h2[k] = __floats2half2_rn(xv[2*k],   xv[2*k+1]);
        #pragma unroll
        for (int k = 0; k < 4; k++) r1.h2[k] = __floats2half2_rn(xv[8+2*k], xv[9+2*k]);
        r2.h2[0] = __floats2half2_rn(xv[16], xv[17]);
        r2.h2[1] = __floats2half2_rn(xv[18], xv[19]);
        r2.h2[2] = __floats2half2_rn(0.f, 0.f);
        r2.h2[3] = __floats2half2_rn(0.f, 0.f);
        rz.h2[0] = rz.h2[1] = rz.h2[2] = rz.h2[3] = __floats2half2_rn(0.f, 0.f);
        *(float4*)&x32[(size_t)i * 32]      = r0.f4;
        *(float4*)&x32[(size_t)i * 32 + 8]  = r1.f4;
        *(float4*)&x32[(size_t)i * 32 + 16] = r2.f4;
        *(float4*)&x32[(size_t)i * 32 + 24] = rz.f4;
    }
}

// ================= fused L1 gather + MLP (MFMA f16 16x16x32), 64 nodes/block, 4 waves =====
// Gather writes agg DIRECTLY into the MFMA A-staging LDS slab (no global agg buffers).
// LDS (halves): W1T [64][40] @0, W2T [64][72] @2560, Ain [4][16][40] @7168, X1 [4][16][72] @9728
template<int D, int ATT, int SCALE>
__device__ __forceinline__ void l1m_body(__half* smemh, int bid, int tid,
                                         const int* __restrict__ rp, const int* __restrict__ col,
                                         const __half* __restrict__ xrow,
                                         const float* __restrict__ es1, const float* __restrict__ ed1,
                                         const float* __restrict__ W1, const float* __restrict__ b1,
                                         const float* __restrict__ W2,
                                         const float* __restrict__ as_, const float* __restrict__ ad_,
                                         __half* __restrict__ hout, float* __restrict__ esO,
                                         float* __restrict__ edO, const float* __restrict__ dinv,
                                         int n){
    __half* W1Ts = smemh;            // 64*40
    __half* W2Ts = smemh + 2560;     // 64*72
    __half* AinS = smemh + 7168;     // 4*16*40
    __half* X1S  = smemh + 9728;     // 4*16*72
    int lane = tid & 63, w = tid >> 6;
    int c = lane & 15, g = lane >> 4;
    int node0 = bid * 64 + w * 16;

    // ---- stage transposed f16 weights ----
    for (int idx = tid; idx < 2048; idx += 256) {
        int k = idx >> 6, colj = idx & 63;
        W1Ts[colj * 40 + k] = __float2half(k < D ? W1[k * 64 + colj] : 0.f);
    }
    for (int idx = tid; idx < 4096; idx += 256) {
        int k = idx >> 6, colj = idx & 63;
        W2Ts[colj * 72 + k] = __float2half(W2[k * 64 + colj]);
    }
    // ---- zero own wave's AinS slab (wave-local, lockstep-ordered before gather writes) ----
    {
        float4 z4 = make_float4(0.f, 0.f, 0.f, 0.f);
        float4* az = (float4*)(AinS + w * 640);
        for (int i = lane; i < 80; i += 64) az[i] = z4;
    }

    // ---- L1 gather straight into AinS ----
    if (!ATT) {
        // mol GCN: 16 nodes/wave, 4 lanes/node (edge slots)
        int nd = lane >> 2, q = lane & 3;
        int node = node0 + nd;
        unsigned pk = (unsigned)rp[node];
        int s0 = (int)(pk & 0xFFFFFu);
        int deg = (int)(pk >> 20);
        float acc[6] = {0.f,0.f,0.f,0.f,0.f,0.f};
        if (q == 0) {
            HF8 r; r.f4 = *(const float4*)&xrow[(size_t)node * 8];
            #pragma unroll
            for (int i = 0; i < 6; i++) acc[i] = (float)r.h[i];
        }
        for (int base = 0; base < deg; base += 4) {
            int s = base + q;
            if (s < deg) {
                int cc = col[s0 + s];
                HF8 r; r.f4 = *(const float4*)&xrow[(size_t)cc * 8];
                #pragma unroll
                for (int i = 0; i < 6; i++) acc[i] += (float)r.h[i];
            }
        }
        #pragma unroll
        for (int m = 1; m < 4; m <<= 1) {
            #pragma unroll
            for (int i = 0; i < 6; i++) acc[i] += __shfl_xor(acc[i], m, 64);
        }
        if (q == 0) {
            float dd = dinv[node];
            #pragma unroll
            for (int k = 0; k < 6; k++)
                AinS[w * 640 + nd * 40 + k] = __float2half(dd * acc[k]);
        }
    } else {
        // prot GAT: 4 rounds of {4 nodes x (4 slots x 4 chunks)}
        int nd4 = lane >> 4;
        int slot = (lane >> 2) & 3;
        int chunk = lane & 3;
        for (int rr = 0; rr < 4; rr++) {
            int row = rr * 4 + nd4;
            int node = node0 + row;
            bool valid = node < n;
            int nodeC = valid ? node : 0;
            unsigned pk = (unsigned)rp[nodeC];
            int s0 = (int)(pk & 0x1FFFFFu);
            int deg = valid ? (int)(pk >> 21) : 0;
            float edv = ed1[nodeC];
            float selfw = __expf(leaky(es1[nodeC] + edv));
            float acc[8] = {0.f,0.f,0.f,0.f,0.f,0.f,0.f,0.f};
            float den = (slot == 0) ? selfw : 0.f;
            if (slot == 0 && valid) {
                HF8 r; r.f4 = *(const float4*)&xrow[(size_t)node * 32 + (chunk << 3)];
                #pragma unroll
                for (int i = 0; i < 8; i++) acc[i] = selfw * (float)r.h[i];
            }
            for (int base = 0; base < deg; base += 4) {
                int s = base + slot;
                if (s < deg) {
                    int u = col[s0 + s];
                    float ww = __expf(leaky(es1[u] + edv));
                    HF8 r; r.f4 = *(const float4*)&xrow[(size_t)u * 32 + (chunk << 3)];
                    #pragma unroll
                    for (int i = 0; i < 8; i++) acc[i] += ww * (float)r.h[i];
                    den += ww;
                }
            }
            #pragma unroll
            for (int m = 4; m <= 8; m <<= 1) {
                #pragma unroll
                for (int i = 0; i < 8; i++) acc[i] += __shfl_xor(acc[i], m, 64);
                den += __shfl_xor(den, m, 64);
            }
            float inv = 1.f / den;
            if (slot == 0 && valid) {
                #pragma unroll
                for (int i = 0; i < 8; i++) {
                    int k = (chunk << 3) + i;
                    if (k < 20) AinS[w * 640 + row * 40 + k] = __float2half(acc[i] * inv);
                }
            }
        }
    }
    __syncthreads();

    // ---- layer 1 ----
    f32x4 zz = {0.f, 0.f, 0.f, 0.f};
    f16x8 a1 = *(const f16x8*)&AinS[w * 640 + c * 40 + 8 * g];
    #pragma unroll
    for (int t = 0; t < 4; t++) {
        f16x8 b = *(const f16x8*)&W1Ts[(16 * t + c) * 40 + 8 * g];
        f32x4 h = __builtin_amdgcn_mfma_f32_16x16x32_f16(a1, b, zz, 0, 0, 0);
        float bv = b1[16 * t + c];
        #pragma unroll
        for (int r = 0; r < 4; r++) {
            float v = fmaxf(h[r] + bv, 0.f);
            X1S[w * 1152 + (4 * g + r) * 72 + 16 * t + c] = __float2half(v);
        }
    }
    __syncthreads();

    // ---- layer 2 ----
    f32x4 acc2[4];
    #pragma unroll
    for (int t = 0; t < 4; t++) acc2[t] = zz;
    #pragma unroll
    for (int kt = 0; kt < 2; kt++) {
        f16x8 a = *(const f16x8*)&X1S[w * 1152 + c * 72 + 32 * kt + 8 * g];
        #pragma unroll
        for (int t = 0; t < 4; t++) {
            f16x8 b = *(const f16x8*)&W2Ts[(16 * t + c) * 72 + 32 * kt + 8 * g];
            acc2[t] = __builtin_amdgcn_mfma_f32_16x16x32_f16(a, b, acc2[t], 0, 0, 0);
        }
    }

    if (ATT) {
        float asv[4], adv[4];
        #pragma unroll
        for (int t = 0; t < 4; t++) { asv[t] = as_[16 * t + c]; adv[t] = ad_[16 * t + c]; }
        #pragma unroll
        for (int r = 0; r < 4; r++) {
            float xa = 0.f, ya = 0.f;
            #pragma unroll
            for (int t = 0; t < 4; t++) { xa += acc2[t][r] * asv[t]; ya += acc2[t][r] * adv[t]; }
            #pragma unroll
            for (int m = 1; m < 16; m <<= 1) { xa += __shfl_xor(xa, m, 16); ya += __shfl_xor(ya, m, 16); }
            int nd = node0 + 4 * g + r;
            if (c == 0 && nd < n) { esO[nd] = xa; edO[nd] = ya; }
        }
    }
    if (SCALE) {
        #pragma unroll
        for (int r = 0; r < 4; r++) {
            float dd = dinv[node0 + 4 * g + r];
            #pragma unroll
            for (int t = 0; t < 4; t++) acc2[t][r] *= dd;
        }
    }

    #pragma unroll
    for (int t = 0; t < 4; t++) {
        #pragma unroll
        for (int r = 0; r < 4; r++)
            X1S[w * 1152 + (4 * g + r) * 72 + 16 * t + c] = __float2half(acc2[t][r]);
    }
    __syncthreads();
    int rr2 = lane >> 2, seg = lane & 3;
    union { f16x8 h; float4 f; } o;
    o.h = *(const f16x8*)&X1S[w * 1152 + rr2 * 72 + seg * 16];
    int nd = node0 + rr2;
    if (!ATT || nd < n)
        *(float4*)&hout[(size_t)nd * 64 + seg * 16] = o.f;
}

__global__ void k_l1m(const int* __restrict__ molRP, const int* __restrict__ molCOL,
                      const __half* __restrict__ x8, const float* __restrict__ dinvM,
                      const float* __restrict__ gcn_w1, const float* __restrict__ gcn_b1,
                      const float* __restrict__ gcn_w2, __half* __restrict__ h2hM,
                      const int* __restrict__ protRP, const int* __restrict__ protCOL,
                      const __half* __restrict__ x32, const float* __restrict__ es1,
                      const float* __restrict__ ed1,
                      const float* __restrict__ gat_w1, const float* __restrict__ gat_b1,
                      const float* __restrict__ gat_w2,
                      const float* __restrict__ as2, const float* __restrict__ ad2,
                      __half* __restrict__ h2hP, float* __restrict__ es2, float* __restrict__ ed2){
    __shared__ __attribute__((aligned(16))) __half smemh[14336];   // 28672 B -> 5 blocks/CU
    if (blockIdx.x < NM/64)
        l1m_body<6, 0, 1>(smemh, blockIdx.x, threadIdx.x, molRP, molCOL, x8, nullptr, nullptr,
                          gcn_w1, gcn_b1, gcn_w2, nullptr, nullptr,
                          h2hM, nullptr, nullptr, dinvM, NM);
    else
        l1m_body<20, 1, 0>(smemh, blockIdx.x - NM/64, threadIdx.x, protRP, protCOL, x32, es1, ed1,
                           gat_w1, gat_b1, gat_w2, as2, ad2,
                           h2hP, es2, ed2, nullptr, NP);
}

// ================= prot den (dst-CSR, es2-only gather) =================
__global__ void k_den(const int* __restrict__ protRP, const int* __restrict__ protCOL,
                      const float* __restrict__ es, const float* __restrict__ ed_,
                      float2* __restrict__ denEd){
    int tid = threadIdx.x;
    int node = (blockIdx.x << 4) + (tid >> 4);
    int l16 = tid & 15;
    unsigned pk = (unsigned)protRP[node];
    int s0 = (int)(pk & 0x1FFFFFu);
    int deg = (int)(pk >> 21);
    float edv = ed_[node];
    float den = 0.f;
    for (int s = l16; s < deg; s += 16) {
        int u = protCOL[s0 + s];
        den += __expf(leaky(es[u] + edv));
    }
    #pragma unroll
    for (int m = 1; m < 16; m <<= 1) den += __shfl_xor(den, m, 16);
    if (l16 == 0) {
        float selfw = __expf(leaky(es[node] + edv));
        denEd[node] = make_float2(1.f / (den + selfw), edv);
    }
}

// ================= merged L2: mol gather+pool (8192 blocks) + prot coef*row sum (3125 blocks) ==
__global__ void k_l2c(const int* __restrict__ molRP, const int* __restrict__ molCOL,
                      const __half* __restrict__ hhM, const float* __restrict__ dinv,
                      const int* __restrict__ batch, float* __restrict__ gsum,
                      const int* __restrict__ srcRP, const int* __restrict__ srcCOL,
                      const float* __restrict__ es, const float2* __restrict__ denEd,
                      const __half* __restrict__ hhP, float* __restrict__ psumP){
    __shared__ float sb[16][64];
    __shared__ int gidS[16];
    int tid = threadIdx.x;
    if (blockIdx.x < NM/16) {
        // mol L2: 16 nodes/block, 4 nodes/wave; per node: 2 edge-slots x 8 feature-chunks
        int bid = blockIdx.x;
        int wv = tid >> 6, l = tid & 63;
        int nd = l >> 4;
        int slot = (l >> 3) & 1;
        int q = l & 7;
        int node = (bid << 4) + (wv << 2) + nd;
        int row = (wv << 2) + nd;
        unsigned pk = (unsigned)molRP[node];
        int s0 = (int)(pk & 0xFFFFFu);
        int deg = (int)(pk >> 20);
        float acc[8] = {0.f,0.f,0.f,0.f,0.f,0.f,0.f,0.f};
        if (slot == 0) {
            HF8 r; r.f4 = *(const float4*)&hhM[(size_t)node * 64 + (q << 3)];
            #pragma unroll
            for (int i = 0; i < 8; i++) acc[i] = (float)r.h[i];
        }
        for (int base = 0; base < deg; base += 2) {
            int s = base + slot;
            if (s < deg) {
                int u = molCOL[s0 + s];
                HF8 r; r.f4 = *(const float4*)&hhM[(size_t)u * 64 + (q << 3)];
                #pragma unroll
                for (int i = 0; i < 8; i++) acc[i] += (float)r.h[i];
            }
        }
        #pragma unroll
        for (int i = 0; i < 8; i++) acc[i] += __shfl_xor(acc[i], 8, 64);
        if (slot == 0) {
            float sc = dinv[node];
            #pragma unroll
            for (int i = 0; i < 8; i++) sb[row][(q << 3) + i] = acc[i] * sc;
        }
        if (l == (nd << 4)) gidS[row] = batch[node];
        __syncthreads();
        if (tid < 64) {
            int i = 0;
            while (i < 16) {
                int g0 = gidS[i];
                float s = sb[i][tid];
                int j = i + 1;
                while (j < 16 && gidS[j] == g0) { s += sb[j][tid]; j++; }
                atomicAdd(&gsum[(g0 << 6) + tid], s);
                i = j;
            }
        }
    } else {
        // prot: per-source coef gather + coalesced weighted row accumulate
        int cb = blockIdx.x - NM/16;
        int wv = tid >> 6, l = tid & 63;
        int node = cb * 32 + (tid >> 3);
        int l8 = tid & 7;
        unsigned pk = (unsigned)srcRP[node];
        int s0 = (int)(pk & 0x1FFFFFu);
        int deg = (int)(pk >> 21);
        float esu = es[node];
        float sum = 0.f;
        for (int s = l8; s < deg; s += 8) {
            int v = srcCOL[s0 + s];
            float2 de = denEd[v];
            sum += __expf(leaky(esu + de.y)) * de.x;
        }
        #pragma unroll
        for (int m = 1; m < 8; m <<= 1) sum += __shfl_xor(sum, m, 8);
        float2 du = denEd[node];
        float coef = __expf(leaky(esu + du.y)) * du.x + sum;
        HF8 r; r.f4 = *(const float4*)&hhP[(size_t)node * 64 + (l8 << 3)];
        float acc[8];
        #pragma unroll
        for (int i = 0; i < 8; i++) acc[i] = coef * (float)r.h[i];
        #pragma unroll
        for (int m = 8; m <= 32; m <<= 1) {
            #pragma unroll
            for (int i = 0; i < 8; i++) acc[i] += __shfl_xor(acc[i], m, 64);
        }
        if ((l >> 3) == 0) {
            #pragma unroll
            for (int i = 0; i < 8; i++) sb[wv][(l8 << 3) + i] = acc[i];
        }
        __syncthreads();
        if (tid < 64) {
            float s = sb[0][tid] + sb[1][tid] + sb[2][tid] + sb[3][tid];
            atomicAdd(&psumP[((cb & 63) << 6) + tid], s);
        }
    }
}

// ---------------- fused classifier (reduces psumP, applies layer-2 biases) ----------------
__global__ void k_cls(const float* __restrict__ gsum, const int* __restrict__ gstart,
                      const int* __restrict__ gend, const float* __restrict__ psumP,
                      const float* __restrict__ bg, const float* __restrict__ bp,
                      const float* __restrict__ W1, const float* __restrict__ b1,
                      const float* __restrict__ w2, const float* __restrict__ b2,
                      float* __restrict__ out){
    __shared__ float W1s[128 * 64];
    __shared__ float pv[64], bgs[64];
    int tid = threadIdx.x;
    for (int k = tid; k < 128 * 64; k += 256) W1s[k] = W1[k];
    if (tid < 64) {
        float s = 0.f;
        for (int sl = 0; sl < 64; sl++) s += psumP[(sl << 6) + tid];
        pv[tid] = s * (1.0f / (float)NP) + bp[tid];
        bgs[tid] = bg[tid];
    }
    __syncthreads();
    int g = blockIdx.x * 4 + (tid >> 6);
    int j = tid & 63;
    float cntf = (float)(gend[g] - gstart[g]);
    float inv = 1.0f / fmaxf(cntf, 1.0f);
    float acc = b1[j];
    #pragma unroll 8
    for (int k = 0; k < 64; k++) acc += (gsum[g * 64 + k] * inv + bgs[k]) * W1s[k * 64 + j];
    #pragma unroll 8
    for (int k = 0; k < 64; k++) acc += pv[k] * W1s[(64 + k) * 64 + j];
    float v = fmaxf(acc, 0.f) * w2[j];
    #pragma unroll
    for (int off = 32; off > 0; off >>= 1) v += __shfl_down(v, off, 64);
    if (j == 0) out[g] = 1.0f / (1.0f + expf(-(v + b2[0])));
}

extern "C" void kernel_launch(void* const* d_in, const int* in_sizes, int n_in,
                              void* d_out, int out_size, void* d_ws, size_t ws_size,
                              hipStream_t stream) {
    const float* mol_x   = (const float*)d_in[0];
    const int*   mol_ei  = (const int*)d_in[1];
    const int*   mol_bat = (const int*)d_in[2];
    const float* prot_x  = (const float*)d_in[3];
    const int*   prot_ei = (const int*)d_in[4];
    const float* gcn_w1  = (const float*)d_in[5];
    const float* gcn_b1  = (const float*)d_in[6];
    const float* gcn_w2  = (const float*)d_in[7];
    const float* gcn_b2  = (const float*)d_in[8];
    const float* gat_w1  = (const float*)d_in[9];
    const float* gat_as1 = (const float*)d_in[10];
    const float* gat_ad1 = (const float*)d_in[11];
    const float* gat_b1  = (const float*)d_in[12];
    const float* gat_w2  = (const float*)d_in[13];
    const float* gat_as2 = (const float*)d_in[14];
    const float* gat_ad2 = (const float*)d_in[15];
    const float* gat_b2  = (const float*)d_in[16];
    const float* cls_w1  = (const float*)d_in[17];
    const float* cls_b1  = (const float*)d_in[18];
    const float* cls_w2  = (const float*)d_in[19];
    const float* cls_b2  = (const float*)d_in[20];
    float* out = (float*)d_out;

    float* ws_f = (float*)d_ws;

    // ---- persistent tail ----
    float* T       = ws_f + 16777216;
    float* gsum    = T;                       // 262,144 floats (zeroed)
    int*   gstart  = (int*)(T + 262144);      // 4,096 (zeroed)
    int*   gend    = (int*)(T + 266240);      // 4,096 (zeroed)
    int*   coarseM = (int*)(T + 270400);      // 512 (zeroed)
    int*   coarseP = (int*)(T + 270912);      // 512 (zeroed)
    int*   cstartM = (int*)(T + 271424);      // 513
    int*   cursorM = (int*)(T + 271937);      // 512
    int*   cstartP = (int*)(T + 272449);      // 513
    int*   cursorP = (int*)(T + 272962);      // 512
    float* psumP   = T + 273474;              // 64x64 (zeroed)
    int*   coarseS = (int*)(T + 277632);      // 512 (zeroed)
    int*   cstartS = (int*)(T + 278144);      // 513
    int*   cursorS = (int*)(T + 278657);      // 512  -> tail ends T+279,169 (= ws_f+17,056,385)

    // ---- early CSR staging (dead after k_fine2) ----
    unsigned* bufM = (unsigned*)ws_f;                    // [0, 524,288)
    unsigned* bufP = (unsigned*)(ws_f + 524352);         // [524,352, 2,124,416)
    unsigned* bufS = (unsigned*)(ws_f + 2124480);        // [2,124,480, 3,724,480)

    // ---- overlapping phase regions (offsets in floats) ----
    // [0, 3,200,000):            h2hP (fp16 NP*64) -- k_l1m -> k_l2c (bufM/P/S dead by then)
    // [4,194,304, 5,794,304):    srcCOL (EP ints) -- fine2 -> k_l2c
    // [5,794,304..5,894,304):    es2 ; [5,894,304..5,994,304): ed2 -- k_l1m -> k_den/k_l2c
    // [7,794,304..7,894,304):    es1 ; [7,894,304..7,994,304): ed1 -- prep2 -> k_l1m
    // [7,994,304, 8,194,304):    denEd (float2 NP) -- k_den -> k_l2c
    // [8,194,304, 8,294,304):    srcRP (NP ints) -- fine2 -> k_l2c
    // [8,388,608, 12,582,912):   h2hM (fp16 NM*64) -- k_l1m -> k_l2c
    // [17,100,000, 18,700,000):  x32h (fp16 NP*32) -- prep2 -> k_l1m (past tail end; ws >= 256 MiB
    //                            per harness fill WRITE_SIZE evidence)
    __half*   h2hP      = (__half*)ws_f;
    int*      srcCOL    = (int*)(ws_f + 4194304);
    float*    es2       = ws_f + 5794304;
    float*    ed2       = ws_f + 5894304;
    float*    es1       = ws_f + 7794304;
    float*    ed1       = ws_f + 7894304;
    float2*   denEd     = (float2*)(ws_f + 7994304);
    int*      srcRP     = (int*)(ws_f + 8194304);
    __half*   h2hM      = (__half*)(ws_f + 8388608);
    int*      molCOL    = (int*)(ws_f + 12582912);       // EM+64 -> 13,107,264
    int*      molRP     = (int*)(ws_f + 13107264);       // NM -> 13,238,336 (+pad)
    float*    dinvM     = ws_f + 13238352;               // NM -> 13,369,424 (+pad)
    __half*   x8h       = (__half*)(ws_f + 13369440);    // NM*8 halves -> 13,893,728 (+pad)
    int*      protCOL   = (int*)(ws_f + 14680256);       // EP+64 -> 16,280,320
    int*      protRP    = (int*)(ws_f + 16280320);       // NP -> 16,380,320
    __half*   x32h      = (__half*)(ws_f + 17100000);    // NP*32 halves -> 18,700,000

    // single upfront zero of gsum..cursorS (contiguous tail region)
    (void)hipMemsetAsync(gsum, 0, (size_t)279169 * sizeof(float), stream);

    // ================= merged CSR build (mol-dst + prot-dst + prot-src) =================
    k_hist2<<<256 + 391 + 391, 256, 0, stream>>>(mol_ei + EM, prot_ei + EP, prot_ei,
                                                 coarseM, coarseP, coarseS);
    k_scan2<<<3, 512, 0, stream>>>(coarseM, cstartM, cursorM, coarseP, cstartP, cursorP,
                                   coarseS, cstartS, cursorS);
    k_part2<<<128 + 391 + 391, 256, 0, stream>>>(mol_ei, cursorM, bufM, prot_ei, cursorP, bufP,
                                                 cursorS, bufS);
    k_fine2<<<512 + 391 + 391, 256, 0, stream>>>(bufM, cstartM, molRP, molCOL, dinvM,
                                                 bufP, cstartP, protRP, protCOL,
                                                 bufS, cstartS, srcRP, srcCOL);

    // ================= merged preps =================
    k_prep2<<<512 + 512 + 391, 256, 0, stream>>>(mol_x, dinvM, x8h, mol_bat, gstart, gend,
                                                 prot_x, gat_w1, gat_as1, gat_ad1, x32h, es1, ed1);

    // ================= fused L1 gather + MLP (64 nodes/block) =================
    k_l1m<<<NM/64 + cdiv(NP, 64), 256, 0, stream>>>(molRP, molCOL, x8h, dinvM,
                                                    gcn_w1, gcn_b1, gcn_w2, h2hM,
                                                    protRP, protCOL, x32h, es1, ed1,
                                                    gat_w1, gat_b1, gat_w2, gat_as2, gat_ad2,
                                                    h2hP, es2, ed2);

    // ================= L2 phase: prot den -> (mol gather+pool || prot coef*row sum) =========
    k_den<<<NP/16, 256, 0, stream>>>(protRP, protCOL, es2, ed2, denEd);
    k_l2c<<<NM/16 + NP/32, 256, 0, stream>>>(molRP, molCOL, h2hM, dinvM, mol_bat, gsum,
                                             srcRP, srcCOL, es2, denEd, h2hP, psumP);

    // ================= classifier (reduces psumP, applies layer-2 biases) =================
    k_cls<<<NG/4, 256, 0, stream>>>(gsum, gstart, gend, psumP, gcn_b2, gat_b2,
                                    cls_w1, cls_b1, cls_w2, cls_b2, out);
}

// Round 9
// 289.646 us; speedup vs baseline: 1.3528x; 1.0527x over previous
//
#include <hip/hip_runtime.h>
#include <hip/hip_fp16.h>

#define NM 131072   // mol nodes
#define EM 524288   // mol edges
#define NG 4096     // graphs
#define DM 6        // mol in dim
#define NP 100000   // prot nodes
#define EP 1600000  // prot edges
#define DP 20       // prot in dim

static inline int cdiv(int a, int b){ return (a + b - 1) / b; }

__device__ __forceinline__ float leaky(float x){ return x > 0.f ? x : 0.2f * x; }

union H8 { float4 f4; __half2 h2[4]; };
union HF8 { float4 f4; _Float16 h[8]; };

typedef _Float16 f16x8 __attribute__((ext_vector_type(8)));
typedef float    f32x4 __attribute__((ext_vector_type(4)));

// ================= merged bucketed CSR build: mol-dst + prot-dst + prot-src =================
__global__ void k_hist2(const int* __restrict__ dstM, const int* __restrict__ dstP,
                        const int* __restrict__ srcP,
                        int* __restrict__ coarseM, int* __restrict__ coarseP,
                        int* __restrict__ coarseS){
    __shared__ int lh[512];
    int t = threadIdx.x;
    const int* dst; int* coarse; int K, E, base, chunk;
    if (blockIdx.x < 256)      { dst = dstM; coarse = coarseM; K = 512; E = EM; chunk = 2048; base = blockIdx.x * 2048; }
    else if (blockIdx.x < 647) { dst = dstP; coarse = coarseP; K = 391; E = EP; chunk = 4096; base = (blockIdx.x - 256) * 4096; }
    else                       { dst = srcP; coarse = coarseS; K = 391; E = EP; chunk = 4096; base = (blockIdx.x - 647) * 4096; }
    for (int i = t; i < K; i += 256) lh[i] = 0;
    __syncthreads();
    int end = min(base + chunk, E);
    for (int e = base + t; e < end; e += 256)
        atomicAdd(&lh[dst[e] >> 8], 1);
    __syncthreads();
    for (int i = t; i < K; i += 256)
        if (lh[i]) atomicAdd(&coarse[i], lh[i]);
}

__global__ void k_scan2(const int* __restrict__ coarseM, int* __restrict__ cstartM, int* __restrict__ cursorM,
                        const int* __restrict__ coarseP, int* __restrict__ cstartP, int* __restrict__ cursorP,
                        const int* __restrict__ coarseS, int* __restrict__ cstartS, int* __restrict__ cursorS){
    const int* coarse; int* cstart; int* cursor; int K;
    if (blockIdx.x == 0)      { coarse = coarseM; cstart = cstartM; cursor = cursorM; K = 512; }
    else if (blockIdx.x == 1) { coarse = coarseP; cstart = cstartP; cursor = cursorP; K = 391; }
    else                      { coarse = coarseS; cstart = cstartS; cursor = cursorS; K = 391; }
    int t = threadIdx.x, lane = t & 63, wid = t >> 6;
    int v0 = (t < K) ? coarse[t] : 0;
    int v = v0;
    #pragma unroll
    for (int off = 1; off < 64; off <<= 1) {
        int x = __shfl_up(v, off, 64);
        if (lane >= off) v += x;
    }
    __shared__ int ws[8];
    if (lane == 63) ws[wid] = v;
    __syncthreads();
    int add = 0;
    for (int w = 0; w < wid; w++) add += ws[w];
    int excl = v + add - v0;
    if (t < K) { cstart[t] = excl; cursor[t] = excl; }
    if (t == K - 1) cstart[K] = excl + v0;
}

__global__ void k_part2(const int* __restrict__ eiM, int* __restrict__ cursorM, unsigned* __restrict__ bufM,
                        const int* __restrict__ eiP, int* __restrict__ cursorP, unsigned* __restrict__ bufP,
                        int* __restrict__ cursorS, unsigned* __restrict__ bufS){
    __shared__ int lh[512];
    __shared__ int lbase[512];
    const int* ei; int* cursor; unsigned* buf; int E, K, base, sw;
    if (blockIdx.x < 128)      { ei = eiM; cursor = cursorM; buf = bufM; E = EM; K = 512; base = blockIdx.x * 4096; sw = 0; }
    else if (blockIdx.x < 519) { ei = eiP; cursor = cursorP; buf = bufP; E = EP; K = 391; base = (blockIdx.x - 128) * 4096; sw = 0; }
    else                       { ei = eiP; cursor = cursorS; buf = bufS; E = EP; K = 391; base = (blockIdx.x - 519) * 4096; sw = 1; }
    int t = threadIdx.x;
    for (int i = t; i < K; i += 256) lh[i] = 0;
    __syncthreads();
    int end = min(base + 4096, E);
    unsigned pay[16]; int bslot[16];
    int cnt = 0;
    for (int e = base + t; e < end; e += 256) {
        int u = ei[e], v = ei[E + e];
        int key = sw ? u : v, oth = sw ? v : u;
        int b = key >> 8;
        int ls = atomicAdd(&lh[b], 1);
        pay[cnt] = ((unsigned)(key & 255) << 24) | (unsigned)oth;
        bslot[cnt] = (b << 13) | ls;
        cnt++;
    }
    __syncthreads();
    for (int i = t; i < K; i += 256)
        lbase[i] = lh[i] ? atomicAdd(&cursor[i], lh[i]) : 0;
    __syncthreads();
    for (int j = 0; j < cnt; j++) {
        int b = bslot[j] >> 13, ls = bslot[j] & 8191;
        buf[lbase[b] + ls] = pay[j];
    }
}

__global__ void k_fine2(const unsigned* __restrict__ bufM, const int* __restrict__ cstartM,
                        int* __restrict__ molRP, int* __restrict__ molCOL, float* __restrict__ dinv,
                        const unsigned* __restrict__ bufP, const int* __restrict__ cstartP,
                        int* __restrict__ protRP, int* __restrict__ protCOL,
                        const unsigned* __restrict__ bufS, const int* __restrict__ cstartS,
                        int* __restrict__ srcRP, int* __restrict__ srcCOL){
    int t = threadIdx.x;
    int k; const unsigned* buf; const int* cstart; int* rp; int* col; int n, OB, dv;
    if (blockIdx.x < 512)      { k = blockIdx.x;       buf = bufM; cstart = cstartM; rp = molRP;  col = molCOL;  n = NM; OB = 20; dv = 1; }
    else if (blockIdx.x < 903) { k = blockIdx.x - 512; buf = bufP; cstart = cstartP; rp = protRP; col = protCOL; n = NP; OB = 21; dv = 0; }
    else                       { k = blockIdx.x - 903; buf = bufS; cstart = cstartS; rp = srcRP;  col = srcCOL;  n = NP; OB = 21; dv = 0; }
    int start = cstart[k], end = cstart[k + 1];
    __shared__ int cnt[256];
    __shared__ int cur[256];
    cnt[t] = 0;
    __syncthreads();
    for (int p = start + t; p < end; p += 256)
        atomicAdd(&cnt[buf[p] >> 24], 1);
    __syncthreads();
    int v0 = cnt[t];
    int lane = t & 63, wid = t >> 6;
    int v = v0;
    #pragma unroll
    for (int off = 1; off < 64; off <<= 1) {
        int x = __shfl_up(v, off, 64);
        if (lane >= off) v += x;
    }
    __shared__ int ws[4];
    if (lane == 63) ws[wid] = v;
    __syncthreads();
    int add = 0;
    for (int w = 0; w < wid; w++) add += ws[w];
    int excl = v + add - v0;
    int ofs = start + excl;
    cur[t] = ofs;
    int idx = (k << 8) + t;
    if (idx < n) {
        rp[idx] = (int)((unsigned)ofs | ((unsigned)v0 << OB));
        if (dv) dinv[idx] = rsqrtf((float)(v0 + 1));
    }
    __syncthreads();
    for (int p = start + t; p < end; p += 256) {
        unsigned pk = buf[p];
        int slot = atomicAdd(&cur[pk >> 24], 1);
        col[slot] = (int)(pk & 0xFFFFFFu);
    }
}

// ================= merged prep: molprep (512) + segbounds (512) + prot prep (391) =================
__global__ void k_prep2(const float* __restrict__ mol_x, const float* __restrict__ dinv,
                        __half* __restrict__ x8, const int* __restrict__ batch,
                        int* __restrict__ gstart, int* __restrict__ gend,
                        const float* __restrict__ prot_x, const float* __restrict__ W1,
                        const float* __restrict__ as_, const float* __restrict__ ad_,
                        __half* __restrict__ x32, float* __restrict__ es,
                        float* __restrict__ ed_){
    __shared__ float vas[20], vds[20];
    int b = blockIdx.x, t = threadIdx.x;
    if (b < 512) {
        int i = b * 256 + t;
        float dd = dinv[i];
        H8 r;
        #pragma unroll
        for (int k = 0; k < 3; k++)
            r.h2[k] = __floats2half2_rn(dd * mol_x[i*6 + 2*k], dd * mol_x[i*6 + 2*k + 1]);
        r.h2[3] = __floats2half2_rn(0.f, 0.f);
        *(float4*)&x8[(size_t)i * 8] = r.f4;
    } else if (b < 1024) {
        int i = (b - 512) * 256 + t;
        int g = batch[i];
        if (i == 0 || batch[i - 1] != g) gstart[g] = i;
        if (i == NM - 1 || batch[i + 1] != g) gend[g] = i + 1;
    } else {
        if (t < 20) {
            float s = 0.f;
            for (int j = 0; j < 64; j++) s += W1[t * 64 + j] * as_[j];
            vas[t] = s;
        } else if (t >= 32 && t < 52) {
            int k = t - 32;
            float s = 0.f;
            for (int j = 0; j < 64; j++) s += W1[k * 64 + j] * ad_[j];
            vds[k] = s;
        }
        __syncthreads();
        int i = (b - 1024) * 256 + t;
        if (i >= NP) return;
        float xv[20];
        float s = 0.f, d = 0.f;
        #pragma unroll
        for (int k = 0; k < 20; k++) {
            xv[k] = prot_x[i*20 + k];
            s += xv[k] * vas[k]; d += xv[k] * vds[k];
        }
        es[i] = s; ed_[i] = d;
        H8 r0, r1, r2, rz;
        #pragma unroll
        for (int k = 0; k < 4; k++) r0.h2[k] = __floats2half2_rn(xv[2*k],   xv[2*k+1]);
        #pragma unroll
        for (int k = 0; k < 4; k++) r1.h2[k] = __floats2half2_rn(xv[8+2*k], xv[9+2*k]);
        r2.h2[0] = __floats2half2_rn(xv[16], xv[17]);
        r2.h2[1] = __floats2half2_rn(xv[18], xv[19]);
        r2.h2[2] = __floats2half2_rn(0.f, 0.f);
        r2.h2[3] = __floats2half2_rn(0.f, 0.f);
        rz.h2[0] = rz.h2[1] = rz.h2[2] = rz.h2[3] = __floats2half2_rn(0.f, 0.f);
        *(float4*)&x32[(size_t)i * 32]      = r0.f4;
        *(float4*)&x32[(size_t)i * 32 + 8]  = r1.f4;
        *(float4*)&x32[(size_t)i * 32 + 16] = r2.f4;
        *(float4*)&x32[(size_t)i * 32 + 24] = rz.f4;
    }
}

// ================= fused L1 gather + MLP (MFMA f16 16x16x32), 64 nodes/block, 4 waves =====
// LDS overlay (halves): W2T [64][72] @0, W1T [64][40] @4608, Ain [4][16][40] @7168,
//                       X1 [4][16][72] @4608 (overlays W1T+Ain after both are dead).
// 19456 B total -> 8 blocks/CU (vs 5 at 28 KB): occupancy for the latency-bound gather.
// Safety: a1 + all W1T fragments are register-cached BEFORE the block sync that precedes
// any X1 write; layer-2/repack X1 access is wave-local slabs.
template<int D, int ATT, int SCALE>
__device__ __forceinline__ void l1m_body(__half* smemh, int bid, int tid,
                                         const int* __restrict__ rp, const int* __restrict__ col,
                                         const __half* __restrict__ xrow,
                                         const float* __restrict__ es1, const float* __restrict__ ed1,
                                         const float* __restrict__ W1, const float* __restrict__ b1,
                                         const float* __restrict__ W2,
                                         const float* __restrict__ as_, const float* __restrict__ ad_,
                                         __half* __restrict__ hout, float* __restrict__ esO,
                                         float* __restrict__ edO, const float* __restrict__ dinv,
                                         int n){
    __half* W2Ts = smemh;            // 4608 halves @0
    __half* W1Ts = smemh + 4608;     // 2560 halves @4608
    __half* AinS = smemh + 7168;     // 2560 halves @7168 (4 waves * 640)
    __half* X1S  = smemh + 4608;     // 4608 halves overlay @4608
    int lane = tid & 63, w = tid >> 6;
    int c = lane & 15, g = lane >> 4;
    int node0 = bid * 64 + w * 16;

    // ---- stage transposed f16 weights ----
    for (int idx = tid; idx < 2048; idx += 256) {
        int k = idx >> 6, colj = idx & 63;
        W1Ts[colj * 40 + k] = __float2half(k < D ? W1[k * 64 + colj] : 0.f);
    }
    for (int idx = tid; idx < 4096; idx += 256) {
        int k = idx >> 6, colj = idx & 63;
        W2Ts[colj * 72 + k] = __float2half(W2[k * 64 + colj]);
    }
    // ---- zero own wave's AinS slab ----
    {
        float4 z4 = make_float4(0.f, 0.f, 0.f, 0.f);
        float4* az = (float4*)(AinS + w * 640);
        for (int i = lane; i < 80; i += 64) az[i] = z4;
    }

    // ---- L1 gather straight into AinS ----
    if (!ATT) {
        // mol GCN: 16 nodes/wave, 4 lanes/node (edge slots)
        int nd = lane >> 2, q = lane & 3;
        int node = node0 + nd;
        unsigned pk = (unsigned)rp[node];
        int s0 = (int)(pk & 0xFFFFFu);
        int deg = (int)(pk >> 20);
        float acc[6] = {0.f,0.f,0.f,0.f,0.f,0.f};
        if (q == 0) {
            HF8 r; r.f4 = *(const float4*)&xrow[(size_t)node * 8];
            #pragma unroll
            for (int i = 0; i < 6; i++) acc[i] = (float)r.h[i];
        }
        for (int base = 0; base < deg; base += 4) {
            int s = base + q;
            if (s < deg) {
                int cc = col[s0 + s];
                HF8 r; r.f4 = *(const float4*)&xrow[(size_t)cc * 8];
                #pragma unroll
                for (int i = 0; i < 6; i++) acc[i] += (float)r.h[i];
            }
        }
        #pragma unroll
        for (int m = 1; m < 4; m <<= 1) {
            #pragma unroll
            for (int i = 0; i < 6; i++) acc[i] += __shfl_xor(acc[i], m, 64);
        }
        if (q == 0) {
            float dd = dinv[node];
            #pragma unroll
            for (int k = 0; k < 6; k++)
                AinS[w * 640 + nd * 40 + k] = __float2half(dd * acc[k]);
        }
    } else {
        // prot GAT: 4 rounds of {4 nodes x (4 slots x 4 chunks)}
        int nd4 = lane >> 4;
        int slot = (lane >> 2) & 3;
        int chunk = lane & 3;
        for (int rr = 0; rr < 4; rr++) {
            int row = rr * 4 + nd4;
            int node = node0 + row;
            bool valid = node < n;
            int nodeC = valid ? node : 0;
            unsigned pk = (unsigned)rp[nodeC];
            int s0 = (int)(pk & 0x1FFFFFu);
            int deg = valid ? (int)(pk >> 21) : 0;
            float edv = ed1[nodeC];
            float selfw = __expf(leaky(es1[nodeC] + edv));
            float acc[8] = {0.f,0.f,0.f,0.f,0.f,0.f,0.f,0.f};
            float den = (slot == 0) ? selfw : 0.f;
            if (slot == 0 && valid) {
                HF8 r; r.f4 = *(const float4*)&xrow[(size_t)node * 32 + (chunk << 3)];
                #pragma unroll
                for (int i = 0; i < 8; i++) acc[i] = selfw * (float)r.h[i];
            }
            for (int base = 0; base < deg; base += 4) {
                int s = base + slot;
                if (s < deg) {
                    int u = col[s0 + s];
                    float ww = __expf(leaky(es1[u] + edv));
                    HF8 r; r.f4 = *(const float4*)&xrow[(size_t)u * 32 + (chunk << 3)];
                    #pragma unroll
                    for (int i = 0; i < 8; i++) acc[i] += ww * (float)r.h[i];
                    den += ww;
                }
            }
            #pragma unroll
            for (int m = 4; m <= 8; m <<= 1) {
                #pragma unroll
                for (int i = 0; i < 8; i++) acc[i] += __shfl_xor(acc[i], m, 64);
                den += __shfl_xor(den, m, 64);
            }
            float inv = 1.f / den;
            if (slot == 0 && valid) {
                #pragma unroll
                for (int i = 0; i < 8; i++) {
                    int k = (chunk << 3) + i;
                    if (k < 20) AinS[w * 640 + row * 40 + k] = __float2half(acc[i] * inv);
                }
            }
        }
    }
    __syncthreads();   // gather + weight staging complete

    // ---- layer 1: register-cache A and all W1T fragments, then sync, then MFMA+X1 write ----
    f32x4 zz = {0.f, 0.f, 0.f, 0.f};
    f16x8 a1 = *(const f16x8*)&AinS[w * 640 + c * 40 + 8 * g];
    f16x8 b1f[4];
    #pragma unroll
    for (int t = 0; t < 4; t++)
        b1f[t] = *(const f16x8*)&W1Ts[(16 * t + c) * 40 + 8 * g];
    __syncthreads();   // all W1Ts/AinS reads done -> X1S overlay may be written
    #pragma unroll
    for (int t = 0; t < 4; t++) {
        f32x4 h = __builtin_amdgcn_mfma_f32_16x16x32_f16(a1, b1f[t], zz, 0, 0, 0);
        float bv = b1[16 * t + c];
        #pragma unroll
        for (int r = 0; r < 4; r++) {
            float v = fmaxf(h[r] + bv, 0.f);
            X1S[w * 1152 + (4 * g + r) * 72 + 16 * t + c] = __float2half(v);
        }
    }
    // X1S slabs are wave-local: no block sync needed before layer 2

    // ---- layer 2 ----
    f32x4 acc2[4];
    #pragma unroll
    for (int t = 0; t < 4; t++) acc2[t] = zz;
    #pragma unroll
    for (int kt = 0; kt < 2; kt++) {
        f16x8 a = *(const f16x8*)&X1S[w * 1152 + c * 72 + 32 * kt + 8 * g];
        #pragma unroll
        for (int t = 0; t < 4; t++) {
            f16x8 b = *(const f16x8*)&W2Ts[(16 * t + c) * 72 + 32 * kt + 8 * g];
            acc2[t] = __builtin_amdgcn_mfma_f32_16x16x32_f16(a, b, acc2[t], 0, 0, 0);
        }
    }

    if (ATT) {
        float asv[4], adv[4];
        #pragma unroll
        for (int t = 0; t < 4; t++) { asv[t] = as_[16 * t + c]; adv[t] = ad_[16 * t + c]; }
        #pragma unroll
        for (int r = 0; r < 4; r++) {
            float xa = 0.f, ya = 0.f;
            #pragma unroll
            for (int t = 0; t < 4; t++) { xa += acc2[t][r] * asv[t]; ya += acc2[t][r] * adv[t]; }
            #pragma unroll
            for (int m = 1; m < 16; m <<= 1) { xa += __shfl_xor(xa, m, 16); ya += __shfl_xor(ya, m, 16); }
            int nd = node0 + 4 * g + r;
            if (c == 0 && nd < n) { esO[nd] = xa; edO[nd] = ya; }
        }
    }
    if (SCALE) {
        #pragma unroll
        for (int r = 0; r < 4; r++) {
            float dd = dinv[node0 + 4 * g + r];
            #pragma unroll
            for (int t = 0; t < 4; t++) acc2[t][r] *= dd;
        }
    }

    // ---- repack through X1S (wave-local) -> coalesced float4 f16 stores ----
    #pragma unroll
    for (int t = 0; t < 4; t++) {
        #pragma unroll
        for (int r = 0; r < 4; r++)
            X1S[w * 1152 + (4 * g + r) * 72 + 16 * t + c] = __float2half(acc2[t][r]);
    }
    int rr2 = lane >> 2, seg = lane & 3;
    union { f16x8 h; float4 f; } o;
    o.h = *(const f16x8*)&X1S[w * 1152 + rr2 * 72 + seg * 16];
    int nd = node0 + rr2;
    if (!ATT || nd < n)
        *(float4*)&hout[(size_t)nd * 64 + seg * 16] = o.f;
}

__global__ __launch_bounds__(256, 8)
void k_l1m(const int* __restrict__ molRP, const int* __restrict__ molCOL,
           const __half* __restrict__ x8, const float* __restrict__ dinvM,
           const float* __restrict__ gcn_w1, const float* __restrict__ gcn_b1,
           const float* __restrict__ gcn_w2, __half* __restrict__ h2hM,
           const int* __restrict__ protRP, const int* __restrict__ protCOL,
           const __half* __restrict__ x32, const float* __restrict__ es1,
           const float* __restrict__ ed1,
           const float* __restrict__ gat_w1, const float* __restrict__ gat_b1,
           const float* __restrict__ gat_w2,
           const float* __restrict__ as2, const float* __restrict__ ad2,
           __half* __restrict__ h2hP, float* __restrict__ es2, float* __restrict__ ed2){
    __shared__ __attribute__((aligned(16))) __half smemh[9728];   // 19456 B -> 8 blocks/CU
    if (blockIdx.x < NM/64)
        l1m_body<6, 0, 1>(smemh, blockIdx.x, threadIdx.x, molRP, molCOL, x8, nullptr, nullptr,
                          gcn_w1, gcn_b1, gcn_w2, nullptr, nullptr,
                          h2hM, nullptr, nullptr, dinvM, NM);
    else
        l1m_body<20, 1, 0>(smemh, blockIdx.x - NM/64, threadIdx.x, protRP, protCOL, x32, es1, ed1,
                           gat_w1, gat_b1, gat_w2, as2, ad2,
                           h2hP, es2, ed2, nullptr, NP);
}

// ================= prot den (dst-CSR, es2-only gather) =================
__global__ void k_den(const int* __restrict__ protRP, const int* __restrict__ protCOL,
                      const float* __restrict__ es, const float* __restrict__ ed_,
                      float2* __restrict__ denEd){
    int tid = threadIdx.x;
    int node = (blockIdx.x << 4) + (tid >> 4);
    int l16 = tid & 15;
    unsigned pk = (unsigned)protRP[node];
    int s0 = (int)(pk & 0x1FFFFFu);
    int deg = (int)(pk >> 21);
    float edv = ed_[node];
    float den = 0.f;
    for (int s = l16; s < deg; s += 16) {
        int u = protCOL[s0 + s];
        den += __expf(leaky(es[u] + edv));
    }
    #pragma unroll
    for (int m = 1; m < 16; m <<= 1) den += __shfl_xor(den, m, 16);
    if (l16 == 0) {
        float selfw = __expf(leaky(es[node] + edv));
        denEd[node] = make_float2(1.f / (den + selfw), edv);
    }
}

// ================= merged L2: mol gather+pool (8192 blocks) + prot coef*row sum (3125 blocks) ==
__global__ void k_l2c(const int* __restrict__ molRP, const int* __restrict__ molCOL,
                      const __half* __restrict__ hhM, const float* __restrict__ dinv,
                      const int* __restrict__ batch, float* __restrict__ gsum,
                      const int* __restrict__ srcRP, const int* __restrict__ srcCOL,
                      const float* __restrict__ es, const float2* __restrict__ denEd,
                      const __half* __restrict__ hhP, float* __restrict__ psumP){
    __shared__ float sb[16][64];
    __shared__ int gidS[16];
    int tid = threadIdx.x;
    if (blockIdx.x < NM/16) {
        // mol L2: 16 nodes/block, 4 nodes/wave; per node: 2 edge-slots x 8 feature-chunks
        int bid = blockIdx.x;
        int wv = tid >> 6, l = tid & 63;
        int nd = l >> 4;
        int slot = (l >> 3) & 1;
        int q = l & 7;
        int node = (bid << 4) + (wv << 2) + nd;
        int row = (wv << 2) + nd;
        unsigned pk = (unsigned)molRP[node];
        int s0 = (int)(pk & 0xFFFFFu);
        int deg = (int)(pk >> 20);
        float acc[8] = {0.f,0.f,0.f,0.f,0.f,0.f,0.f,0.f};
        if (slot == 0) {
            HF8 r; r.f4 = *(const float4*)&hhM[(size_t)node * 64 + (q << 3)];
            #pragma unroll
            for (int i = 0; i < 8; i++) acc[i] = (float)r.h[i];
        }
        for (int base = 0; base < deg; base += 2) {
            int s = base + slot;
            if (s < deg) {
                int u = molCOL[s0 + s];
                HF8 r; r.f4 = *(const float4*)&hhM[(size_t)u * 64 + (q << 3)];
                #pragma unroll
                for (int i = 0; i < 8; i++) acc[i] += (float)r.h[i];
            }
        }
        #pragma unroll
        for (int i = 0; i < 8; i++) acc[i] += __shfl_xor(acc[i], 8, 64);
        if (slot == 0) {
            float sc = dinv[node];
            #pragma unroll
            for (int i = 0; i < 8; i++) sb[row][(q << 3) + i] = acc[i] * sc;
        }
        if (l == (nd << 4)) gidS[row] = batch[node];
        __syncthreads();
        if (tid < 64) {
            int i = 0;
            while (i < 16) {
                int g0 = gidS[i];
                float s = sb[i][tid];
                int j = i + 1;
                while (j < 16 && gidS[j] == g0) { s += sb[j][tid]; j++; }
                atomicAdd(&gsum[(g0 << 6) + tid], s);
                i = j;
            }
        }
    } else {
        // prot: per-source coef gather + coalesced weighted row accumulate
        int cb = blockIdx.x - NM/16;
        int wv = tid >> 6, l = tid & 63;
        int node = cb * 32 + (tid >> 3);
        int l8 = tid & 7;
        unsigned pk = (unsigned)srcRP[node];
        int s0 = (int)(pk & 0x1FFFFFu);
        int deg = (int)(pk >> 21);
        float esu = es[node];
        float sum = 0.f;
        for (int s = l8; s < deg; s += 8) {
            int v = srcCOL[s0 + s];
            float2 de = denEd[v];
            sum += __expf(leaky(esu + de.y)) * de.x;
        }
        #pragma unroll
        for (int m = 1; m < 8; m <<= 1) sum += __shfl_xor(sum, m, 8);
        float2 du = denEd[node];
        float coef = __expf(leaky(esu + du.y)) * du.x + sum;
        HF8 r; r.f4 = *(const float4*)&hhP[(size_t)node * 64 + (l8 << 3)];
        float acc[8];
        #pragma unroll
        for (int i = 0; i < 8; i++) acc[i] = coef * (float)r.h[i];
        #pragma unroll
        for (int m = 8; m <= 32; m <<= 1) {
            #pragma unroll
            for (int i = 0; i < 8; i++) acc[i] += __shfl_xor(acc[i], m, 64);
        }
        if ((l >> 3) == 0) {
            #pragma unroll
            for (int i = 0; i < 8; i++) sb[wv][(l8 << 3) + i] = acc[i];
        }
        __syncthreads();
        if (tid < 64) {
            float s = sb[0][tid] + sb[1][tid] + sb[2][tid] + sb[3][tid];
            atomicAdd(&psumP[((cb & 63) << 6) + tid], s);
        }
    }
}

// ---------------- fused classifier (reduces psumP, applies layer-2 biases) ----------------
__global__ void k_cls(const float* __restrict__ gsum, const int* __restrict__ gstart,
                      const int* __restrict__ gend, const float* __restrict__ psumP,
                      const float* __restrict__ bg, const float* __restrict__ bp,
                      const float* __restrict__ W1, const float* __restrict__ b1,
                      const float* __restrict__ w2, const float* __restrict__ b2,
                      float* __restrict__ out){
    __shared__ float W1s[128 * 64];
    __shared__ float pv[64], bgs[64];
    int tid = threadIdx.x;
    for (int k = tid; k < 128 * 64; k += 256) W1s[k] = W1[k];
    if (tid < 64) {
        float s = 0.f;
        for (int sl = 0; sl < 64; sl++) s += psumP[(sl << 6) + tid];
        pv[tid] = s * (1.0f / (float)NP) + bp[tid];
        bgs[tid] = bg[tid];
    }
    __syncthreads();
    int g = blockIdx.x * 4 + (tid >> 6);
    int j = tid & 63;
    float cntf = (float)(gend[g] - gstart[g]);
    float inv = 1.0f / fmaxf(cntf, 1.0f);
    float acc = b1[j];
    #pragma unroll 8
    for (int k = 0; k < 64; k++) acc += (gsum[g * 64 + k] * inv + bgs[k]) * W1s[k * 64 + j];
    #pragma unroll 8
    for (int k = 0; k < 64; k++) acc += pv[k] * W1s[(64 + k) * 64 + j];
    float v = fmaxf(acc, 0.f) * w2[j];
    #pragma unroll
    for (int off = 32; off > 0; off >>= 1) v += __shfl_down(v, off, 64);
    if (j == 0) out[g] = 1.0f / (1.0f + expf(-(v + b2[0])));
}

extern "C" void kernel_launch(void* const* d_in, const int* in_sizes, int n_in,
                              void* d_out, int out_size, void* d_ws, size_t ws_size,
                              hipStream_t stream) {
    const float* mol_x   = (const float*)d_in[0];
    const int*   mol_ei  = (const int*)d_in[1];
    const int*   mol_bat = (const int*)d_in[2];
    const float* prot_x  = (const float*)d_in[3];
    const int*   prot_ei = (const int*)d_in[4];
    const float* gcn_w1  = (const float*)d_in[5];
    const float* gcn_b1  = (const float*)d_in[6];
    const float* gcn_w2  = (const float*)d_in[7];
    const float* gcn_b2  = (const float*)d_in[8];
    const float* gat_w1  = (const float*)d_in[9];
    const float* gat_as1 = (const float*)d_in[10];
    const float* gat_ad1 = (const float*)d_in[11];
    const float* gat_b1  = (const float*)d_in[12];
    const float* gat_w2  = (const float*)d_in[13];
    const float* gat_as2 = (const float*)d_in[14];
    const float* gat_ad2 = (const float*)d_in[15];
    const float* gat_b2  = (const float*)d_in[16];
    const float* cls_w1  = (const float*)d_in[17];
    const float* cls_b1  = (const float*)d_in[18];
    const float* cls_w2  = (const float*)d_in[19];
    const float* cls_b2  = (const float*)d_in[20];
    float* out = (float*)d_out;

    float* ws_f = (float*)d_ws;

    // ---- persistent tail ----
    float* T       = ws_f + 16777216;
    float* gsum    = T;                       // 262,144 floats (zeroed)
    int*   gstart  = (int*)(T + 262144);      // 4,096 (zeroed)
    int*   gend    = (int*)(T + 266240);      // 4,096 (zeroed)
    int*   coarseM = (int*)(T + 270400);      // 512 (zeroed)
    int*   coarseP = (int*)(T + 270912);      // 512 (zeroed)
    int*   cstartM = (int*)(T + 271424);      // 513
    int*   cursorM = (int*)(T + 271937);      // 512
    int*   cstartP = (int*)(T + 272449);      // 513
    int*   cursorP = (int*)(T + 272962);      // 512
    float* psumP   = T + 273474;              // 64x64 (zeroed)
    int*   coarseS = (int*)(T + 277632);      // 512 (zeroed)
    int*   cstartS = (int*)(T + 278144);      // 513
    int*   cursorS = (int*)(T + 278657);      // 512  -> tail ends T+279,169 (= ws_f+17,056,385)

    // ---- early CSR staging (dead after k_fine2) ----
    unsigned* bufM = (unsigned*)ws_f;                    // [0, 524,288)
    unsigned* bufP = (unsigned*)(ws_f + 524352);         // [524,352, 2,124,416)
    unsigned* bufS = (unsigned*)(ws_f + 2124480);        // [2,124,480, 3,724,480)

    // ---- overlapping phase regions (offsets in floats) ----
    __half*   h2hP      = (__half*)ws_f;
    int*      srcCOL    = (int*)(ws_f + 4194304);
    float*    es2       = ws_f + 5794304;
    float*    ed2       = ws_f + 5894304;
    float*    es1       = ws_f + 7794304;
    float*    ed1       = ws_f + 7894304;
    float2*   denEd     = (float2*)(ws_f + 7994304);
    int*      srcRP     = (int*)(ws_f + 8194304);
    __half*   h2hM      = (__half*)(ws_f + 8388608);
    int*      molCOL    = (int*)(ws_f + 12582912);       // EM+64 -> 13,107,264
    int*      molRP     = (int*)(ws_f + 13107264);       // NM -> 13,238,336 (+pad)
    float*    dinvM     = ws_f + 13238352;               // NM -> 13,369,424 (+pad)
    __half*   x8h       = (__half*)(ws_f + 13369440);    // NM*8 halves -> 13,893,728 (+pad)
    int*      protCOL   = (int*)(ws_f + 14680256);       // EP+64 -> 16,280,320
    int*      protRP    = (int*)(ws_f + 16280320);       // NP -> 16,380,320
    __half*   x32h      = (__half*)(ws_f + 17100000);    // NP*32 halves -> 18,700,000

    // single upfront zero of gsum..cursorS (contiguous tail region)
    (void)hipMemsetAsync(gsum, 0, (size_t)279169 * sizeof(float), stream);

    // ================= merged CSR build (mol-dst + prot-dst + prot-src) =================
    k_hist2<<<256 + 391 + 391, 256, 0, stream>>>(mol_ei + EM, prot_ei + EP, prot_ei,
                                                 coarseM, coarseP, coarseS);
    k_scan2<<<3, 512, 0, stream>>>(coarseM, cstartM, cursorM, coarseP, cstartP, cursorP,
                                   coarseS, cstartS, cursorS);
    k_part2<<<128 + 391 + 391, 256, 0, stream>>>(mol_ei, cursorM, bufM, prot_ei, cursorP, bufP,
                                                 cursorS, bufS);
    k_fine2<<<512 + 391 + 391, 256, 0, stream>>>(bufM, cstartM, molRP, molCOL, dinvM,
                                                 bufP, cstartP, protRP, protCOL,
                                                 bufS, cstartS, srcRP, srcCOL);

    // ================= merged preps =================
    k_prep2<<<512 + 512 + 391, 256, 0, stream>>>(mol_x, dinvM, x8h, mol_bat, gstart, gend,
                                                 prot_x, gat_w1, gat_as1, gat_ad1, x32h, es1, ed1);

    // ================= fused L1 gather + MLP (64 nodes/block) =================
    k_l1m<<<NM/64 + cdiv(NP, 64), 256, 0, stream>>>(molRP, molCOL, x8h, dinvM,
                                                    gcn_w1, gcn_b1, gcn_w2, h2hM,
                                                    protRP, protCOL, x32h, es1, ed1,
                                                    gat_w1, gat_b1, gat_w2, gat_as2, gat_ad2,
                                                    h2hP, es2, ed2);

    // ================= L2 phase: prot den -> (mol gather+pool || prot coef*row sum) =========
    k_den<<<NP/16, 256, 0, stream>>>(protRP, protCOL, es2, ed2, denEd);
    k_l2c<<<NM/16 + NP/32, 256, 0, stream>>>(molRP, molCOL, h2hM, dinvM, mol_bat, gsum,
                                             srcRP, srcCOL, es2, denEd, h2hP, psumP);

    // ================= classifier (reduces psumP, applies layer-2 biases) =================
    k_cls<<<NG/4, 256, 0, stream>>>(gsum, gstart, gend, psumP, gcn_b2, gat_b2,
                                    cls_w1, cls_b1, cls_w2, cls_b2, out);
}

// Round 10
// 282.273 us; speedup vs baseline: 1.3882x; 1.0261x over previous
//
#include <hip/hip_runtime.h>
#include <hip/hip_fp16.h>

#define NM 131072   // mol nodes
#define EM 524288   // mol edges
#define NG 4096     // graphs
#define DM 6        // mol in dim
#define NP 100000   // prot nodes
#define EP 1600000  // prot edges
#define DP 20       // prot in dim

static inline int cdiv(int a, int b){ return (a + b - 1) / b; }

__device__ __forceinline__ float leaky(float x){ return x > 0.f ? x : 0.2f * x; }

union H8 { float4 f4; __half2 h2[4]; };
union HF8 { float4 f4; _Float16 h[8]; };

typedef _Float16 f16x8 __attribute__((ext_vector_type(8)));
typedef float    f32x4 __attribute__((ext_vector_type(4)));

// ================= merged bucketed CSR build: mol-dst + prot-dst + prot-src =================
__global__ void k_hist2(const int* __restrict__ dstM, const int* __restrict__ dstP,
                        const int* __restrict__ srcP,
                        int* __restrict__ coarseM, int* __restrict__ coarseP,
                        int* __restrict__ coarseS){
    __shared__ int lh[512];
    int t = threadIdx.x;
    const int* dst; int* coarse; int K, E, base, chunk;
    if (blockIdx.x < 256)      { dst = dstM; coarse = coarseM; K = 512; E = EM; chunk = 2048; base = blockIdx.x * 2048; }
    else if (blockIdx.x < 647) { dst = dstP; coarse = coarseP; K = 391; E = EP; chunk = 4096; base = (blockIdx.x - 256) * 4096; }
    else                       { dst = srcP; coarse = coarseS; K = 391; E = EP; chunk = 4096; base = (blockIdx.x - 647) * 4096; }
    for (int i = t; i < K; i += 256) lh[i] = 0;
    __syncthreads();
    int end = min(base + chunk, E);
    for (int e = base + t; e < end; e += 256)
        atomicAdd(&lh[dst[e] >> 8], 1);
    __syncthreads();
    for (int i = t; i < K; i += 256)
        if (lh[i]) atomicAdd(&coarse[i], lh[i]);
}

__global__ void k_scan2(const int* __restrict__ coarseM, int* __restrict__ cstartM, int* __restrict__ cursorM,
                        const int* __restrict__ coarseP, int* __restrict__ cstartP, int* __restrict__ cursorP,
                        const int* __restrict__ coarseS, int* __restrict__ cstartS, int* __restrict__ cursorS){
    const int* coarse; int* cstart; int* cursor; int K;
    if (blockIdx.x == 0)      { coarse = coarseM; cstart = cstartM; cursor = cursorM; K = 512; }
    else if (blockIdx.x == 1) { coarse = coarseP; cstart = cstartP; cursor = cursorP; K = 391; }
    else                      { coarse = coarseS; cstart = cstartS; cursor = cursorS; K = 391; }
    int t = threadIdx.x, lane = t & 63, wid = t >> 6;
    int v0 = (t < K) ? coarse[t] : 0;
    int v = v0;
    #pragma unroll
    for (int off = 1; off < 64; off <<= 1) {
        int x = __shfl_up(v, off, 64);
        if (lane >= off) v += x;
    }
    __shared__ int ws[8];
    if (lane == 63) ws[wid] = v;
    __syncthreads();
    int add = 0;
    for (int w = 0; w < wid; w++) add += ws[w];
    int excl = v + add - v0;
    if (t < K) { cstart[t] = excl; cursor[t] = excl; }
    if (t == K - 1) cstart[K] = excl + v0;
}

__global__ void k_part2(const int* __restrict__ eiM, int* __restrict__ cursorM, unsigned* __restrict__ bufM,
                        const int* __restrict__ eiP, int* __restrict__ cursorP, unsigned* __restrict__ bufP,
                        int* __restrict__ cursorS, unsigned* __restrict__ bufS){
    __shared__ int lh[512];
    __shared__ int lbase[512];
    const int* ei; int* cursor; unsigned* buf; int E, K, base, sw;
    if (blockIdx.x < 128)      { ei = eiM; cursor = cursorM; buf = bufM; E = EM; K = 512; base = blockIdx.x * 4096; sw = 0; }
    else if (blockIdx.x < 519) { ei = eiP; cursor = cursorP; buf = bufP; E = EP; K = 391; base = (blockIdx.x - 128) * 4096; sw = 0; }
    else                       { ei = eiP; cursor = cursorS; buf = bufS; E = EP; K = 391; base = (blockIdx.x - 519) * 4096; sw = 1; }
    int t = threadIdx.x;
    for (int i = t; i < K; i += 256) lh[i] = 0;
    __syncthreads();
    int end = min(base + 4096, E);
    unsigned pay[16]; int bslot[16];
    int cnt = 0;
    for (int e = base + t; e < end; e += 256) {
        int u = ei[e], v = ei[E + e];
        int key = sw ? u : v, oth = sw ? v : u;
        int b = key >> 8;
        int ls = atomicAdd(&lh[b], 1);
        pay[cnt] = ((unsigned)(key & 255) << 24) | (unsigned)oth;
        bslot[cnt] = (b << 13) | ls;
        cnt++;
    }
    __syncthreads();
    for (int i = t; i < K; i += 256)
        lbase[i] = lh[i] ? atomicAdd(&cursor[i], lh[i]) : 0;
    __syncthreads();
    for (int j = 0; j < cnt; j++) {
        int b = bslot[j] >> 13, ls = bslot[j] & 8191;
        buf[lbase[b] + ls] = pay[j];
    }
}

// fine pass + fused prep epilogue (molprep+segbounds in mol blocks; prot prep in prot-dst blocks)
__global__ void k_fine2(const unsigned* __restrict__ bufM, const int* __restrict__ cstartM,
                        int* __restrict__ molRP, int* __restrict__ molCOL, float* __restrict__ dinv,
                        const unsigned* __restrict__ bufP, const int* __restrict__ cstartP,
                        int* __restrict__ protRP, int* __restrict__ protCOL,
                        const unsigned* __restrict__ bufS, const int* __restrict__ cstartS,
                        int* __restrict__ srcRP, int* __restrict__ srcCOL,
                        const float* __restrict__ mol_x, __half* __restrict__ x8,
                        const int* __restrict__ batch, int* __restrict__ gstart,
                        int* __restrict__ gend,
                        const float* __restrict__ prot_x, const float* __restrict__ W1a,
                        const float* __restrict__ as_, const float* __restrict__ ad_,
                        __half* __restrict__ x32, float* __restrict__ es,
                        float* __restrict__ ed_){
    __shared__ float vas[20], vds[20];
    int t = threadIdx.x;
    int k; const unsigned* buf; const int* cstart; int* rp; int* col; int n, OB, dv, pp;
    if (blockIdx.x < 512)      { k = blockIdx.x;       buf = bufM; cstart = cstartM; rp = molRP;  col = molCOL;  n = NM; OB = 20; dv = 1; pp = 0; }
    else if (blockIdx.x < 903) { k = blockIdx.x - 512; buf = bufP; cstart = cstartP; rp = protRP; col = protCOL; n = NP; OB = 21; dv = 0; pp = 1; }
    else                       { k = blockIdx.x - 903; buf = bufS; cstart = cstartS; rp = srcRP;  col = srcCOL;  n = NP; OB = 21; dv = 0; pp = 0; }
    if (pp) {
        if (t < 20) {
            float s = 0.f;
            for (int j = 0; j < 64; j++) s += W1a[t * 64 + j] * as_[j];
            vas[t] = s;
        } else if (t >= 32 && t < 52) {
            int kk = t - 32;
            float s = 0.f;
            for (int j = 0; j < 64; j++) s += W1a[kk * 64 + j] * ad_[j];
            vds[kk] = s;
        }
    }
    int start = cstart[k], end = cstart[k + 1];
    __shared__ int cnt[256];
    __shared__ int cur[256];
    cnt[t] = 0;
    __syncthreads();
    for (int p = start + t; p < end; p += 256)
        atomicAdd(&cnt[buf[p] >> 24], 1);
    __syncthreads();
    int v0 = cnt[t];
    int lane = t & 63, wid = t >> 6;
    int v = v0;
    #pragma unroll
    for (int off = 1; off < 64; off <<= 1) {
        int x = __shfl_up(v, off, 64);
        if (lane >= off) v += x;
    }
    __shared__ int ws[4];
    if (lane == 63) ws[wid] = v;
    __syncthreads();
    int add = 0;
    for (int w = 0; w < wid; w++) add += ws[w];
    int excl = v + add - v0;
    int ofs = start + excl;
    cur[t] = ofs;
    int idx = (k << 8) + t;
    if (idx < n) {
        rp[idx] = (int)((unsigned)ofs | ((unsigned)v0 << OB));
        if (dv) dinv[idx] = rsqrtf((float)(v0 + 1));
    }
    __syncthreads();
    for (int p = start + t; p < end; p += 256) {
        unsigned pk = buf[p];
        int slot = atomicAdd(&cur[pk >> 24], 1);
        col[slot] = (int)(pk & 0xFFFFFFu);
    }
    // ---- fused prep epilogue (no extra syncs: vas/vds synced long ago, v0 thread-local) ----
    if (dv) {
        // mol: x8 pack (dinv local) + segment bounds
        float dd = rsqrtf((float)(v0 + 1));
        H8 r;
        #pragma unroll
        for (int kk = 0; kk < 3; kk++)
            r.h2[kk] = __floats2half2_rn(dd * mol_x[idx*6 + 2*kk], dd * mol_x[idx*6 + 2*kk + 1]);
        r.h2[3] = __floats2half2_rn(0.f, 0.f);
        *(float4*)&x8[(size_t)idx * 8] = r.f4;
        int g = batch[idx];
        if (idx == 0 || batch[idx - 1] != g) gstart[g] = idx;
        if (idx == NM - 1 || batch[idx + 1] != g) gend[g] = idx + 1;
    } else if (pp && idx < n) {
        float xv[20];
        float s = 0.f, d = 0.f;
        #pragma unroll
        for (int kk = 0; kk < 20; kk++) {
            xv[kk] = prot_x[idx*20 + kk];
            s += xv[kk] * vas[kk]; d += xv[kk] * vds[kk];
        }
        es[idx] = s; ed_[idx] = d;
        H8 r0, r1, r2, rz;
        #pragma unroll
        for (int kk = 0; kk < 4; kk++) r0.h2[kk] = __floats2half2_rn(xv[2*kk],   xv[2*kk+1]);
        #pragma unroll
        for (int kk = 0; kk < 4; kk++) r1.h2[kk] = __floats2half2_rn(xv[8+2*kk], xv[9+2*kk]);
        r2.h2[0] = __floats2half2_rn(xv[16], xv[17]);
        r2.h2[1] = __floats2half2_rn(xv[18], xv[19]);
        r2.h2[2] = __floats2half2_rn(0.f, 0.f);
        r2.h2[3] = __floats2half2_rn(0.f, 0.f);
        rz.h2[0] = rz.h2[1] = rz.h2[2] = rz.h2[3] = __floats2half2_rn(0.f, 0.f);
        *(float4*)&x32[(size_t)idx * 32]      = r0.f4;
        *(float4*)&x32[(size_t)idx * 32 + 8]  = r1.f4;
        *(float4*)&x32[(size_t)idx * 32 + 16] = r2.f4;
        *(float4*)&x32[(size_t)idx * 32 + 24] = rz.f4;
    }
}

// ================= fused L1 gather + MLP (MFMA f16 16x16x32), 64 nodes/block, 4 waves =====
// LDS overlay (halves): W2T [64][72] @0, W1T [64][40] @4608, Ain [4][16][40] @7168,
//                       X1 [4][16][72] @4608 (overlays W1T+Ain after both are dead).
// 19456 B total -> 8 blocks/CU. Grid runs PROT blocks first (longest-processing-time order).
template<int D, int ATT, int SCALE>
__device__ __forceinline__ void l1m_body(__half* smemh, int bid, int tid,
                                         const int* __restrict__ rp, const int* __restrict__ col,
                                         const __half* __restrict__ xrow,
                                         const float* __restrict__ es1, const float* __restrict__ ed1,
                                         const float* __restrict__ W1, const float* __restrict__ b1,
                                         const float* __restrict__ W2,
                                         const float* __restrict__ as_, const float* __restrict__ ad_,
                                         __half* __restrict__ hout, float* __restrict__ esO,
                                         float* __restrict__ edO, const float* __restrict__ dinv,
                                         int n){
    __half* W2Ts = smemh;            // 4608 halves @0
    __half* W1Ts = smemh + 4608;     // 2560 halves @4608
    __half* AinS = smemh + 7168;     // 2560 halves @7168 (4 waves * 640)
    __half* X1S  = smemh + 4608;     // 4608 halves overlay @4608
    int lane = tid & 63, w = tid >> 6;
    int c = lane & 15, g = lane >> 4;
    int node0 = bid * 64 + w * 16;

    // ---- stage transposed f16 weights ----
    for (int idx = tid; idx < 2048; idx += 256) {
        int k = idx >> 6, colj = idx & 63;
        W1Ts[colj * 40 + k] = __float2half(k < D ? W1[k * 64 + colj] : 0.f);
    }
    for (int idx = tid; idx < 4096; idx += 256) {
        int k = idx >> 6, colj = idx & 63;
        W2Ts[colj * 72 + k] = __float2half(W2[k * 64 + colj]);
    }
    // ---- zero own wave's AinS slab ----
    {
        float4 z4 = make_float4(0.f, 0.f, 0.f, 0.f);
        float4* az = (float4*)(AinS + w * 640);
        for (int i = lane; i < 80; i += 64) az[i] = z4;
    }

    // ---- L1 gather straight into AinS ----
    if (!ATT) {
        // mol GCN: 16 nodes/wave, 4 lanes/node (edge slots)
        int nd = lane >> 2, q = lane & 3;
        int node = node0 + nd;
        unsigned pk = (unsigned)rp[node];
        int s0 = (int)(pk & 0xFFFFFu);
        int deg = (int)(pk >> 20);
        float acc[6] = {0.f,0.f,0.f,0.f,0.f,0.f};
        if (q == 0) {
            HF8 r; r.f4 = *(const float4*)&xrow[(size_t)node * 8];
            #pragma unroll
            for (int i = 0; i < 6; i++) acc[i] = (float)r.h[i];
        }
        for (int base = 0; base < deg; base += 4) {
            int s = base + q;
            if (s < deg) {
                int cc = col[s0 + s];
                HF8 r; r.f4 = *(const float4*)&xrow[(size_t)cc * 8];
                #pragma unroll
                for (int i = 0; i < 6; i++) acc[i] += (float)r.h[i];
            }
        }
        #pragma unroll
        for (int m = 1; m < 4; m <<= 1) {
            #pragma unroll
            for (int i = 0; i < 6; i++) acc[i] += __shfl_xor(acc[i], m, 64);
        }
        if (q == 0) {
            float dd = dinv[node];
            #pragma unroll
            for (int k = 0; k < 6; k++)
                AinS[w * 640 + nd * 40 + k] = __float2half(dd * acc[k]);
        }
    } else {
        // prot GAT: 4 rounds of {4 nodes x (4 slots x 4 chunks)}
        int nd4 = lane >> 4;
        int slot = (lane >> 2) & 3;
        int chunk = lane & 3;
        for (int rr = 0; rr < 4; rr++) {
            int row = rr * 4 + nd4;
            int node = node0 + row;
            bool valid = node < n;
            int nodeC = valid ? node : 0;
            unsigned pk = (unsigned)rp[nodeC];
            int s0 = (int)(pk & 0x1FFFFFu);
            int deg = valid ? (int)(pk >> 21) : 0;
            float edv = ed1[nodeC];
            float selfw = __expf(leaky(es1[nodeC] + edv));
            float acc[8] = {0.f,0.f,0.f,0.f,0.f,0.f,0.f,0.f};
            float den = (slot == 0) ? selfw : 0.f;
            if (slot == 0 && valid) {
                HF8 r; r.f4 = *(const float4*)&xrow[(size_t)node * 32 + (chunk << 3)];
                #pragma unroll
                for (int i = 0; i < 8; i++) acc[i] = selfw * (float)r.h[i];
            }
            for (int base = 0; base < deg; base += 4) {
                int s = base + slot;
                if (s < deg) {
                    int u = col[s0 + s];
                    float ww = __expf(leaky(es1[u] + edv));
                    HF8 r; r.f4 = *(const float4*)&xrow[(size_t)u * 32 + (chunk << 3)];
                    #pragma unroll
                    for (int i = 0; i < 8; i++) acc[i] += ww * (float)r.h[i];
                    den += ww;
                }
            }
            #pragma unroll
            for (int m = 4; m <= 8; m <<= 1) {
                #pragma unroll
                for (int i = 0; i < 8; i++) acc[i] += __shfl_xor(acc[i], m, 64);
                den += __shfl_xor(den, m, 64);
            }
            float inv = 1.f / den;
            if (slot == 0 && valid) {
                #pragma unroll
                for (int i = 0; i < 8; i++) {
                    int k = (chunk << 3) + i;
                    if (k < 20) AinS[w * 640 + row * 40 + k] = __float2half(acc[i] * inv);
                }
            }
        }
    }
    __syncthreads();   // gather + weight staging complete

    // ---- layer 1: register-cache A and all W1T fragments, then sync, then MFMA+X1 write ----
    f32x4 zz = {0.f, 0.f, 0.f, 0.f};
    f16x8 a1 = *(const f16x8*)&AinS[w * 640 + c * 40 + 8 * g];
    f16x8 b1f[4];
    #pragma unroll
    for (int t = 0; t < 4; t++)
        b1f[t] = *(const f16x8*)&W1Ts[(16 * t + c) * 40 + 8 * g];
    __syncthreads();   // all W1Ts/AinS reads done -> X1S overlay may be written
    #pragma unroll
    for (int t = 0; t < 4; t++) {
        f32x4 h = __builtin_amdgcn_mfma_f32_16x16x32_f16(a1, b1f[t], zz, 0, 0, 0);
        float bv = b1[16 * t + c];
        #pragma unroll
        for (int r = 0; r < 4; r++) {
            float v = fmaxf(h[r] + bv, 0.f);
            X1S[w * 1152 + (4 * g + r) * 72 + 16 * t + c] = __float2half(v);
        }
    }
    // X1S slabs are wave-local: no block sync needed before layer 2

    // ---- layer 2 ----
    f32x4 acc2[4];
    #pragma unroll
    for (int t = 0; t < 4; t++) acc2[t] = zz;
    #pragma unroll
    for (int kt = 0; kt < 2; kt++) {
        f16x8 a = *(const f16x8*)&X1S[w * 1152 + c * 72 + 32 * kt + 8 * g];
        #pragma unroll
        for (int t = 0; t < 4; t++) {
            f16x8 b = *(const f16x8*)&W2Ts[(16 * t + c) * 72 + 32 * kt + 8 * g];
            acc2[t] = __builtin_amdgcn_mfma_f32_16x16x32_f16(a, b, acc2[t], 0, 0, 0);
        }
    }

    if (ATT) {
        float asv[4], adv[4];
        #pragma unroll
        for (int t = 0; t < 4; t++) { asv[t] = as_[16 * t + c]; adv[t] = ad_[16 * t + c]; }
        #pragma unroll
        for (int r = 0; r < 4; r++) {
            float xa = 0.f, ya = 0.f;
            #pragma unroll
            for (int t = 0; t < 4; t++) { xa += acc2[t][r] * asv[t]; ya += acc2[t][r] * adv[t]; }
            #pragma unroll
            for (int m = 1; m < 16; m <<= 1) { xa += __shfl_xor(xa, m, 16); ya += __shfl_xor(ya, m, 16); }
            int nd = node0 + 4 * g + r;
            if (c == 0 && nd < n) { esO[nd] = xa; edO[nd] = ya; }
        }
    }
    if (SCALE) {
        #pragma unroll
        for (int r = 0; r < 4; r++) {
            float dd = dinv[node0 + 4 * g + r];
            #pragma unroll
            for (int t = 0; t < 4; t++) acc2[t][r] *= dd;
        }
    }

    // ---- repack through X1S (wave-local) -> coalesced float4 f16 stores ----
    #pragma unroll
    for (int t = 0; t < 4; t++) {
        #pragma unroll
        for (int r = 0; r < 4; r++)
            X1S[w * 1152 + (4 * g + r) * 72 + 16 * t + c] = __float2half(acc2[t][r]);
    }
    int rr2 = lane >> 2, seg = lane & 3;
    union { f16x8 h; float4 f; } o;
    o.h = *(const f16x8*)&X1S[w * 1152 + rr2 * 72 + seg * 16];
    int nd = node0 + rr2;
    if (!ATT || nd < n)
        *(float4*)&hout[(size_t)nd * 64 + seg * 16] = o.f;
}

#define PROTB 1563   // cdiv(NP, 64)

__global__ __launch_bounds__(256, 8)
void k_l1m(const int* __restrict__ molRP, const int* __restrict__ molCOL,
           const __half* __restrict__ x8, const float* __restrict__ dinvM,
           const float* __restrict__ gcn_w1, const float* __restrict__ gcn_b1,
           const float* __restrict__ gcn_w2, __half* __restrict__ h2hM,
           const int* __restrict__ protRP, const int* __restrict__ protCOL,
           const __half* __restrict__ x32, const float* __restrict__ es1,
           const float* __restrict__ ed1,
           const float* __restrict__ gat_w1, const float* __restrict__ gat_b1,
           const float* __restrict__ gat_w2,
           const float* __restrict__ as2, const float* __restrict__ ad2,
           __half* __restrict__ h2hP, float* __restrict__ es2, float* __restrict__ ed2){
    __shared__ __attribute__((aligned(16))) __half smemh[9728];   // 19456 B -> 8 blocks/CU
    if (blockIdx.x < PROTB)   // long prot blocks first (LPT)
        l1m_body<20, 1, 0>(smemh, blockIdx.x, threadIdx.x, protRP, protCOL, x32, es1, ed1,
                           gat_w1, gat_b1, gat_w2, as2, ad2,
                           h2hP, es2, ed2, nullptr, NP);
    else
        l1m_body<6, 0, 1>(smemh, blockIdx.x - PROTB, threadIdx.x, molRP, molCOL, x8, nullptr, nullptr,
                          gcn_w1, gcn_b1, gcn_w2, nullptr, nullptr,
                          h2hM, nullptr, nullptr, dinvM, NM);
}

// ================= prot den (dst-CSR, es2-only gather) =================
__global__ void k_den(const int* __restrict__ protRP, const int* __restrict__ protCOL,
                      const float* __restrict__ es, const float* __restrict__ ed_,
                      float2* __restrict__ denEd){
    int tid = threadIdx.x;
    int node = (blockIdx.x << 4) + (tid >> 4);
    int l16 = tid & 15;
    unsigned pk = (unsigned)protRP[node];
    int s0 = (int)(pk & 0x1FFFFFu);
    int deg = (int)(pk >> 21);
    float edv = ed_[node];
    float den = 0.f;
    for (int s = l16; s < deg; s += 16) {
        int u = protCOL[s0 + s];
        den += __expf(leaky(es[u] + edv));
    }
    #pragma unroll
    for (int m = 1; m < 16; m <<= 1) den += __shfl_xor(den, m, 16);
    if (l16 == 0) {
        float selfw = __expf(leaky(es[node] + edv));
        denEd[node] = make_float2(1.f / (den + selfw), edv);
    }
}

// ================= merged L2: mol gather+pool (8192 blocks) + prot coef*row sum (3125 blocks) ==
__global__ void k_l2c(const int* __restrict__ molRP, const int* __restrict__ molCOL,
                      const __half* __restrict__ hhM, const float* __restrict__ dinv,
                      const int* __restrict__ batch, float* __restrict__ gsum,
                      const int* __restrict__ srcRP, const int* __restrict__ srcCOL,
                      const float* __restrict__ es, const float2* __restrict__ denEd,
                      const __half* __restrict__ hhP, float* __restrict__ psumP){
    __shared__ float sb[16][64];
    __shared__ int gidS[16];
    int tid = threadIdx.x;
    if (blockIdx.x < NM/16) {
        // mol L2: 16 nodes/block, 4 nodes/wave; per node: 2 edge-slots x 8 feature-chunks
        int bid = blockIdx.x;
        int wv = tid >> 6, l = tid & 63;
        int nd = l >> 4;
        int slot = (l >> 3) & 1;
        int q = l & 7;
        int node = (bid << 4) + (wv << 2) + nd;
        int row = (wv << 2) + nd;
        unsigned pk = (unsigned)molRP[node];
        int s0 = (int)(pk & 0xFFFFFu);
        int deg = (int)(pk >> 20);
        float acc[8] = {0.f,0.f,0.f,0.f,0.f,0.f,0.f,0.f};
        if (slot == 0) {
            HF8 r; r.f4 = *(const float4*)&hhM[(size_t)node * 64 + (q << 3)];
            #pragma unroll
            for (int i = 0; i < 8; i++) acc[i] = (float)r.h[i];
        }
        for (int base = 0; base < deg; base += 2) {
            int s = base + slot;
            if (s < deg) {
                int u = molCOL[s0 + s];
                HF8 r; r.f4 = *(const float4*)&hhM[(size_t)u * 64 + (q << 3)];
                #pragma unroll
                for (int i = 0; i < 8; i++) acc[i] += (float)r.h[i];
            }
        }
        #pragma unroll
        for (int i = 0; i < 8; i++) acc[i] += __shfl_xor(acc[i], 8, 64);
        if (slot == 0) {
            float sc = dinv[node];
            #pragma unroll
            for (int i = 0; i < 8; i++) sb[row][(q << 3) + i] = acc[i] * sc;
        }
        if (l == (nd << 4)) gidS[row] = batch[node];
        __syncthreads();
        if (tid < 64) {
            int i = 0;
            while (i < 16) {
                int g0 = gidS[i];
                float s = sb[i][tid];
                int j = i + 1;
                while (j < 16 && gidS[j] == g0) { s += sb[j][tid]; j++; }
                atomicAdd(&gsum[(g0 << 6) + tid], s);
                i = j;
            }
        }
    } else {
        // prot: per-source coef gather + coalesced weighted row accumulate
        int cb = blockIdx.x - NM/16;
        int wv = tid >> 6, l = tid & 63;
        int node = cb * 32 + (tid >> 3);
        int l8 = tid & 7;
        unsigned pk = (unsigned)srcRP[node];
        int s0 = (int)(pk & 0x1FFFFFu);
        int deg = (int)(pk >> 21);
        float esu = es[node];
        float sum = 0.f;
        for (int s = l8; s < deg; s += 8) {
            int v = srcCOL[s0 + s];
            float2 de = denEd[v];
            sum += __expf(leaky(esu + de.y)) * de.x;
        }
        #pragma unroll
        for (int m = 1; m < 8; m <<= 1) sum += __shfl_xor(sum, m, 8);
        float2 du = denEd[node];
        float coef = __expf(leaky(esu + du.y)) * du.x + sum;
        HF8 r; r.f4 = *(const float4*)&hhP[(size_t)node * 64 + (l8 << 3)];
        float acc[8];
        #pragma unroll
        for (int i = 0; i < 8; i++) acc[i] = coef * (float)r.h[i];
        #pragma unroll
        for (int m = 8; m <= 32; m <<= 1) {
            #pragma unroll
            for (int i = 0; i < 8; i++) acc[i] += __shfl_xor(acc[i], m, 64);
        }
        if ((l >> 3) == 0) {
            #pragma unroll
            for (int i = 0; i < 8; i++) sb[wv][(l8 << 3) + i] = acc[i];
        }
        __syncthreads();
        if (tid < 64) {
            float s = sb[0][tid] + sb[1][tid] + sb[2][tid] + sb[3][tid];
            atomicAdd(&psumP[((cb & 63) << 6) + tid], s);
        }
    }
}

// ---------------- fused classifier (reduces psumP, applies layer-2 biases) ----------------
__global__ void k_cls(const float* __restrict__ gsum, const int* __restrict__ gstart,
                      const int* __restrict__ gend, const float* __restrict__ psumP,
                      const float* __restrict__ bg, const float* __restrict__ bp,
                      const float* __restrict__ W1, const float* __restrict__ b1,
                      const float* __restrict__ w2, const float* __restrict__ b2,
                      float* __restrict__ out){
    __shared__ float W1s[128 * 64];
    __shared__ float pv[64], bgs[64];
    int tid = threadIdx.x;
    for (int k = tid; k < 128 * 64; k += 256) W1s[k] = W1[k];
    if (tid < 64) {
        float s = 0.f;
        for (int sl = 0; sl < 64; sl++) s += psumP[(sl << 6) + tid];
        pv[tid] = s * (1.0f / (float)NP) + bp[tid];
        bgs[tid] = bg[tid];
    }
    __syncthreads();
    int g = blockIdx.x * 4 + (tid >> 6);
    int j = tid & 63;
    float cntf = (float)(gend[g] - gstart[g]);
    float inv = 1.0f / fmaxf(cntf, 1.0f);
    float acc = b1[j];
    #pragma unroll 8
    for (int k = 0; k < 64; k++) acc += (gsum[g * 64 + k] * inv + bgs[k]) * W1s[k * 64 + j];
    #pragma unroll 8
    for (int k = 0; k < 64; k++) acc += pv[k] * W1s[(64 + k) * 64 + j];
    float v = fmaxf(acc, 0.f) * w2[j];
    #pragma unroll
    for (int off = 32; off > 0; off >>= 1) v += __shfl_down(v, off, 64);
    if (j == 0) out[g] = 1.0f / (1.0f + expf(-(v + b2[0])));
}

extern "C" void kernel_launch(void* const* d_in, const int* in_sizes, int n_in,
                              void* d_out, int out_size, void* d_ws, size_t ws_size,
                              hipStream_t stream) {
    const float* mol_x   = (const float*)d_in[0];
    const int*   mol_ei  = (const int*)d_in[1];
    const int*   mol_bat = (const int*)d_in[2];
    const float* prot_x  = (const float*)d_in[3];
    const int*   prot_ei = (const int*)d_in[4];
    const float* gcn_w1  = (const float*)d_in[5];
    const float* gcn_b1  = (const float*)d_in[6];
    const float* gcn_w2  = (const float*)d_in[7];
    const float* gcn_b2  = (const float*)d_in[8];
    const float* gat_w1  = (const float*)d_in[9];
    const float* gat_as1 = (const float*)d_in[10];
    const float* gat_ad1 = (const float*)d_in[11];
    const float* gat_b1  = (const float*)d_in[12];
    const float* gat_w2  = (const float*)d_in[13];
    const float* gat_as2 = (const float*)d_in[14];
    const float* gat_ad2 = (const float*)d_in[15];
    const float* gat_b2  = (const float*)d_in[16];
    const float* cls_w1  = (const float*)d_in[17];
    const float* cls_b1  = (const float*)d_in[18];
    const float* cls_w2  = (const float*)d_in[19];
    const float* cls_b2  = (const float*)d_in[20];
    float* out = (float*)d_out;

    float* ws_f = (float*)d_ws;

    // ---- persistent tail ----
    float* T       = ws_f + 16777216;
    float* gsum    = T;                       // 262,144 floats (zeroed)
    int*   gstart  = (int*)(T + 262144);      // 4,096 (zeroed)
    int*   gend    = (int*)(T + 266240);      // 4,096 (zeroed)
    int*   coarseM = (int*)(T + 270400);      // 512 (zeroed)
    int*   coarseP = (int*)(T + 270912);      // 512 (zeroed)
    int*   cstartM = (int*)(T + 271424);      // 513
    int*   cursorM = (int*)(T + 271937);      // 512
    int*   cstartP = (int*)(T + 272449);      // 513
    int*   cursorP = (int*)(T + 272962);      // 512
    float* psumP   = T + 273474;              // 64x64 (zeroed)
    int*   coarseS = (int*)(T + 277632);      // 512 (zeroed)
    int*   cstartS = (int*)(T + 278144);      // 513
    int*   cursorS = (int*)(T + 278657);      // 512  -> tail ends T+279,169 (= ws_f+17,056,385)

    // ---- early CSR staging (dead after k_fine2) ----
    unsigned* bufM = (unsigned*)ws_f;                    // [0, 524,288)
    unsigned* bufP = (unsigned*)(ws_f + 524352);         // [524,352, 2,124,416)
    unsigned* bufS = (unsigned*)(ws_f + 2124480);        // [2,124,480, 3,724,480)

    // ---- overlapping phase regions (offsets in floats) ----
    __half*   h2hP      = (__half*)ws_f;
    int*      srcCOL    = (int*)(ws_f + 4194304);
    float*    es2       = ws_f + 5794304;
    float*    ed2       = ws_f + 5894304;
    float*    es1       = ws_f + 7794304;
    float*    ed1       = ws_f + 7894304;
    float2*   denEd     = (float2*)(ws_f + 7994304);
    int*      srcRP     = (int*)(ws_f + 8194304);
    __half*   h2hM      = (__half*)(ws_f + 8388608);
    int*      molCOL    = (int*)(ws_f + 12582912);       // EM+64 -> 13,107,264
    int*      molRP     = (int*)(ws_f + 13107264);       // NM -> 13,238,336 (+pad)
    float*    dinvM     = ws_f + 13238352;               // NM -> 13,369,424 (+pad)
    __half*   x8h       = (__half*)(ws_f + 13369440);    // NM*8 halves -> 13,893,728 (+pad)
    int*      protCOL   = (int*)(ws_f + 14680256);       // EP+64 -> 16,280,320
    int*      protRP    = (int*)(ws_f + 16280320);       // NP -> 16,380,320
    __half*   x32h      = (__half*)(ws_f + 17100000);    // NP*32 halves -> 18,700,000

    // single upfront zero of gsum..cursorS (contiguous tail region)
    (void)hipMemsetAsync(gsum, 0, (size_t)279169 * sizeof(float), stream);

    // ================= merged CSR build (mol-dst + prot-dst + prot-src) =================
    k_hist2<<<256 + 391 + 391, 256, 0, stream>>>(mol_ei + EM, prot_ei + EP, prot_ei,
                                                 coarseM, coarseP, coarseS);
    k_scan2<<<3, 512, 0, stream>>>(coarseM, cstartM, cursorM, coarseP, cstartP, cursorP,
                                   coarseS, cstartS, cursorS);
    k_part2<<<128 + 391 + 391, 256, 0, stream>>>(mol_ei, cursorM, bufM, prot_ei, cursorP, bufP,
                                                 cursorS, bufS);
    // fine pass + fused prep epilogue (replaces k_prep2)
    k_fine2<<<512 + 391 + 391, 256, 0, stream>>>(bufM, cstartM, molRP, molCOL, dinvM,
                                                 bufP, cstartP, protRP, protCOL,
                                                 bufS, cstartS, srcRP, srcCOL,
                                                 mol_x, x8h, mol_bat, gstart, gend,
                                                 prot_x, gat_w1, gat_as1, gat_ad1,
                                                 x32h, es1, ed1);

    // ================= fused L1 gather + MLP (64 nodes/block, prot-first LPT order) ==========
    k_l1m<<<PROTB + NM/64, 256, 0, stream>>>(molRP, molCOL, x8h, dinvM,
                                             gcn_w1, gcn_b1, gcn_w2, h2hM,
                                             protRP, protCOL, x32h, es1, ed1,
                                             gat_w1, gat_b1, gat_w2, gat_as2, gat_ad2,
                                             h2hP, es2, ed2);

    // ================= L2 phase: prot den -> (mol gather+pool || prot coef*row sum) =========
    k_den<<<NP/16, 256, 0, stream>>>(protRP, protCOL, es2, ed2, denEd);
    k_l2c<<<NM/16 + NP/32, 256, 0, stream>>>(molRP, molCOL, h2hM, dinvM, mol_bat, gsum,
                                             srcRP, srcCOL, es2, denEd, h2hP, psumP);

    // ================= classifier (reduces psumP, applies layer-2 biases) =================
    k_cls<<<NG/4, 256, 0, stream>>>(gsum, gstart, gend, psumP, gcn_b2, gat_b2,
                                    cls_w1, cls_b1, cls_w2, cls_b2, out);
}